// Round 12
// baseline (1542.929 us; speedup 1.0000x reference)
//
#include <hip/hip_runtime.h>
#include <cstddef>
#include <cstdint>

constexpr int B_ = 8, P_ = 4096, K_ = 20, H_ = 64, C_ = 40;
constexpr int NPT = B_ * P_;
constexpr int NSEG = 2, SEGLEN = P_ / NSEG;   // 2048 candidates per segment
#define NEG_SLOPE 0.2f

typedef unsigned long long u64;
typedef unsigned int u32;
typedef unsigned short u16;
typedef __attribute__((ext_vector_type(8))) short bf16x8;
typedef __attribute__((ext_vector_type(4))) float f32x4;

__device__ inline u16 f2bf(float v) {   // round-to-nearest-even bf16
    u32 bits = __float_as_uint(v);
    return (u16)((bits + 0x7FFFu + ((bits >> 16) & 1)) >> 16);
}
__device__ inline float bf2f(u16 h) { return __uint_as_float((u32)h << 16); }

// ---------------------------------------------------------------- d2 = sum(x*x)
template <int D>
__global__ __launch_bounds__(256) void d2_kernel(const float* __restrict__ x,
                                                 float* __restrict__ d2) {
    int i = blockIdx.x * 256 + threadIdx.x;
    if (i >= NPT) return;
    const float* r = x + (size_t)i * D;
    float s = 0.f;
    if constexpr (D % 4 == 0) {
#pragma unroll
        for (int d = 0; d < D; d += 4) {
            float4 v = *(const float4*)(r + d);
            s += v.x * v.x + v.y * v.y + v.z * v.z + v.w * v.w;
        }
    } else {
#pragma unroll
        for (int d = 0; d < D; ++d) { float v = r[d]; s += v * v; }
    }
    d2[i] = s;
}

// ---------------------------------------------------------------- split x (f32) -> h,m,l bf16
__global__ __launch_bounds__(256) void cvt3_kernel(const float* __restrict__ x,
                                                   u16* __restrict__ xh,
                                                   u16* __restrict__ xm,
                                                   u16* __restrict__ xl) {
    int i = blockIdx.x * 256 + threadIdx.x;   // NPT*64 elems
    float v = x[i];
    u16 h = f2bf(v);
    float r1 = v - bf2f(h);
    u16 m = f2bf(r1);
    float r2 = r1 - bf2f(m);
    xh[i] = h; xm[i] = m; xl[i] = f2bf(r2);
}

// ---------------------------------------------------------------- layer-1 fused knn (D=3), segmented
// blockIdx.z = candidate segment; writes sorted per-query segment top-20 to segl.
template <int D>
__global__ __launch_bounds__(256) void knnf_kernel(const float* __restrict__ x,
                                                   const float* __restrict__ d2,
                                                   u64* __restrict__ segl) {
    __shared__ float sQT[D][68];
    __shared__ float sCT[D][68];
    __shared__ float sD[64][68];

    int b = blockIdx.y;
    int q0 = blockIdx.x * 64;
    int seg = blockIdx.z;
    const float* xc  = x + (size_t)b * P_ * D;
    const float* d2b = d2 + (size_t)b * P_;

    int t = threadIdx.x;
    int ty = t >> 4, tx = t & 15;
    int w = t >> 6, ln = t & 63;
    int qs = w * 16 + (ln >> 2);
    int cs = ln & 3;

    if (t < 64) {
#pragma unroll
        for (int d = 0; d < D; ++d) sQT[d][t] = xc[(size_t)(q0 + t) * D + d];
    }
    float qd2i[4];
#pragma unroll
    for (int i = 0; i < 4; ++i) qd2i[i] = d2b[q0 + ty * 4 + i];

    double a[K_];
#pragma unroll
    for (int s = 0; s < K_; ++s)
        a[s] = __longlong_as_double((0x7F7FFFFFLL << 32) | (long long)(0xFFFF0000u + s));
    const double PINV = __longlong_as_double(0x7FE0000000000000LL);
    const double BIG  = __longlong_as_double((0x7F7FFFFFLL << 32) | 0xFFFFFFF0LL);

    double p0 = PINV, p1 = PINV;
    int pcnt = 0;
    float kthr = __uint_as_float((u32)(__double_as_longlong(a[K_ - 1]) >> 32));

#pragma unroll 1
    for (int c0 = seg * SEGLEN; c0 < (seg + 1) * SEGLEN; c0 += 64) {
        __syncthreads();
        if (t < 64) {
#pragma unroll
            for (int d = 0; d < D; ++d) sCT[d][t] = xc[(size_t)(c0 + t) * D + d];
        }
        __syncthreads();

        float acc[4][4] = {};
#pragma unroll
        for (int kk = 0; kk < D; ++kk) {
            float4 aq = *(const float4*)&sQT[kk][ty * 4];
            float4 bc = *(const float4*)&sCT[kk][tx * 4];
            acc[0][0] = fmaf(aq.x, bc.x, acc[0][0]); acc[0][1] = fmaf(aq.x, bc.y, acc[0][1]);
            acc[0][2] = fmaf(aq.x, bc.z, acc[0][2]); acc[0][3] = fmaf(aq.x, bc.w, acc[0][3]);
            acc[1][0] = fmaf(aq.y, bc.x, acc[1][0]); acc[1][1] = fmaf(aq.y, bc.y, acc[1][1]);
            acc[1][2] = fmaf(aq.y, bc.z, acc[1][2]); acc[1][3] = fmaf(aq.y, bc.w, acc[1][3]);
            acc[2][0] = fmaf(aq.z, bc.x, acc[2][0]); acc[2][1] = fmaf(aq.z, bc.y, acc[2][1]);
            acc[2][2] = fmaf(aq.z, bc.z, acc[2][2]); acc[2][3] = fmaf(aq.z, bc.w, acc[2][3]);
            acc[3][0] = fmaf(aq.w, bc.x, acc[3][0]); acc[3][1] = fmaf(aq.w, bc.y, acc[3][1]);
            acc[3][2] = fmaf(aq.w, bc.z, acc[3][2]); acc[3][3] = fmaf(aq.w, bc.w, acc[3][3]);
        }
        float cd2j[4];
#pragma unroll
        for (int j = 0; j < 4; ++j) cd2j[j] = d2b[c0 + tx * 4 + j];
        bool diag = (q0 == c0);
#pragma unroll
        for (int i = 0; i < 4; ++i) {
            float dd[4];
#pragma unroll
            for (int j = 0; j < 4; ++j) {
                float v = (qd2i[i] + cd2j[j]) - 2.f * acc[i][j];
                if (diag && (ty * 4 + i == tx * 4 + j)) v += 1e10f;
                dd[j] = fmaxf(v, 0.f);
            }
            *(float4*)&sD[ty * 4 + i][tx * 4] = make_float4(dd[0], dd[1], dd[2], dd[3]);
        }
        __syncthreads();

#pragma unroll
        for (int u = 0; u < 16; ++u) {
            int c = cs + u * 4;
            float dv = sD[qs][c];
            if (__any(dv <= kthr)) {            // conservative f32 pre-gate
                u64 kb = ((u64)__float_as_uint(dv) << 32) | (u32)(c0 + c);
                double key = __longlong_as_double((long long)kb);
                bool pass = key < a[K_ - 1];
                p1 = pass ? p0 : p1;
                p0 = pass ? key : p0;
                pcnt = pass ? pcnt + 1 : pcnt;
                if (__any(pcnt >= 2)) {
                    double carry = p1;
#pragma unroll
                    for (int s = 0; s < K_; ++s) {
                        double as = a[s];
                        a[s]  = fmin(carry, as);
                        carry = fmax(carry, as);
                    }
                    carry = p0;
#pragma unroll
                    for (int s = 0; s < K_; ++s) {
                        double as = a[s];
                        a[s]  = fmin(carry, as);
                        carry = fmax(carry, as);
                    }
                    p0 = PINV; p1 = PINV; pcnt = 0;
                    kthr = __uint_as_float((u32)(__double_as_longlong(a[K_ - 1]) >> 32));
                }
            }
        }
    }
    {   // final flush
        double carry = p1;
#pragma unroll
        for (int s = 0; s < K_; ++s) {
            double as = a[s];
            a[s]  = fmin(carry, as);
            carry = fmax(carry, as);
        }
        carry = p0;
#pragma unroll
        for (int s = 0; s < K_; ++s) {
            double as = a[s];
            a[s]  = fmin(carry, as);
            carry = fmax(carry, as);
        }
    }

    // pop-min merge of the 4 sub-streams; write sorted segment top-20 keys
    u64* op = segl + ((size_t)(b * P_ + q0 + qs) * NSEG + seg) * K_;
#pragma unroll 1
    for (int k = 0; k < K_; ++k) {
        double v = a[0];
        double v1 = __shfl_xor(v, 1);
        v = fmin(v, v1);
        double v2 = __shfl_xor(v, 2);
        v = fmin(v, v2);
        bool win = (__double_as_longlong(a[0]) == __double_as_longlong(v));
#pragma unroll
        for (int s = 0; s < K_ - 1; ++s) a[s] = win ? a[s + 1] : a[s];
        a[K_ - 1] = win ? BIG : a[K_ - 1];
        if (cs == 0) op[k] = (u64)__double_as_longlong(v);
    }
}

// ---------------------------------------------------------------- fused knn (D=64) via MFMA, segmented
__global__ __launch_bounds__(256) void knnm64_kernel(const u16* __restrict__ xh,
                                                     const u16* __restrict__ xm,
                                                     const u16* __restrict__ xl,
                                                     const float* __restrict__ d2,
                                                     u64* __restrict__ segl) {
    __shared__ u16 sH[64 * 64];      // elem (r,k) at byte r*128 + ((k*2) ^ ((r&7)<<4))
    __shared__ u16 sM[64 * 64];
    __shared__ u16 sL[64 * 64];
    __shared__ float sd2[P_];        // 16 KB

    int b = blockIdx.y;
    int q0 = blockIdx.x * 64;
    int seg = blockIdx.z;
    const u16* xhb = xh + (size_t)b * P_ * 64;
    const u16* xmb = xm + (size_t)b * P_ * 64;
    const u16* xlb = xl + (size_t)b * P_ * 64;
    const float* d2b = d2 + (size_t)b * P_;

    int t = threadIdx.x, w = t >> 6, ln = t & 63;
    int q  = ln & 15;                // query col within wave tile
    int ss = ln >> 4;                // sub-stream / k-offset group 0..3

    for (int i = t; i < P_ / 4; i += 256)
        ((float4*)sd2)[i] = ((const float4*)d2b)[i];

    int qrow = q0 + w * 16 + q;
    bf16x8 qh[2], qm[2], ql[2];
#pragma unroll
    for (int kt = 0; kt < 2; ++kt) {
        size_t off = (size_t)qrow * 64 + kt * 32 + ss * 8;
        qh[kt] = *(const bf16x8*)(xhb + off);
        qm[kt] = *(const bf16x8*)(xmb + off);
        ql[kt] = *(const bf16x8*)(xlb + off);
    }

    __syncthreads();   // sd2 ready
    float qd2 = sd2[qrow];

    double a[K_];
#pragma unroll
    for (int s = 0; s < K_; ++s)
        a[s] = __longlong_as_double((0x7F7FFFFFLL << 32) | (long long)(0xFFFF0000u + s));
    const double BIG  = __longlong_as_double((0x7F7FFFFFLL << 32) | 0xFFFFFFF0LL);
    const double PINV = __longlong_as_double(0x7FE0000000000000LL);

    double p0 = PINV, p1 = PINV;
    int pcnt = 0;
    float kthr = __uint_as_float((u32)(__double_as_longlong(a[K_ - 1]) >> 32));

    int sr = t >> 2;
    int sk2 = (t & 3) * 32;
    int sbase = sr * 128, sswz = (sr & 7) << 4;
    size_t sgof = (size_t)sr * 64 + (t & 3) * 16;

#pragma unroll 1
    for (int c0 = seg * SEGLEN; c0 < (seg + 1) * SEGLEN; c0 += 64) {
        __syncthreads();
        {
            size_t g = (size_t)c0 * 64 + sgof;
            bf16x8 h0 = *(const bf16x8*)(xhb + g);
            bf16x8 h1 = *(const bf16x8*)(xhb + g + 8);
            bf16x8 m0 = *(const bf16x8*)(xmb + g);
            bf16x8 m1 = *(const bf16x8*)(xmb + g + 8);
            bf16x8 l0 = *(const bf16x8*)(xlb + g);
            bf16x8 l1 = *(const bf16x8*)(xlb + g + 8);
            *(bf16x8*)((char*)sH + sbase + (sk2 ^ sswz)) = h0;
            *(bf16x8*)((char*)sH + sbase + ((sk2 + 16) ^ sswz)) = h1;
            *(bf16x8*)((char*)sM + sbase + (sk2 ^ sswz)) = m0;
            *(bf16x8*)((char*)sM + sbase + ((sk2 + 16) ^ sswz)) = m1;
            *(bf16x8*)((char*)sL + sbase + (sk2 ^ sswz)) = l0;
            *(bf16x8*)((char*)sL + sbase + ((sk2 + 16) ^ sswz)) = l1;
        }
        __syncthreads();

        f32x4 acc[4];
#pragma unroll
        for (int nt = 0; nt < 4; ++nt) {
            acc[nt] = (f32x4){0.f, 0.f, 0.f, 0.f};
            int r = nt * 16 + q;
            int base = r * 128, swz = (r & 7) << 4;
#pragma unroll
            for (int kt = 0; kt < 2; ++kt) {
                int k2 = kt * 64 + ss * 16;
                bf16x8 ch = *(const bf16x8*)((char*)sH + base + (k2 ^ swz));
                bf16x8 cm = *(const bf16x8*)((char*)sM + base + (k2 ^ swz));
                bf16x8 cl = *(const bf16x8*)((char*)sL + base + (k2 ^ swz));
                acc[nt] = __builtin_amdgcn_mfma_f32_16x16x32_bf16(cm, qm[kt], acc[nt], 0, 0, 0);
                acc[nt] = __builtin_amdgcn_mfma_f32_16x16x32_bf16(cl, qh[kt], acc[nt], 0, 0, 0);
                acc[nt] = __builtin_amdgcn_mfma_f32_16x16x32_bf16(ch, ql[kt], acc[nt], 0, 0, 0);
                acc[nt] = __builtin_amdgcn_mfma_f32_16x16x32_bf16(cm, qh[kt], acc[nt], 0, 0, 0);
                acc[nt] = __builtin_amdgcn_mfma_f32_16x16x32_bf16(ch, qm[kt], acc[nt], 0, 0, 0);
                acc[nt] = __builtin_amdgcn_mfma_f32_16x16x32_bf16(ch, qh[kt], acc[nt], 0, 0, 0);
            }
        }

#pragma unroll
        for (int nt = 0; nt < 4; ++nt) {
#pragma unroll
            for (int r = 0; r < 4; ++r) {
                int cID = c0 + nt * 16 + ss * 4 + r;
                float dv = (qd2 + sd2[cID]) - 2.f * acc[nt][r];
                if (cID == qrow) dv += 1e10f;
                dv = fmaxf(dv, 0.f);
                if (__any(dv <= kthr)) {        // conservative f32 pre-gate
                    u64 kb = ((u64)__float_as_uint(dv) << 32) | (u32)cID;
                    double key = __longlong_as_double((long long)kb);
                    bool pass = key < a[K_ - 1];
                    p1 = pass ? p0 : p1;
                    p0 = pass ? key : p0;
                    pcnt = pass ? pcnt + 1 : pcnt;
                    if (__any(pcnt >= 2)) {
                        double carry = p1;
#pragma unroll
                        for (int s = 0; s < K_; ++s) {
                            double as = a[s];
                            a[s]  = fmin(carry, as);
                            carry = fmax(carry, as);
                        }
                        carry = p0;
#pragma unroll
                        for (int s = 0; s < K_; ++s) {
                            double as = a[s];
                            a[s]  = fmin(carry, as);
                            carry = fmax(carry, as);
                        }
                        p0 = PINV; p1 = PINV; pcnt = 0;
                        kthr = __uint_as_float((u32)(__double_as_longlong(a[K_ - 1]) >> 32));
                    }
                }
            }
        }
    }
    {   // final flush
        double carry = p1;
#pragma unroll
        for (int s = 0; s < K_; ++s) {
            double as = a[s];
            a[s]  = fmin(carry, as);
            carry = fmax(carry, as);
        }
        carry = p0;
#pragma unroll
        for (int s = 0; s < K_; ++s) {
            double as = a[s];
            a[s]  = fmin(carry, as);
            carry = fmax(carry, as);
        }
    }

    // pop-min merge of 4 sub-streams (lanes q, q+16, q+32, q+48); write sorted keys
    u64* op = segl + ((size_t)(b * P_ + qrow) * NSEG + seg) * K_;
#pragma unroll 1
    for (int k = 0; k < K_; ++k) {
        double v = a[0];
        double v1 = __shfl_xor(v, 16);
        v = fmin(v, v1);
        double v2 = __shfl_xor(v, 32);
        v = fmin(v, v2);
        bool win = (__double_as_longlong(a[0]) == __double_as_longlong(v));
#pragma unroll
        for (int s = 0; s < K_ - 1; ++s) a[s] = win ? a[s + 1] : a[s];
        a[K_ - 1] = win ? BIG : a[K_ - 1];
        if (ss == 0) op[k] = (u64)__double_as_longlong(v);
    }
}

// ---------------------------------------------------------------- merge 2 segment lists (40 unique keys)
__global__ __launch_bounds__(256) void knn_merge2_kernel(const u64* __restrict__ segl,
                                                         int* __restrict__ idx) {
    int w = threadIdx.x >> 6, lane = threadIdx.x & 63;
    int q = blockIdx.x * 4 + w;
    const u64* src = segl + (size_t)q * (NSEG * K_);
    u64 k0 = (lane < NSEG * K_) ? src[lane] : ~0ULL;
    int base = (q >> 12) << 12;
    int* op = idx + (size_t)q * K_;
#pragma unroll 1
    for (int k = 0; k < K_; ++k) {
        u64 m = k0;
#pragma unroll
        for (int s = 1; s < 64; s <<= 1) {
            u64 o = __shfl_xor(m, s);
            m = o < m ? o : m;
        }
        if (k0 == m) k0 = ~0ULL;
        if (lane == 0) op[k] = base + (int)(m & 0xFFFFFFFFu);
    }
}

// ---------------------------------------------------------------- pack W[128,64] -> Wpk[64,128], bpk
__global__ __launch_bounds__(128) void pack_kernel(const float* __restrict__ W,
                                                   const float* __restrict__ b,
                                                   float* __restrict__ Wpk,
                                                   float* __restrict__ bpk) {
    int t = blockIdx.x * 128 + threadIdx.x;
    int d = t >> 7, h2 = t & 127;
    Wpk[t] = (h2 < 64) ? W[d * 64 + h2] : W[(64 + d) * 64 + (h2 - 64)];
    if (t < 128) bpk[t] = (t < 64) ? b[t] : 0.f;
}

// ---------------------------------------------------------------- layer-1 UV (D=3, direct)
__global__ __launch_bounds__(256) void uv3_kernel(const float* __restrict__ x,
                                                  const float* __restrict__ W,
                                                  const float* __restrict__ b,
                                                  float* __restrict__ UV) {
    int t = blockIdx.x * 256 + threadIdx.x;
    int p = t >> 7, h2 = t & 127;
    float x0 = x[p * 3], x1 = x[p * 3 + 1], x2 = x[p * 3 + 2];
    float r;
    if (h2 < 64) {
        r = b[h2] + x0 * W[h2] + x1 * W[64 + h2] + x2 * W[128 + h2];
    } else {
        int h = h2 - 64;
        r = x0 * W[192 + h] + x1 * W[256 + h] + x2 * W[320 + h];
    }
    UV[t] = r;
}

// ---------------------------------------------------------------- edge max
__global__ __launch_bounds__(256) void edgemax_kernel(const float* __restrict__ UV,
                                                      const int* __restrict__ idx,
                                                      float* __restrict__ xout) {
    int wv = threadIdx.x >> 6, lane = threadIdx.x & 63;
    int p = blockIdx.x * 4 + wv;
    const float* uvp = UV + (size_t)p * 128;
    float duv = uvp[lane] - uvp[64 + lane];
    const int* ip = idx + (size_t)p * K_;
    int jj[K_];
#pragma unroll
    for (int k = 0; k < K_; ++k) jj[k] = ip[k];
    float m = -3.4e38f;
#pragma unroll
    for (int k = 0; k < K_; ++k) {
        float vj = UV[(size_t)jj[k] * 128 + 64 + lane];
        float t = duv + vj;
        m = fmaxf(m, fmaxf(t, NEG_SLOPE * t));
    }
    xout[(size_t)p * H_ + lane] = m;
}

// ---------------------------------------------------------------- GEMM 64x64 f32 (UV + Wo)
__global__ __launch_bounds__(256) void gemm_kernel(const float* __restrict__ A1,
                                                   const float* __restrict__ Wm,
                                                   const float* __restrict__ bias,
                                                   float* __restrict__ Cm,
                                                   int M, int N, int Kd, int leaky) {
    __shared__ float sA[32][68];
    __shared__ float sB[32][68];

    int tid = threadIdx.x;
    int row0 = blockIdx.x * 64, col0 = blockIdx.y * 64;
    int tx = tid & 15, ty = tid >> 4;

    int lr  = tid >> 2;
    int lk4 = (tid & 3) * 4;
    int lkb = tid >> 4;
    int lnb = (tid & 15) * 4;

    float acc[4][4] = {};

    for (int k0 = 0; k0 < Kd; k0 += 32) {
        int arow = row0 + lr;
#pragma unroll
        for (int h = 0; h < 32; h += 16) {
            int kk = k0 + lk4 + h;
            const float* src = A1 + (size_t)arow * Kd + kk;
            float4 av = *(const float4*)src;
            sA[lk4 + h + 0][lr] = av.x; sA[lk4 + h + 1][lr] = av.y;
            sA[lk4 + h + 2][lr] = av.z; sA[lk4 + h + 3][lr] = av.w;
        }
        int bcol = col0 + lnb;
#pragma unroll
        for (int h = 0; h < 32; h += 16) {
            float4 bv = make_float4(0.f, 0.f, 0.f, 0.f);
            if (bcol < N) bv = *(const float4*)(Wm + (size_t)(k0 + lkb + h) * N + bcol);
            *(float4*)&sB[lkb + h][lnb] = bv;
        }
        __syncthreads();

#pragma unroll
        for (int kk2 = 0; kk2 < 32; ++kk2) {
            float4 a = *(const float4*)&sA[kk2][ty * 4];
            float4 bb = *(const float4*)&sB[kk2][tx * 4];
            acc[0][0] = fmaf(a.x, bb.x, acc[0][0]); acc[0][1] = fmaf(a.x, bb.y, acc[0][1]);
            acc[0][2] = fmaf(a.x, bb.z, acc[0][2]); acc[0][3] = fmaf(a.x, bb.w, acc[0][3]);
            acc[1][0] = fmaf(a.y, bb.x, acc[1][0]); acc[1][1] = fmaf(a.y, bb.y, acc[1][1]);
            acc[1][2] = fmaf(a.y, bb.z, acc[1][2]); acc[1][3] = fmaf(a.y, bb.w, acc[1][3]);
            acc[2][0] = fmaf(a.z, bb.x, acc[2][0]); acc[2][1] = fmaf(a.z, bb.y, acc[2][1]);
            acc[2][2] = fmaf(a.z, bb.z, acc[2][2]); acc[2][3] = fmaf(a.z, bb.w, acc[2][3]);
            acc[3][0] = fmaf(a.w, bb.x, acc[3][0]); acc[3][1] = fmaf(a.w, bb.y, acc[3][1]);
            acc[3][2] = fmaf(a.w, bb.z, acc[3][2]); acc[3][3] = fmaf(a.w, bb.w, acc[3][3]);
        }
        __syncthreads();
    }

    for (int i = 0; i < 4; ++i) {
        int row = row0 + ty * 4 + i;
        for (int j = 0; j < 4; ++j) {
            int col = col0 + tx * 4 + j;
            if (col < N) {
                float v = acc[i][j] + bias[col];
                if (leaky) v = v > 0.f ? v : NEG_SLOPE * v;
                Cm[(size_t)row * N + col] = v;
            }
        }
    }
}

// ---------------------------------------------------------------- head: f32 W[K,N] -> bf16 WT[N,K]
__global__ __launch_bounds__(256) void wcvtT_kernel(const float* __restrict__ W,
                                                    u16* __restrict__ WT, int K, int N) {
    int t = blockIdx.x * 256 + threadIdx.x;
    if (t >= K * N) return;
    int k = t / N, n = t % N;
    WT[(size_t)n * K + k] = f2bf(W[t]);
}

// ---------------------------------------------------------------- head: concat chunk -> bf16 [4096,192]
__global__ __launch_bounds__(256) void cvt_cat_kernel(const float* __restrict__ x1,
                                                      const float* __restrict__ x2,
                                                      const float* __restrict__ x3,
                                                      u16* __restrict__ A0) {
    int t = blockIdx.x * 256 + threadIdx.x;     // 4096*48
    int r = t / 48, c4 = (t % 48) * 4;
    const float* src = (c4 < 64) ? (x1 + (size_t)r * 64 + c4)
                     : (c4 < 128) ? (x2 + (size_t)r * 64 + (c4 - 64))
                                  : (x3 + (size_t)r * 64 + (c4 - 128));
    float4 v = *(const float4*)src;
    u16* dst = A0 + (size_t)r * 192 + c4;
    dst[0] = f2bf(v.x); dst[1] = f2bf(v.y); dst[2] = f2bf(v.z); dst[3] = f2bf(v.w);
}

// ---------------------------------------------------------------- MFMA GEMM head
template <int KD, int OUT_BF16>
__global__ __launch_bounds__(256) void gemm_mfma_kernel(const u16* __restrict__ A,
                                                        const u16* __restrict__ BT,
                                                        const float* __restrict__ bias,
                                                        void* __restrict__ Cout,
                                                        int N, int leaky) {
    __shared__ u16 sA[128 * 64];   // elem (r,k) at byte r*128 + ((k*2) ^ ((r&7)<<4))
    __shared__ u16 sB[128 * 64];

    int t = threadIdx.x;
    int wave = t >> 6, lane = t & 63;
    int wm = wave >> 1, wn = wave & 1;
    int row0 = blockIdx.x * 128;
    int col0 = blockIdx.y * 128;

    f32x4 acc[4][4] = {};

    for (int k0 = 0; k0 < KD; k0 += 64) {
        __syncthreads();
#pragma unroll
        for (int i = 0; i < 4; ++i) {
            int li = t + i * 256;
            int r = li >> 3;
            int kc = (li & 7) * 8;
            bf16x8 v = *(const bf16x8*)(A + (size_t)(row0 + r) * KD + k0 + kc);
            *(bf16x8*)((char*)sA + r * 128 + ((kc * 2) ^ ((r & 7) << 4))) = v;
        }
#pragma unroll
        for (int i = 0; i < 4; ++i) {
            int li = t + i * 256;
            int n = li >> 3;
            int kc = (li & 7) * 8;
            bf16x8 v = *(const bf16x8*)(BT + (size_t)(col0 + n) * KD + k0 + kc);
            *(bf16x8*)((char*)sB + n * 128 + ((kc * 2) ^ ((n & 7) << 4))) = v;
        }
        __syncthreads();

#pragma unroll
        for (int kk = 0; kk < 2; ++kk) {
            int kb = kk * 64 + (lane >> 4) * 16;
            bf16x8 af[4], bfr[4];
#pragma unroll
            for (int mi = 0; mi < 4; ++mi) {
                int r = wm * 64 + mi * 16 + (lane & 15);
                af[mi] = *(const bf16x8*)((char*)sA + r * 128 + (kb ^ ((r & 7) << 4)));
            }
#pragma unroll
            for (int ni = 0; ni < 4; ++ni) {
                int n = wn * 64 + ni * 16 + (lane & 15);
                bfr[ni] = *(const bf16x8*)((char*)sB + n * 128 + (kb ^ ((n & 7) << 4)));
            }
#pragma unroll
            for (int mi = 0; mi < 4; ++mi)
#pragma unroll
                for (int ni = 0; ni < 4; ++ni)
                    acc[mi][ni] = __builtin_amdgcn_mfma_f32_16x16x32_bf16(
                        af[mi], bfr[ni], acc[mi][ni], 0, 0, 0);
        }
    }

#pragma unroll
    for (int ni = 0; ni < 4; ++ni) {
        int col = col0 + wn * 64 + ni * 16 + (lane & 15);
        float bs = bias[col];
#pragma unroll
        for (int mi = 0; mi < 4; ++mi) {
#pragma unroll
            for (int r = 0; r < 4; ++r) {
                int row = row0 + wm * 64 + mi * 16 + (lane >> 4) * 4 + r;
                float v = acc[mi][ni][r] + bs;
                if (leaky) v = v > 0.f ? v : NEG_SLOPE * v;
                if (OUT_BF16)
                    ((u16*)Cout)[(size_t)row * N + col] = f2bf(v);
                else
                    ((float*)Cout)[(size_t)row * N + col] = v;
            }
        }
    }
}

// ---------------------------------------------------------------- log_softmax rows of 40
__global__ __launch_bounds__(256) void lsm_kernel(float* __restrict__ out) {
    int row = blockIdx.x * 4 + (threadIdx.x >> 6);
    int lane = threadIdx.x & 63;
    float v = -3.4e38f;
    if (lane < C_) v = out[(size_t)row * C_ + lane];
    float m = v;
#pragma unroll
    for (int s = 1; s < 64; s <<= 1) m = fmaxf(m, __shfl_xor(m, s));
    float e = (lane < C_) ? expf(v - m) : 0.f;
    float sum = e;
#pragma unroll
    for (int s = 1; s < 64; s <<= 1) sum += __shfl_xor(sum, s);
    if (lane < C_) out[(size_t)row * C_ + lane] = v - m - logf(sum);
}

// ----------------------------------------------------------------
extern "C" void kernel_launch(void* const* d_in, const int* in_sizes, int n_in,
                              void* d_out, int out_size, void* d_ws, size_t ws_size,
                              hipStream_t stream) {
    const float* x   = (const float*)d_in[0];
    const float* W1  = (const float*)d_in[2];
    const float* b1  = (const float*)d_in[3];
    const float* W2  = (const float*)d_in[4];
    const float* b2  = (const float*)d_in[5];
    const float* W3  = (const float*)d_in[6];
    const float* b3  = (const float*)d_in[7];
    const float* Wl  = (const float*)d_in[8];
    const float* bl  = (const float*)d_in[9];
    const float* Wm1 = (const float*)d_in[10];
    const float* bm1 = (const float*)d_in[11];
    const float* Wm2 = (const float*)d_in[12];
    const float* bm2 = (const float*)d_in[13];
    const float* Wo  = (const float*)d_in[14];
    const float* bo  = (const float*)d_in[15];
    float* out = (float*)d_out;

    // ---- workspace (max 50,987,008 B — proven footprint) ----
    char* ws = (char*)d_ws;
    float* x1   = (float*)(ws);                       // 8 MB
    float* x2   = (float*)(ws + 8388608);             // 8 MB
    float* x3   = (float*)(ws + 16777216);            // 8 MB
    int*   idx  = (int*)  (ws + 25165824);            // 2.62 MB
    float* d2   = (float*)(ws + 27787264);            // 128 KB
    // region 27,918,336 .. 50,987,008 (23,068,672 B), phase-aliased (stream-ordered):
    char* hb = ws + 27918336;
    // knn phase: h/m/l splits (12 MB) + segl (10.49 MB)
    u16*   xhs  = (u16*)(hb);                         // 4 MB
    u16*   xms  = (u16*)(hb + 4194304);               // 4 MB
    u16*   xls  = (u16*)(hb + 8388608);               // 4 MB
    u64*   segl = (u64*)(hb + 12582912);              // 32768*2*20*8 = 10,485,760
    // edge phase:
    float* UV   = (float*)(hb);                       // 16 MB
    float* Wpk  = (float*)(ws + 44695552);
    float* bpk  = (float*)(ws + 44728320);
    // head phase:
    u16*   WlT   = (u16*)(hb);                        // [1024][192]
    u16*   Wm1T  = (u16*)(hb + 393216);               // [256][1024]
    u16*   Wm2T  = (u16*)(hb + 917504);               // [128][256]
    u16*   A0bf  = (u16*)(hb + 983040);               // [4096][192]
    u16*   act1  = (u16*)(hb + 2555904);              // [4096][1024]
    u16*   act2  = (u16*)(hb + 10944512);             // [4096][256]
    float* act3  = (float*)(hb + 13041664);           // [4096][128] f32

    // ---- layer 1 (D=3): vector fused knn, 2 segments
    d2_kernel<3><<<NPT / 256, 256, 0, stream>>>(x, d2);
    knnf_kernel<3><<<dim3(P_ / 64, B_, NSEG), 256, 0, stream>>>(x, d2, segl);
    knn_merge2_kernel<<<NPT / 4, 256, 0, stream>>>(segl, idx);
    uv3_kernel<<<NPT * 128 / 256, 256, 0, stream>>>(x, W1, b1, UV);
    edgemax_kernel<<<NPT / 4, 256, 0, stream>>>(UV, idx, x1);
    // ---- layer 2 (D=64): MFMA fused knn, 2 segments
    d2_kernel<64><<<NPT / 256, 256, 0, stream>>>(x1, d2);
    cvt3_kernel<<<NPT * 64 / 256, 256, 0, stream>>>(x1, xhs, xms, xls);
    knnm64_kernel<<<dim3(P_ / 64, B_, NSEG), 256, 0, stream>>>(xhs, xms, xls, d2, segl);
    knn_merge2_kernel<<<NPT / 4, 256, 0, stream>>>(segl, idx);
    pack_kernel<<<64, 128, 0, stream>>>(W2, b2, Wpk, bpk);
    gemm_kernel<<<dim3(NPT / 64, 2), 256, 0, stream>>>(x1, Wpk, bpk, UV, NPT, 128, 64, 0);
    edgemax_kernel<<<NPT / 4, 256, 0, stream>>>(UV, idx, x2);
    // ---- layer 3 (D=64)
    d2_kernel<64><<<NPT / 256, 256, 0, stream>>>(x2, d2);
    cvt3_kernel<<<NPT * 64 / 256, 256, 0, stream>>>(x2, xhs, xms, xls);
    knnm64_kernel<<<dim3(P_ / 64, B_, NSEG), 256, 0, stream>>>(xhs, xms, xls, d2, segl);
    knn_merge2_kernel<<<NPT / 4, 256, 0, stream>>>(segl, idx);
    pack_kernel<<<64, 128, 0, stream>>>(W3, b3, Wpk, bpk);
    gemm_kernel<<<dim3(NPT / 64, 2), 256, 0, stream>>>(x2, Wpk, bpk, UV, NPT, 128, 64, 0);
    edgemax_kernel<<<NPT / 4, 256, 0, stream>>>(UV, idx, x3);

    // ---- MLP head: bf16 MFMA (Wl, Wm1, Wm2) + f32 (Wo)
    wcvtT_kernel<<<(192 * 1024 + 255) / 256, 256, 0, stream>>>(Wl, WlT, 192, 1024);
    wcvtT_kernel<<<(1024 * 256 + 255) / 256, 256, 0, stream>>>(Wm1, Wm1T, 1024, 256);
    wcvtT_kernel<<<(256 * 128 + 255) / 256, 256, 0, stream>>>(Wm2, Wm2T, 256, 128);

    for (int c = 0; c < 8; ++c) {
        size_t r0 = (size_t)c * 4096;
        cvt_cat_kernel<<<4096 * 48 / 256, 256, 0, stream>>>(x1 + r0 * 64, x2 + r0 * 64,
                                                            x3 + r0 * 64, A0bf);
        gemm_mfma_kernel<192, 1><<<dim3(32, 8), 256, 0, stream>>>(A0bf, WlT, bl, act1, 1024, 1);
        gemm_mfma_kernel<1024, 1><<<dim3(32, 2), 256, 0, stream>>>(act1, Wm1T, bm1, act2, 256, 1);
        gemm_mfma_kernel<256, 0><<<dim3(32, 1), 256, 0, stream>>>(act2, Wm2T, bm2, act3, 128, 1);
        gemm_kernel<<<dim3(64, 1), 256, 0, stream>>>(act3, Wo, bo, out + r0 * C_, 4096, 40, 128, 0);
    }
    lsm_kernel<<<NPT / 4, 256, 0, stream>>>(out);
}

// Round 13
// 1272.333 us; speedup vs baseline: 1.2127x; 1.2127x over previous
//
#include <hip/hip_runtime.h>
#include <cstddef>
#include <cstdint>

constexpr int B_ = 8, P_ = 4096, K_ = 20, H_ = 64, C_ = 40;
constexpr int NPT = B_ * P_;
#define NEG_SLOPE 0.2f

typedef unsigned long long u64;
typedef unsigned int u32;
typedef unsigned short u16;
typedef __attribute__((ext_vector_type(8))) short bf16x8;
typedef __attribute__((ext_vector_type(4))) float f32x4;

__device__ inline u16 f2bf(float v) {   // round-to-nearest-even bf16
    u32 bits = __float_as_uint(v);
    return (u16)((bits + 0x7FFFu + ((bits >> 16) & 1)) >> 16);
}
__device__ inline float bf2f(u16 h) { return __uint_as_float((u32)h << 16); }

// ---------------------------------------------------------------- d2 = sum(x*x)
template <int D>
__global__ __launch_bounds__(256) void d2_kernel(const float* __restrict__ x,
                                                 float* __restrict__ d2) {
    int i = blockIdx.x * 256 + threadIdx.x;
    if (i >= NPT) return;
    const float* r = x + (size_t)i * D;
    float s = 0.f;
    if constexpr (D % 4 == 0) {
#pragma unroll
        for (int d = 0; d < D; d += 4) {
            float4 v = *(const float4*)(r + d);
            s += v.x * v.x + v.y * v.y + v.z * v.z + v.w * v.w;
        }
    } else {
#pragma unroll
        for (int d = 0; d < D; ++d) { float v = r[d]; s += v * v; }
    }
    d2[i] = s;
}

// ---------------------------------------------------------------- split x (f32) -> h,m,l bf16
__global__ __launch_bounds__(256) void cvt3_kernel(const float* __restrict__ x,
                                                   u16* __restrict__ xh,
                                                   u16* __restrict__ xm,
                                                   u16* __restrict__ xl) {
    int i = blockIdx.x * 256 + threadIdx.x;   // NPT*64 elems
    float v = x[i];
    u16 h = f2bf(v);
    float r1 = v - bf2f(h);
    u16 m = f2bf(r1);
    float r2 = r1 - bf2f(m);
    xh[i] = h; xm[i] = m; xl[i] = f2bf(r2);
}

// ---------------------------------------------------------------- layer-1 fused knn (D=3)
// R9-proven structure + coarse f32 pre-gate on the 16 per-chunk evals.
template <int D>
__global__ __launch_bounds__(256) void knnf_kernel(const float* __restrict__ x,
                                                   const float* __restrict__ d2,
                                                   int* __restrict__ idx) {
    __shared__ float sQT[D][68];
    __shared__ float sCT[D][68];
    __shared__ float sD[64][68];

    int b = blockIdx.y;
    int q0 = blockIdx.x * 64;
    const float* xc  = x + (size_t)b * P_ * D;
    const float* d2b = d2 + (size_t)b * P_;

    int t = threadIdx.x;
    int ty = t >> 4, tx = t & 15;
    int w = t >> 6, ln = t & 63;
    int qs = w * 16 + (ln >> 2);
    int cs = ln & 3;

    if (t < 64) {
#pragma unroll
        for (int d = 0; d < D; ++d) sQT[d][t] = xc[(size_t)(q0 + t) * D + d];
    }
    float qd2i[4];
#pragma unroll
    for (int i = 0; i < 4; ++i) qd2i[i] = d2b[q0 + ty * 4 + i];

    double a[K_];
#pragma unroll
    for (int s = 0; s < K_; ++s)
        a[s] = __longlong_as_double((0x7F7FFFFFLL << 32) | (long long)(0xFFFF0000u + s));
    const double PINV = __longlong_as_double(0x7FE0000000000000LL);
    const double BIG  = __longlong_as_double((0x7F7FFFFFLL << 32) | 0xFFFFFFF0LL);

    double p0 = PINV, p1 = PINV;
    int pcnt = 0;
    float kthr = __uint_as_float(0x7F7FFFFFu);   // FLT_MAX

#pragma unroll 1
    for (int c0 = 0; c0 < P_; c0 += 64) {
        __syncthreads();
        if (t < 64) {
#pragma unroll
            for (int d = 0; d < D; ++d) sCT[d][t] = xc[(size_t)(c0 + t) * D + d];
        }
        __syncthreads();

        float acc[4][4] = {};
#pragma unroll
        for (int kk = 0; kk < D; ++kk) {
            float4 aq = *(const float4*)&sQT[kk][ty * 4];
            float4 bc = *(const float4*)&sCT[kk][tx * 4];
            acc[0][0] = fmaf(aq.x, bc.x, acc[0][0]); acc[0][1] = fmaf(aq.x, bc.y, acc[0][1]);
            acc[0][2] = fmaf(aq.x, bc.z, acc[0][2]); acc[0][3] = fmaf(aq.x, bc.w, acc[0][3]);
            acc[1][0] = fmaf(aq.y, bc.x, acc[1][0]); acc[1][1] = fmaf(aq.y, bc.y, acc[1][1]);
            acc[1][2] = fmaf(aq.y, bc.z, acc[1][2]); acc[1][3] = fmaf(aq.y, bc.w, acc[1][3]);
            acc[2][0] = fmaf(aq.z, bc.x, acc[2][0]); acc[2][1] = fmaf(aq.z, bc.y, acc[2][1]);
            acc[2][2] = fmaf(aq.z, bc.z, acc[2][2]); acc[2][3] = fmaf(aq.z, bc.w, acc[2][3]);
            acc[3][0] = fmaf(aq.w, bc.x, acc[3][0]); acc[3][1] = fmaf(aq.w, bc.y, acc[3][1]);
            acc[3][2] = fmaf(aq.w, bc.z, acc[3][2]); acc[3][3] = fmaf(aq.w, bc.w, acc[3][3]);
        }
        float cd2j[4];
#pragma unroll
        for (int j = 0; j < 4; ++j) cd2j[j] = d2b[c0 + tx * 4 + j];
        bool diag = (q0 == c0);
#pragma unroll
        for (int i = 0; i < 4; ++i) {
            float dd[4];
#pragma unroll
            for (int j = 0; j < 4; ++j) {
                float v = (qd2i[i] + cd2j[j]) - 2.f * acc[i][j];
                if (diag && (ty * 4 + i == tx * 4 + j)) v += 1e10f;
                dd[j] = fmaxf(v, 0.f);
            }
            *(float4*)&sD[ty * 4 + i][tx * 4] = make_float4(dd[0], dd[1], dd[2], dd[3]);
        }
        __syncthreads();

        // read the 16 candidate dists, coarse-gate the whole selection block
        float dvv[16];
        float mn = 3.4e38f;
#pragma unroll
        for (int u = 0; u < 16; ++u) {
            dvv[u] = sD[qs][cs + u * 4];
            mn = fminf(mn, dvv[u]);
        }
        if (__any(mn <= kthr)) {
#pragma unroll
            for (int u = 0; u < 16; ++u) {
                float dv = dvv[u];
                if (__any(dv <= kthr)) {
                    u64 kb = ((u64)__float_as_uint(dv) << 32) | (u32)(c0 + cs + u * 4);
                    double key = __longlong_as_double((long long)kb);
                    bool pass = key < a[K_ - 1];
                    p1 = pass ? p0 : p1;
                    p0 = pass ? key : p0;
                    pcnt = pass ? pcnt + 1 : pcnt;
                    if (__any(pcnt >= 2)) {
                        double carry = p1;
#pragma unroll
                        for (int s = 0; s < K_; ++s) {
                            double as = a[s];
                            a[s]  = fmin(carry, as);
                            carry = fmax(carry, as);
                        }
                        carry = p0;
#pragma unroll
                        for (int s = 0; s < K_; ++s) {
                            double as = a[s];
                            a[s]  = fmin(carry, as);
                            carry = fmax(carry, as);
                        }
                        p0 = PINV; p1 = PINV; pcnt = 0;
                        kthr = __uint_as_float((u32)(__double_as_longlong(a[K_ - 1]) >> 32));
                    }
                }
            }
        }
    }
    {   // final flush
        double carry = p1;
#pragma unroll
        for (int s = 0; s < K_; ++s) {
            double as = a[s];
            a[s]  = fmin(carry, as);
            carry = fmax(carry, as);
        }
        carry = p0;
#pragma unroll
        for (int s = 0; s < K_; ++s) {
            double as = a[s];
            a[s]  = fmin(carry, as);
            carry = fmax(carry, as);
        }
    }

    int* op = idx + ((size_t)(b * P_ + q0 + qs)) * K_;
#pragma unroll 1
    for (int k = 0; k < K_; ++k) {
        double v = a[0];
        double v1 = __shfl_xor(v, 1);
        v = fmin(v, v1);
        double v2 = __shfl_xor(v, 2);
        v = fmin(v, v2);
        bool win = (__double_as_longlong(a[0]) == __double_as_longlong(v));
#pragma unroll
        for (int s = 0; s < K_ - 1; ++s) a[s] = win ? a[s + 1] : a[s];
        a[K_ - 1] = win ? BIG : a[K_ - 1];
        if (cs == 0)
            op[k] = b * P_ + (int)(__double_as_longlong(v) & 0xFFFFFFFFLL);
    }
}

// ---------------------------------------------------------------- fused knn (D=64) via MFMA, v3:
// double-buffered LDS candidate tiles + T14 reg-staged async split (one barrier
// per chunk, staging latency hidden under MFMA) + coarse f32 selection pre-gate.
__global__ __launch_bounds__(256) void knnm64_kernel(const u16* __restrict__ xh,
                                                     const u16* __restrict__ xm,
                                                     const u16* __restrict__ xl,
                                                     const float* __restrict__ d2,
                                                     int* __restrict__ idx) {
    __shared__ u16 sH[2][64 * 64];   // elem (r,k) at byte r*128 + ((k*2) ^ ((r&7)<<4))
    __shared__ u16 sM[2][64 * 64];
    __shared__ u16 sL[2][64 * 64];
    __shared__ float sd2[P_];        // 16 KB  (total LDS 64 KB -> 2 blocks/CU)

    int b = blockIdx.y;
    int q0 = blockIdx.x * 64;
    const u16* xhb = xh + (size_t)b * P_ * 64;
    const u16* xmb = xm + (size_t)b * P_ * 64;
    const u16* xlb = xl + (size_t)b * P_ * 64;
    const float* d2b = d2 + (size_t)b * P_;

    int t = threadIdx.x, w = t >> 6, ln = t & 63;
    int q  = ln & 15;                // query col within wave tile
    int ss = ln >> 4;                // sub-stream / k-offset group 0..3

    // stage d2 into LDS
    for (int i = t; i < P_ / 4; i += 256)
        ((float4*)sd2)[i] = ((const float4*)d2b)[i];

    // query B-fragments, loaded once
    int qrow = q0 + w * 16 + q;
    bf16x8 qh[2], qm[2], ql[2];
#pragma unroll
    for (int kt = 0; kt < 2; ++kt) {
        size_t off = (size_t)qrow * 64 + kt * 32 + ss * 8;
        qh[kt] = *(const bf16x8*)(xhb + off);
        qm[kt] = *(const bf16x8*)(xmb + off);
        ql[kt] = *(const bf16x8*)(xlb + off);
    }

    // staging geometry: thread t handles candidate row sr, 16 elems at (t&3)*16
    int sr = t >> 2;
    int sk2 = (t & 3) * 32;          // byte offset of 16 elems
    int sbase = sr * 128, sswz = (sr & 7) << 4;
    size_t sgof = (size_t)sr * 64 + (t & 3) * 16;

    // prologue: stage chunk 0 into buffer 0
    {
        size_t g = sgof;
        bf16x8 h0 = *(const bf16x8*)(xhb + g), h1 = *(const bf16x8*)(xhb + g + 8);
        bf16x8 m0 = *(const bf16x8*)(xmb + g), m1 = *(const bf16x8*)(xmb + g + 8);
        bf16x8 l0 = *(const bf16x8*)(xlb + g), l1 = *(const bf16x8*)(xlb + g + 8);
        *(bf16x8*)((char*)sH[0] + sbase + (sk2 ^ sswz)) = h0;
        *(bf16x8*)((char*)sH[0] + sbase + ((sk2 + 16) ^ sswz)) = h1;
        *(bf16x8*)((char*)sM[0] + sbase + (sk2 ^ sswz)) = m0;
        *(bf16x8*)((char*)sM[0] + sbase + ((sk2 + 16) ^ sswz)) = m1;
        *(bf16x8*)((char*)sL[0] + sbase + (sk2 ^ sswz)) = l0;
        *(bf16x8*)((char*)sL[0] + sbase + ((sk2 + 16) ^ sswz)) = l1;
    }
    __syncthreads();   // buf0 + sd2 ready
    float qd2 = sd2[qrow];

    double a[K_];
#pragma unroll
    for (int s = 0; s < K_; ++s)
        a[s] = __longlong_as_double((0x7F7FFFFFLL << 32) | (long long)(0xFFFF0000u + s));
    const double BIG  = __longlong_as_double((0x7F7FFFFFLL << 32) | 0xFFFFFFF0LL);
    const double PINV = __longlong_as_double(0x7FE0000000000000LL);

    double p0 = PINV, p1 = PINV;
    int pcnt = 0;
    float kthr = __uint_as_float(0x7F7FFFFFu);   // FLT_MAX

    const int NCH = P_ / 64;
#pragma unroll 1
    for (int ci = 0; ci < NCH; ++ci) {
        int c0 = ci * 64;
        int cur = ci & 1;
        bool hasnext = (ci + 1 < NCH);

        // T14: issue next chunk's global loads into registers EARLY
        bf16x8 nh0, nh1, nm0, nm1, nl0, nl1;
        if (hasnext) {
            size_t g = (size_t)(c0 + 64) * 64 + sgof;
            nh0 = *(const bf16x8*)(xhb + g); nh1 = *(const bf16x8*)(xhb + g + 8);
            nm0 = *(const bf16x8*)(xmb + g); nm1 = *(const bf16x8*)(xmb + g + 8);
            nl0 = *(const bf16x8*)(xlb + g); nl1 = *(const bf16x8*)(xlb + g + 8);
        }

        // ---- MFMA from buf[cur]: candidates as A (rows), queries as B (cols)
        const char* bH = (const char*)sH[cur];
        const char* bM = (const char*)sM[cur];
        const char* bL = (const char*)sL[cur];
        f32x4 acc[4];
#pragma unroll
        for (int nt = 0; nt < 4; ++nt) {
            acc[nt] = (f32x4){0.f, 0.f, 0.f, 0.f};
            int r = nt * 16 + q;
            int base = r * 128, swz = (r & 7) << 4;
#pragma unroll
            for (int kt = 0; kt < 2; ++kt) {
                int k2 = kt * 64 + ss * 16;
                bf16x8 ch = *(const bf16x8*)(bH + base + (k2 ^ swz));
                bf16x8 cm = *(const bf16x8*)(bM + base + (k2 ^ swz));
                bf16x8 cl = *(const bf16x8*)(bL + base + (k2 ^ swz));
                // ascending-magnitude order (same as R10/R11)
                acc[nt] = __builtin_amdgcn_mfma_f32_16x16x32_bf16(cm, qm[kt], acc[nt], 0, 0, 0);
                acc[nt] = __builtin_amdgcn_mfma_f32_16x16x32_bf16(cl, qh[kt], acc[nt], 0, 0, 0);
                acc[nt] = __builtin_amdgcn_mfma_f32_16x16x32_bf16(ch, ql[kt], acc[nt], 0, 0, 0);
                acc[nt] = __builtin_amdgcn_mfma_f32_16x16x32_bf16(cm, qh[kt], acc[nt], 0, 0, 0);
                acc[nt] = __builtin_amdgcn_mfma_f32_16x16x32_bf16(ch, qm[kt], acc[nt], 0, 0, 0);
                acc[nt] = __builtin_amdgcn_mfma_f32_16x16x32_bf16(ch, qh[kt], acc[nt], 0, 0, 0);
            }
        }

        // ---- assemble distances, coarse pre-gate, gated selection
        float dvv[4][4];
        float mn = 3.4e38f;
#pragma unroll
        for (int nt = 0; nt < 4; ++nt) {
#pragma unroll
            for (int r = 0; r < 4; ++r) {
                int cID = c0 + nt * 16 + ss * 4 + r;
                float dv = (qd2 + sd2[cID]) - 2.f * acc[nt][r];
                if (cID == qrow) dv += 1e10f;    // self mask
                dv = fmaxf(dv, 0.f);
                dvv[nt][r] = dv;
                mn = fminf(mn, dv);
            }
        }
        if (__any(mn <= kthr)) {
#pragma unroll
            for (int nt = 0; nt < 4; ++nt) {
#pragma unroll
                for (int r = 0; r < 4; ++r) {
                    float dv = dvv[nt][r];
                    if (__any(dv <= kthr)) {
                        int cID = c0 + nt * 16 + ss * 4 + r;
                        u64 kb = ((u64)__float_as_uint(dv) << 32) | (u32)cID;
                        double key = __longlong_as_double((long long)kb);
                        bool pass = key < a[K_ - 1];
                        p1 = pass ? p0 : p1;
                        p0 = pass ? key : p0;
                        pcnt = pass ? pcnt + 1 : pcnt;
                        if (__any(pcnt >= 2)) {
                            double carry = p1;
#pragma unroll
                            for (int s = 0; s < K_; ++s) {
                                double as = a[s];
                                a[s]  = fmin(carry, as);
                                carry = fmax(carry, as);
                            }
                            carry = p0;
#pragma unroll
                            for (int s = 0; s < K_; ++s) {
                                double as = a[s];
                                a[s]  = fmin(carry, as);
                                carry = fmax(carry, as);
                            }
                            p0 = PINV; p1 = PINV; pcnt = 0;
                            kthr = __uint_as_float((u32)(__double_as_longlong(a[K_ - 1]) >> 32));
                        }
                    }
                }
            }
        }

        // ---- write the prefetched tile into buf[cur^1]
        if (hasnext) {
            char* dH = (char*)sH[cur ^ 1];
            char* dM = (char*)sM[cur ^ 1];
            char* dL = (char*)sL[cur ^ 1];
            *(bf16x8*)(dH + sbase + (sk2 ^ sswz)) = nh0;
            *(bf16x8*)(dH + sbase + ((sk2 + 16) ^ sswz)) = nh1;
            *(bf16x8*)(dM + sbase + (sk2 ^ sswz)) = nm0;
            *(bf16x8*)(dM + sbase + ((sk2 + 16) ^ sswz)) = nm1;
            *(bf16x8*)(dL + sbase + (sk2 ^ sswz)) = nl0;
            *(bf16x8*)(dL + sbase + ((sk2 + 16) ^ sswz)) = nl1;
        }
        __syncthreads();   // writes visible; all reads of buf[cur] complete
    }
    // final flush
    {
        double carry = p1;
#pragma unroll
        for (int s = 0; s < K_; ++s) {
            double as = a[s];
            a[s]  = fmin(carry, as);
            carry = fmax(carry, as);
        }
        carry = p0;
#pragma unroll
        for (int s = 0; s < K_; ++s) {
            double as = a[s];
            a[s]  = fmin(carry, as);
            carry = fmax(carry, as);
        }
    }

    // merge 4 sub-streams (lanes q, q+16, q+32, q+48): 20 rounds pop-min
    int* op = idx + ((size_t)(b * P_ + qrow)) * K_;
#pragma unroll 1
    for (int k = 0; k < K_; ++k) {
        double v = a[0];
        double v1 = __shfl_xor(v, 16);
        v = fmin(v, v1);
        double v2 = __shfl_xor(v, 32);
        v = fmin(v, v2);
        bool win = (__double_as_longlong(a[0]) == __double_as_longlong(v));
#pragma unroll
        for (int s = 0; s < K_ - 1; ++s) a[s] = win ? a[s + 1] : a[s];
        a[K_ - 1] = win ? BIG : a[K_ - 1];
        if (ss == 0)
            op[k] = b * P_ + (int)(__double_as_longlong(v) & 0xFFFFFFFFLL);
    }
}

// ---------------------------------------------------------------- pack W[128,64] -> Wpk[64,128], bpk
__global__ __launch_bounds__(128) void pack_kernel(const float* __restrict__ W,
                                                   const float* __restrict__ b,
                                                   float* __restrict__ Wpk,
                                                   float* __restrict__ bpk) {
    int t = blockIdx.x * 128 + threadIdx.x;
    int d = t >> 7, h2 = t & 127;
    Wpk[t] = (h2 < 64) ? W[d * 64 + h2] : W[(64 + d) * 64 + (h2 - 64)];
    if (t < 128) bpk[t] = (t < 64) ? b[t] : 0.f;
}

// ---------------------------------------------------------------- layer-1 UV (D=3, direct)
__global__ __launch_bounds__(256) void uv3_kernel(const float* __restrict__ x,
                                                  const float* __restrict__ W,
                                                  const float* __restrict__ b,
                                                  float* __restrict__ UV) {
    int t = blockIdx.x * 256 + threadIdx.x;
    int p = t >> 7, h2 = t & 127;
    float x0 = x[p * 3], x1 = x[p * 3 + 1], x2 = x[p * 3 + 2];
    float r;
    if (h2 < 64) {
        r = b[h2] + x0 * W[h2] + x1 * W[64 + h2] + x2 * W[128 + h2];
    } else {
        int h = h2 - 64;
        r = x0 * W[192 + h] + x1 * W[256 + h] + x2 * W[320 + h];
    }
    UV[t] = r;
}

// ---------------------------------------------------------------- edge max
__global__ __launch_bounds__(256) void edgemax_kernel(const float* __restrict__ UV,
                                                      const int* __restrict__ idx,
                                                      float* __restrict__ xout) {
    int wv = threadIdx.x >> 6, lane = threadIdx.x & 63;
    int p = blockIdx.x * 4 + wv;
    const float* uvp = UV + (size_t)p * 128;
    float duv = uvp[lane] - uvp[64 + lane];
    const int* ip = idx + (size_t)p * K_;
    int jj[K_];
#pragma unroll
    for (int k = 0; k < K_; ++k) jj[k] = ip[k];
    float m = -3.4e38f;
#pragma unroll
    for (int k = 0; k < K_; ++k) {
        float vj = UV[(size_t)jj[k] * 128 + 64 + lane];
        float t = duv + vj;
        m = fmaxf(m, fmaxf(t, NEG_SLOPE * t));
    }
    xout[(size_t)p * H_ + lane] = m;
}

// ---------------------------------------------------------------- GEMM 64x64 f32 (UV + Wo)
__global__ __launch_bounds__(256) void gemm_kernel(const float* __restrict__ A1,
                                                   const float* __restrict__ Wm,
                                                   const float* __restrict__ bias,
                                                   float* __restrict__ Cm,
                                                   int M, int N, int Kd, int leaky) {
    __shared__ float sA[32][68];
    __shared__ float sB[32][68];

    int tid = threadIdx.x;
    int row0 = blockIdx.x * 64, col0 = blockIdx.y * 64;
    int tx = tid & 15, ty = tid >> 4;

    int lr  = tid >> 2;
    int lk4 = (tid & 3) * 4;
    int lkb = tid >> 4;
    int lnb = (tid & 15) * 4;

    float acc[4][4] = {};

    for (int k0 = 0; k0 < Kd; k0 += 32) {
        int arow = row0 + lr;
#pragma unroll
        for (int h = 0; h < 32; h += 16) {
            int kk = k0 + lk4 + h;
            const float* src = A1 + (size_t)arow * Kd + kk;
            float4 av = *(const float4*)src;
            sA[lk4 + h + 0][lr] = av.x; sA[lk4 + h + 1][lr] = av.y;
            sA[lk4 + h + 2][lr] = av.z; sA[lk4 + h + 3][lr] = av.w;
        }
        int bcol = col0 + lnb;
#pragma unroll
        for (int h = 0; h < 32; h += 16) {
            float4 bv = make_float4(0.f, 0.f, 0.f, 0.f);
            if (bcol < N) bv = *(const float4*)(Wm + (size_t)(k0 + lkb + h) * N + bcol);
            *(float4*)&sB[lkb + h][lnb] = bv;
        }
        __syncthreads();

#pragma unroll
        for (int kk2 = 0; kk2 < 32; ++kk2) {
            float4 a = *(const float4*)&sA[kk2][ty * 4];
            float4 bb = *(const float4*)&sB[kk2][tx * 4];
            acc[0][0] = fmaf(a.x, bb.x, acc[0][0]); acc[0][1] = fmaf(a.x, bb.y, acc[0][1]);
            acc[0][2] = fmaf(a.x, bb.z, acc[0][2]); acc[0][3] = fmaf(a.x, bb.w, acc[0][3]);
            acc[1][0] = fmaf(a.y, bb.x, acc[1][0]); acc[1][1] = fmaf(a.y, bb.y, acc[1][1]);
            acc[1][2] = fmaf(a.y, bb.z, acc[1][2]); acc[1][3] = fmaf(a.y, bb.w, acc[1][3]);
            acc[2][0] = fmaf(a.z, bb.x, acc[2][0]); acc[2][1] = fmaf(a.z, bb.y, acc[2][1]);
            acc[2][2] = fmaf(a.z, bb.z, acc[2][2]); acc[2][3] = fmaf(a.z, bb.w, acc[2][3]);
            acc[3][0] = fmaf(a.w, bb.x, acc[3][0]); acc[3][1] = fmaf(a.w, bb.y, acc[3][1]);
            acc[3][2] = fmaf(a.w, bb.z, acc[3][2]); acc[3][3] = fmaf(a.w, bb.w, acc[3][3]);
        }
        __syncthreads();
    }

    for (int i = 0; i < 4; ++i) {
        int row = row0 + ty * 4 + i;
        for (int j = 0; j < 4; ++j) {
            int col = col0 + tx * 4 + j;
            if (col < N) {
                float v = acc[i][j] + bias[col];
                if (leaky) v = v > 0.f ? v : NEG_SLOPE * v;
                Cm[(size_t)row * N + col] = v;
            }
        }
    }
}

// ---------------------------------------------------------------- head: f32 W[K,N] -> bf16 WT[N,K]
__global__ __launch_bounds__(256) void wcvtT_kernel(const float* __restrict__ W,
                                                    u16* __restrict__ WT, int K, int N) {
    int t = blockIdx.x * 256 + threadIdx.x;
    if (t >= K * N) return;
    int k = t / N, n = t % N;
    WT[(size_t)n * K + k] = f2bf(W[t]);
}

// ---------------------------------------------------------------- head: concat chunk -> bf16 [4096,192]
__global__ __launch_bounds__(256) void cvt_cat_kernel(const float* __restrict__ x1,
                                                      const float* __restrict__ x2,
                                                      const float* __restrict__ x3,
                                                      u16* __restrict__ A0) {
    int t = blockIdx.x * 256 + threadIdx.x;     // 4096*48
    int r = t / 48, c4 = (t % 48) * 4;
    const float* src = (c4 < 64) ? (x1 + (size_t)r * 64 + c4)
                     : (c4 < 128) ? (x2 + (size_t)r * 64 + (c4 - 64))
                                  : (x3 + (size_t)r * 64 + (c4 - 128));
    float4 v = *(const float4*)src;
    u16* dst = A0 + (size_t)r * 192 + c4;
    dst[0] = f2bf(v.x); dst[1] = f2bf(v.y); dst[2] = f2bf(v.z); dst[3] = f2bf(v.w);
}

// ---------------------------------------------------------------- MFMA GEMM head
template <int KD, int OUT_BF16>
__global__ __launch_bounds__(256) void gemm_mfma_kernel(const u16* __restrict__ A,
                                                        const u16* __restrict__ BT,
                                                        const float* __restrict__ bias,
                                                        void* __restrict__ Cout,
                                                        int N, int leaky) {
    __shared__ u16 sA[128 * 64];   // elem (r,k) at byte r*128 + ((k*2) ^ ((r&7)<<4))
    __shared__ u16 sB[128 * 64];

    int t = threadIdx.x;
    int wave = t >> 6, lane = t & 63;
    int wm = wave >> 1, wn = wave & 1;
    int row0 = blockIdx.x * 128;
    int col0 = blockIdx.y * 128;

    f32x4 acc[4][4] = {};

    for (int k0 = 0; k0 < KD; k0 += 64) {
        __syncthreads();
#pragma unroll
        for (int i = 0; i < 4; ++i) {
            int li = t + i * 256;
            int r = li >> 3;
            int kc = (li & 7) * 8;
            bf16x8 v = *(const bf16x8*)(A + (size_t)(row0 + r) * KD + k0 + kc);
            *(bf16x8*)((char*)sA + r * 128 + ((kc * 2) ^ ((r & 7) << 4))) = v;
        }
#pragma unroll
        for (int i = 0; i < 4; ++i) {
            int li = t + i * 256;
            int n = li >> 3;
            int kc = (li & 7) * 8;
            bf16x8 v = *(const bf16x8*)(BT + (size_t)(col0 + n) * KD + k0 + kc);
            *(bf16x8*)((char*)sB + n * 128 + ((kc * 2) ^ ((n & 7) << 4))) = v;
        }
        __syncthreads();

#pragma unroll
        for (int kk = 0; kk < 2; ++kk) {
            int kb = kk * 64 + (lane >> 4) * 16;
            bf16x8 af[4], bfr[4];
#pragma unroll
            for (int mi = 0; mi < 4; ++mi) {
                int r = wm * 64 + mi * 16 + (lane & 15);
                af[mi] = *(const bf16x8*)((char*)sA + r * 128 + (kb ^ ((r & 7) << 4)));
            }
#pragma unroll
            for (int ni = 0; ni < 4; ++ni) {
                int n = wn * 64 + ni * 16 + (lane & 15);
                bfr[ni] = *(const bf16x8*)((char*)sB + n * 128 + (kb ^ ((n & 7) << 4)));
            }
#pragma unroll
            for (int mi = 0; mi < 4; ++mi)
#pragma unroll
                for (int ni = 0; ni < 4; ++ni)
                    acc[mi][ni] = __builtin_amdgcn_mfma_f32_16x16x32_bf16(
                        af[mi], bfr[ni], acc[mi][ni], 0, 0, 0);
        }
    }

#pragma unroll
    for (int ni = 0; ni < 4; ++ni) {
        int col = col0 + wn * 64 + ni * 16 + (lane & 15);
        float bs = bias[col];
#pragma unroll
        for (int mi = 0; mi < 4; ++mi) {
#pragma unroll
            for (int r = 0; r < 4; ++r) {
                int row = row0 + wm * 64 + mi * 16 + (lane >> 4) * 4 + r;
                float v = acc[mi][ni][r] + bs;
                if (leaky) v = v > 0.f ? v : NEG_SLOPE * v;
                if (OUT_BF16)
                    ((u16*)Cout)[(size_t)row * N + col] = f2bf(v);
                else
                    ((float*)Cout)[(size_t)row * N + col] = v;
            }
        }
    }
}

// ---------------------------------------------------------------- log_softmax rows of 40
__global__ __launch_bounds__(256) void lsm_kernel(float* __restrict__ out) {
    int row = blockIdx.x * 4 + (threadIdx.x >> 6);
    int lane = threadIdx.x & 63;
    float v = -3.4e38f;
    if (lane < C_) v = out[(size_t)row * C_ + lane];
    float m = v;
#pragma unroll
    for (int s = 1; s < 64; s <<= 1) m = fmaxf(m, __shfl_xor(m, s));
    float e = (lane < C_) ? expf(v - m) : 0.f;
    float sum = e;
#pragma unroll
    for (int s = 1; s < 64; s <<= 1) sum += __shfl_xor(sum, s);
    if (lane < C_) out[(size_t)row * C_ + lane] = v - m - logf(sum);
}

// ----------------------------------------------------------------
extern "C" void kernel_launch(void* const* d_in, const int* in_sizes, int n_in,
                              void* d_out, int out_size, void* d_ws, size_t ws_size,
                              hipStream_t stream) {
    const float* x   = (const float*)d_in[0];
    const float* W1  = (const float*)d_in[2];
    const float* b1  = (const float*)d_in[3];
    const float* W2  = (const float*)d_in[4];
    const float* b2  = (const float*)d_in[5];
    const float* W3  = (const float*)d_in[6];
    const float* b3  = (const float*)d_in[7];
    const float* Wl  = (const float*)d_in[8];
    const float* bl  = (const float*)d_in[9];
    const float* Wm1 = (const float*)d_in[10];
    const float* bm1 = (const float*)d_in[11];
    const float* Wm2 = (const float*)d_in[12];
    const float* bm2 = (const float*)d_in[13];
    const float* Wo  = (const float*)d_in[14];
    const float* bo  = (const float*)d_in[15];
    float* out = (float*)d_out;

    // ---- workspace (max 50,987,008 B — proven footprint) ----
    char* ws = (char*)d_ws;
    float* x1   = (float*)(ws);                       // 8 MB
    float* x2   = (float*)(ws + 8388608);             // 8 MB
    float* x3   = (float*)(ws + 16777216);            // 8 MB
    int*   idx  = (int*)  (ws + 25165824);            // 2.62 MB
    float* d2   = (float*)(ws + 27787264);            // 128 KB
    // region 27,918,336 .. 50,987,008, phase-aliased (stream-ordered):
    char* hb = ws + 27918336;
    // knn phase: h/m/l splits (12 MB); dead before UV/pack writes
    u16*   xhs  = (u16*)(hb);                         // 4 MB
    u16*   xms  = (u16*)(hb + 4194304);               // 4 MB
    u16*   xls  = (u16*)(hb + 8388608);               // 4 MB
    // edge phase:
    float* UV   = (float*)(hb);                       // 16 MB
    float* Wpk  = (float*)(ws + 44695552);
    float* bpk  = (float*)(ws + 44728320);
    // head phase:
    u16*   WlT   = (u16*)(hb);                        // [1024][192]
    u16*   Wm1T  = (u16*)(hb + 393216);               // [256][1024]
    u16*   Wm2T  = (u16*)(hb + 917504);               // [128][256]
    u16*   A0bf  = (u16*)(hb + 983040);               // [4096][192]
    u16*   act1  = (u16*)(hb + 2555904);              // [4096][1024]
    u16*   act2  = (u16*)(hb + 10944512);             // [4096][256]
    float* act3  = (float*)(hb + 13041664);           // [4096][128] f32

    // ---- layer 1 (D=3): vector fused knn
    d2_kernel<3><<<NPT / 256, 256, 0, stream>>>(x, d2);
    knnf_kernel<3><<<dim3(P_ / 64, B_), 256, 0, stream>>>(x, d2, idx);
    uv3_kernel<<<NPT * 128 / 256, 256, 0, stream>>>(x, W1, b1, UV);
    edgemax_kernel<<<NPT / 4, 256, 0, stream>>>(UV, idx, x1);
    // ---- layer 2 (D=64): MFMA fused knn v3
    d2_kernel<64><<<NPT / 256, 256, 0, stream>>>(x1, d2);
    cvt3_kernel<<<NPT * 64 / 256, 256, 0, stream>>>(x1, xhs, xms, xls);
    knnm64_kernel<<<dim3(P_ / 64, B_), 256, 0, stream>>>(xhs, xms, xls, d2, idx);
    pack_kernel<<<64, 128, 0, stream>>>(W2, b2, Wpk, bpk);
    gemm_kernel<<<dim3(NPT / 64, 2), 256, 0, stream>>>(x1, Wpk, bpk, UV, NPT, 128, 64, 0);
    edgemax_kernel<<<NPT / 4, 256, 0, stream>>>(UV, idx, x2);
    // ---- layer 3 (D=64)
    d2_kernel<64><<<NPT / 256, 256, 0, stream>>>(x2, d2);
    cvt3_kernel<<<NPT * 64 / 256, 256, 0, stream>>>(x2, xhs, xms, xls);
    knnm64_kernel<<<dim3(P_ / 64, B_), 256, 0, stream>>>(xhs, xms, xls, d2, idx);
    pack_kernel<<<64, 128, 0, stream>>>(W3, b3, Wpk, bpk);
    gemm_kernel<<<dim3(NPT / 64, 2), 256, 0, stream>>>(x2, Wpk, bpk, UV, NPT, 128, 64, 0);
    edgemax_kernel<<<NPT / 4, 256, 0, stream>>>(UV, idx, x3);

    // ---- MLP head: bf16 MFMA (Wl, Wm1, Wm2) + f32 (Wo)
    wcvtT_kernel<<<(192 * 1024 + 255) / 256, 256, 0, stream>>>(Wl, WlT, 192, 1024);
    wcvtT_kernel<<<(1024 * 256 + 255) / 256, 256, 0, stream>>>(Wm1, Wm1T, 1024, 256);
    wcvtT_kernel<<<(256 * 128 + 255) / 256, 256, 0, stream>>>(Wm2, Wm2T, 256, 128);

    for (int c = 0; c < 8; ++c) {
        size_t r0 = (size_t)c * 4096;
        cvt_cat_kernel<<<4096 * 48 / 256, 256, 0, stream>>>(x1 + r0 * 64, x2 + r0 * 64,
                                                            x3 + r0 * 64, A0bf);
        gemm_mfma_kernel<192, 1><<<dim3(32, 8), 256, 0, stream>>>(A0bf, WlT, bl, act1, 1024, 1);
        gemm_mfma_kernel<1024, 1><<<dim3(32, 2), 256, 0, stream>>>(act1, Wm1T, bm1, act2, 256, 1);
        gemm_mfma_kernel<256, 0><<<dim3(32, 1), 256, 0, stream>>>(act2, Wm2T, bm2, act3, 128, 1);
        gemm_kernel<<<dim3(64, 1), 256, 0, stream>>>(act3, Wo, bo, out + r0 * C_, 4096, 40, 128, 0);
    }
    lsm_kernel<<<NPT / 4, 256, 0, stream>>>(out);
}

// Round 14
// 1109.375 us; speedup vs baseline: 1.3908x; 1.1469x over previous
//
#include <hip/hip_runtime.h>
#include <cstddef>
#include <cstdint>

constexpr int B_ = 8, P_ = 4096, K_ = 20, H_ = 64, C_ = 40;
constexpr int NPT = B_ * P_;
#define NEG_SLOPE 0.2f

typedef unsigned long long u64;
typedef unsigned int u32;
typedef unsigned short u16;
typedef __attribute__((ext_vector_type(8))) short bf16x8;
typedef __attribute__((ext_vector_type(4))) float f32x4;

__device__ inline u16 f2bf(float v) {   // round-to-nearest-even bf16
    u32 bits = __float_as_uint(v);
    return (u16)((bits + 0x7FFFu + ((bits >> 16) & 1)) >> 16);
}
__device__ inline float bf2f(u16 h) { return __uint_as_float((u32)h << 16); }

// ---------------------------------------------------------------- d2 = sum(x*x)
template <int D>
__global__ __launch_bounds__(256) void d2_kernel(const float* __restrict__ x,
                                                 float* __restrict__ d2) {
    int i = blockIdx.x * 256 + threadIdx.x;
    if (i >= NPT) return;
    const float* r = x + (size_t)i * D;
    float s = 0.f;
    if constexpr (D % 4 == 0) {
#pragma unroll
        for (int d = 0; d < D; d += 4) {
            float4 v = *(const float4*)(r + d);
            s += v.x * v.x + v.y * v.y + v.z * v.z + v.w * v.w;
        }
    } else {
#pragma unroll
        for (int d = 0; d < D; ++d) { float v = r[d]; s += v * v; }
    }
    d2[i] = s;
}

// ---------------------------------------------------------------- split x (f32) -> h,m,l bf16
__global__ __launch_bounds__(256) void cvt3_kernel(const float* __restrict__ x,
                                                   u16* __restrict__ xh,
                                                   u16* __restrict__ xm,
                                                   u16* __restrict__ xl) {
    int i = blockIdx.x * 256 + threadIdx.x;   // NPT*64 elems
    float v = x[i];
    u16 h = f2bf(v);
    float r1 = v - bf2f(h);
    u16 m = f2bf(r1);
    float r2 = r1 - bf2f(m);
    xh[i] = h; xm[i] = m; xl[i] = f2bf(r2);
}

// ---------------------------------------------------------------- layer-1 fused knn (D=3), R13-proven
template <int D>
__global__ __launch_bounds__(256) void knnf_kernel(const float* __restrict__ x,
                                                   const float* __restrict__ d2,
                                                   int* __restrict__ idx) {
    __shared__ float sQT[D][68];
    __shared__ float sCT[D][68];
    __shared__ float sD[64][68];

    int b = blockIdx.y;
    int q0 = blockIdx.x * 64;
    const float* xc  = x + (size_t)b * P_ * D;
    const float* d2b = d2 + (size_t)b * P_;

    int t = threadIdx.x;
    int ty = t >> 4, tx = t & 15;
    int w = t >> 6, ln = t & 63;
    int qs = w * 16 + (ln >> 2);
    int cs = ln & 3;

    if (t < 64) {
#pragma unroll
        for (int d = 0; d < D; ++d) sQT[d][t] = xc[(size_t)(q0 + t) * D + d];
    }
    float qd2i[4];
#pragma unroll
    for (int i = 0; i < 4; ++i) qd2i[i] = d2b[q0 + ty * 4 + i];

    double a[K_];
#pragma unroll
    for (int s = 0; s < K_; ++s)
        a[s] = __longlong_as_double((0x7F7FFFFFLL << 32) | (long long)(0xFFFF0000u + s));
    const double PINV = __longlong_as_double(0x7FE0000000000000LL);
    const double BIG  = __longlong_as_double((0x7F7FFFFFLL << 32) | 0xFFFFFFF0LL);

    double p0 = PINV, p1 = PINV;
    int pcnt = 0;
    float kthr = __uint_as_float(0x7F7FFFFFu);   // FLT_MAX

#pragma unroll 1
    for (int c0 = 0; c0 < P_; c0 += 64) {
        __syncthreads();
        if (t < 64) {
#pragma unroll
            for (int d = 0; d < D; ++d) sCT[d][t] = xc[(size_t)(c0 + t) * D + d];
        }
        __syncthreads();

        float acc[4][4] = {};
#pragma unroll
        for (int kk = 0; kk < D; ++kk) {
            float4 aq = *(const float4*)&sQT[kk][ty * 4];
            float4 bc = *(const float4*)&sCT[kk][tx * 4];
            acc[0][0] = fmaf(aq.x, bc.x, acc[0][0]); acc[0][1] = fmaf(aq.x, bc.y, acc[0][1]);
            acc[0][2] = fmaf(aq.x, bc.z, acc[0][2]); acc[0][3] = fmaf(aq.x, bc.w, acc[0][3]);
            acc[1][0] = fmaf(aq.y, bc.x, acc[1][0]); acc[1][1] = fmaf(aq.y, bc.y, acc[1][1]);
            acc[1][2] = fmaf(aq.y, bc.z, acc[1][2]); acc[1][3] = fmaf(aq.y, bc.w, acc[1][3]);
            acc[2][0] = fmaf(aq.z, bc.x, acc[2][0]); acc[2][1] = fmaf(aq.z, bc.y, acc[2][1]);
            acc[2][2] = fmaf(aq.z, bc.z, acc[2][2]); acc[2][3] = fmaf(aq.z, bc.w, acc[2][3]);
            acc[3][0] = fmaf(aq.w, bc.x, acc[3][0]); acc[3][1] = fmaf(aq.w, bc.y, acc[3][1]);
            acc[3][2] = fmaf(aq.w, bc.z, acc[3][2]); acc[3][3] = fmaf(aq.w, bc.w, acc[3][3]);
        }
        float cd2j[4];
#pragma unroll
        for (int j = 0; j < 4; ++j) cd2j[j] = d2b[c0 + tx * 4 + j];
        bool diag = (q0 == c0);
#pragma unroll
        for (int i = 0; i < 4; ++i) {
            float dd[4];
#pragma unroll
            for (int j = 0; j < 4; ++j) {
                float v = (qd2i[i] + cd2j[j]) - 2.f * acc[i][j];
                if (diag && (ty * 4 + i == tx * 4 + j)) v += 1e10f;
                dd[j] = fmaxf(v, 0.f);
            }
            *(float4*)&sD[ty * 4 + i][tx * 4] = make_float4(dd[0], dd[1], dd[2], dd[3]);
        }
        __syncthreads();

        float dvv[16];
        float mn = 3.4e38f;
#pragma unroll
        for (int u = 0; u < 16; ++u) {
            dvv[u] = sD[qs][cs + u * 4];
            mn = fminf(mn, dvv[u]);
        }
        if (__any(mn <= kthr)) {
#pragma unroll
            for (int u = 0; u < 16; ++u) {
                float dv = dvv[u];
                if (__any(dv <= kthr)) {
                    u64 kb = ((u64)__float_as_uint(dv) << 32) | (u32)(c0 + cs + u * 4);
                    double key = __longlong_as_double((long long)kb);
                    bool pass = key < a[K_ - 1];
                    p1 = pass ? p0 : p1;
                    p0 = pass ? key : p0;
                    pcnt = pass ? pcnt + 1 : pcnt;
                    if (__any(pcnt >= 2)) {
                        double carry = p1;
#pragma unroll
                        for (int s = 0; s < K_; ++s) {
                            double as = a[s];
                            a[s]  = fmin(carry, as);
                            carry = fmax(carry, as);
                        }
                        carry = p0;
#pragma unroll
                        for (int s = 0; s < K_; ++s) {
                            double as = a[s];
                            a[s]  = fmin(carry, as);
                            carry = fmax(carry, as);
                        }
                        p0 = PINV; p1 = PINV; pcnt = 0;
                        kthr = __uint_as_float((u32)(__double_as_longlong(a[K_ - 1]) >> 32));
                    }
                }
            }
        }
    }
    {   // final flush
        double carry = p1;
#pragma unroll
        for (int s = 0; s < K_; ++s) {
            double as = a[s];
            a[s]  = fmin(carry, as);
            carry = fmax(carry, as);
        }
        carry = p0;
#pragma unroll
        for (int s = 0; s < K_; ++s) {
            double as = a[s];
            a[s]  = fmin(carry, as);
            carry = fmax(carry, as);
        }
    }

    int* op = idx + ((size_t)(b * P_ + q0 + qs)) * K_;
#pragma unroll 1
    for (int k = 0; k < K_; ++k) {
        double v = a[0];
        double v1 = __shfl_xor(v, 1);
        v = fmin(v, v1);
        double v2 = __shfl_xor(v, 2);
        v = fmin(v, v2);
        bool win = (__double_as_longlong(a[0]) == __double_as_longlong(v));
#pragma unroll
        for (int s = 0; s < K_ - 1; ++s) a[s] = win ? a[s + 1] : a[s];
        a[K_ - 1] = win ? BIG : a[K_ - 1];
        if (cs == 0)
            op[k] = b * P_ + (int)(__double_as_longlong(v) & 0xFFFFFFFFLL);
    }
}

// ---------------------------------------------------------------- fused knn (D=64) via MFMA (R11 structure)
__global__ __launch_bounds__(256) void knnm64_kernel(const u16* __restrict__ xh,
                                                     const u16* __restrict__ xm,
                                                     const u16* __restrict__ xl,
                                                     const float* __restrict__ d2,
                                                     int* __restrict__ idx) {
    __shared__ u16 sH[64 * 64];      // elem (r,k) at byte r*128 + ((k*2) ^ ((r&7)<<4))
    __shared__ u16 sM[64 * 64];
    __shared__ u16 sL[64 * 64];
    __shared__ float sd2[P_];        // 16 KB

    int b = blockIdx.y;
    int q0 = blockIdx.x * 64;
    const u16* xhb = xh + (size_t)b * P_ * 64;
    const u16* xmb = xm + (size_t)b * P_ * 64;
    const u16* xlb = xl + (size_t)b * P_ * 64;
    const float* d2b = d2 + (size_t)b * P_;

    int t = threadIdx.x, w = t >> 6, ln = t & 63;
    int q  = ln & 15;
    int ss = ln >> 4;

    for (int i = t; i < P_ / 4; i += 256)
        ((float4*)sd2)[i] = ((const float4*)d2b)[i];

    int qrow = q0 + w * 16 + q;
    bf16x8 qh[2], qm[2], ql[2];
#pragma unroll
    for (int kt = 0; kt < 2; ++kt) {
        size_t off = (size_t)qrow * 64 + kt * 32 + ss * 8;
        qh[kt] = *(const bf16x8*)(xhb + off);
        qm[kt] = *(const bf16x8*)(xmb + off);
        ql[kt] = *(const bf16x8*)(xlb + off);
    }

    __syncthreads();
    float qd2 = sd2[qrow];

    double a[K_];
#pragma unroll
    for (int s = 0; s < K_; ++s)
        a[s] = __longlong_as_double((0x7F7FFFFFLL << 32) | (long long)(0xFFFF0000u + s));
    const double BIG  = __longlong_as_double((0x7F7FFFFFLL << 32) | 0xFFFFFFF0LL);
    const double PINV = __longlong_as_double(0x7FE0000000000000LL);

    double p0 = PINV, p1 = PINV;
    int pcnt = 0;
    float kthr = __uint_as_float(0x7F7FFFFFu);

    int sr = t >> 2;
    int sk2 = (t & 3) * 32;
    int sbase = sr * 128, sswz = (sr & 7) << 4;
    size_t sgof = (size_t)sr * 64 + (t & 3) * 16;

#pragma unroll 1
    for (int c0 = 0; c0 < P_; c0 += 64) {
        __syncthreads();
        {
            size_t g = (size_t)c0 * 64 + sgof;
            bf16x8 h0 = *(const bf16x8*)(xhb + g);
            bf16x8 h1 = *(const bf16x8*)(xhb + g + 8);
            bf16x8 m0 = *(const bf16x8*)(xmb + g);
            bf16x8 m1 = *(const bf16x8*)(xmb + g + 8);
            bf16x8 l0 = *(const bf16x8*)(xlb + g);
            bf16x8 l1 = *(const bf16x8*)(xlb + g + 8);
            *(bf16x8*)((char*)sH + sbase + (sk2 ^ sswz)) = h0;
            *(bf16x8*)((char*)sH + sbase + ((sk2 + 16) ^ sswz)) = h1;
            *(bf16x8*)((char*)sM + sbase + (sk2 ^ sswz)) = m0;
            *(bf16x8*)((char*)sM + sbase + ((sk2 + 16) ^ sswz)) = m1;
            *(bf16x8*)((char*)sL + sbase + (sk2 ^ sswz)) = l0;
            *(bf16x8*)((char*)sL + sbase + ((sk2 + 16) ^ sswz)) = l1;
        }
        __syncthreads();

        f32x4 acc[4];
#pragma unroll
        for (int nt = 0; nt < 4; ++nt) {
            acc[nt] = (f32x4){0.f, 0.f, 0.f, 0.f};
            int r = nt * 16 + q;
            int base = r * 128, swz = (r & 7) << 4;
#pragma unroll
            for (int kt = 0; kt < 2; ++kt) {
                int k2 = kt * 64 + ss * 16;
                bf16x8 ch = *(const bf16x8*)((char*)sH + base + (k2 ^ swz));
                bf16x8 cm = *(const bf16x8*)((char*)sM + base + (k2 ^ swz));
                bf16x8 cl = *(const bf16x8*)((char*)sL + base + (k2 ^ swz));
                acc[nt] = __builtin_amdgcn_mfma_f32_16x16x32_bf16(cm, qm[kt], acc[nt], 0, 0, 0);
                acc[nt] = __builtin_amdgcn_mfma_f32_16x16x32_bf16(cl, qh[kt], acc[nt], 0, 0, 0);
                acc[nt] = __builtin_amdgcn_mfma_f32_16x16x32_bf16(ch, ql[kt], acc[nt], 0, 0, 0);
                acc[nt] = __builtin_amdgcn_mfma_f32_16x16x32_bf16(cm, qh[kt], acc[nt], 0, 0, 0);
                acc[nt] = __builtin_amdgcn_mfma_f32_16x16x32_bf16(ch, qm[kt], acc[nt], 0, 0, 0);
                acc[nt] = __builtin_amdgcn_mfma_f32_16x16x32_bf16(ch, qh[kt], acc[nt], 0, 0, 0);
            }
        }

        float dvv[4][4];
        float mn = 3.4e38f;
#pragma unroll
        for (int nt = 0; nt < 4; ++nt) {
#pragma unroll
            for (int r = 0; r < 4; ++r) {
                int cID = c0 + nt * 16 + ss * 4 + r;
                float dv = (qd2 + sd2[cID]) - 2.f * acc[nt][r];
                if (cID == qrow) dv += 1e10f;
                dv = fmaxf(dv, 0.f);
                dvv[nt][r] = dv;
                mn = fminf(mn, dv);
            }
        }
        if (__any(mn <= kthr)) {
#pragma unroll
            for (int nt = 0; nt < 4; ++nt) {
#pragma unroll
                for (int r = 0; r < 4; ++r) {
                    float dv = dvv[nt][r];
                    if (__any(dv <= kthr)) {
                        int cID = c0 + nt * 16 + ss * 4 + r;
                        u64 kb = ((u64)__float_as_uint(dv) << 32) | (u32)cID;
                        double key = __longlong_as_double((long long)kb);
                        bool pass = key < a[K_ - 1];
                        p1 = pass ? p0 : p1;
                        p0 = pass ? key : p0;
                        pcnt = pass ? pcnt + 1 : pcnt;
                        if (__any(pcnt >= 2)) {
                            double carry = p1;
#pragma unroll
                            for (int s = 0; s < K_; ++s) {
                                double as = a[s];
                                a[s]  = fmin(carry, as);
                                carry = fmax(carry, as);
                            }
                            carry = p0;
#pragma unroll
                            for (int s = 0; s < K_; ++s) {
                                double as = a[s];
                                a[s]  = fmin(carry, as);
                                carry = fmax(carry, as);
                            }
                            p0 = PINV; p1 = PINV; pcnt = 0;
                            kthr = __uint_as_float((u32)(__double_as_longlong(a[K_ - 1]) >> 32));
                        }
                    }
                }
            }
        }
    }
    {
        double carry = p1;
#pragma unroll
        for (int s = 0; s < K_; ++s) {
            double as = a[s];
            a[s]  = fmin(carry, as);
            carry = fmax(carry, as);
        }
        carry = p0;
#pragma unroll
        for (int s = 0; s < K_; ++s) {
            double as = a[s];
            a[s]  = fmin(carry, as);
            carry = fmax(carry, as);
        }
    }

    int* op = idx + ((size_t)(b * P_ + qrow)) * K_;
#pragma unroll 1
    for (int k = 0; k < K_; ++k) {
        double v = a[0];
        double v1 = __shfl_xor(v, 16);
        v = fmin(v, v1);
        double v2 = __shfl_xor(v, 32);
        v = fmin(v, v2);
        bool win = (__double_as_longlong(a[0]) == __double_as_longlong(v));
#pragma unroll
        for (int s = 0; s < K_ - 1; ++s) a[s] = win ? a[s + 1] : a[s];
        a[K_ - 1] = win ? BIG : a[K_ - 1];
        if (ss == 0)
            op[k] = b * P_ + (int)(__double_as_longlong(v) & 0xFFFFFFFFLL);
    }
}

// ---------------------------------------------------------------- pack W[128,64] -> Wpk[64,128], bpk
__global__ __launch_bounds__(128) void pack_kernel(const float* __restrict__ W,
                                                   const float* __restrict__ b,
                                                   float* __restrict__ Wpk,
                                                   float* __restrict__ bpk) {
    int t = blockIdx.x * 128 + threadIdx.x;
    int d = t >> 7, h2 = t & 127;
    Wpk[t] = (h2 < 64) ? W[d * 64 + h2] : W[(64 + d) * 64 + (h2 - 64)];
    if (t < 128) bpk[t] = (t < 64) ? b[t] : 0.f;
}

// ---------------------------------------------------------------- layer-1 UV (D=3, direct)
__global__ __launch_bounds__(256) void uv3_kernel(const float* __restrict__ x,
                                                  const float* __restrict__ W,
                                                  const float* __restrict__ b,
                                                  float* __restrict__ UV) {
    int t = blockIdx.x * 256 + threadIdx.x;
    int p = t >> 7, h2 = t & 127;
    float x0 = x[p * 3], x1 = x[p * 3 + 1], x2 = x[p * 3 + 2];
    float r;
    if (h2 < 64) {
        r = b[h2] + x0 * W[h2] + x1 * W[64 + h2] + x2 * W[128 + h2];
    } else {
        int h = h2 - 64;
        r = x0 * W[192 + h] + x1 * W[256 + h] + x2 * W[320 + h];
    }
    UV[t] = r;
}

// ---------------------------------------------------------------- edge max
__global__ __launch_bounds__(256) void edgemax_kernel(const float* __restrict__ UV,
                                                      const int* __restrict__ idx,
                                                      float* __restrict__ xout) {
    int wv = threadIdx.x >> 6, lane = threadIdx.x & 63;
    int p = blockIdx.x * 4 + wv;
    const float* uvp = UV + (size_t)p * 128;
    float duv = uvp[lane] - uvp[64 + lane];
    const int* ip = idx + (size_t)p * K_;
    int jj[K_];
#pragma unroll
    for (int k = 0; k < K_; ++k) jj[k] = ip[k];
    float m = -3.4e38f;
#pragma unroll
    for (int k = 0; k < K_; ++k) {
        float vj = UV[(size_t)jj[k] * 128 + 64 + lane];
        float t = duv + vj;
        m = fmaxf(m, fmaxf(t, NEG_SLOPE * t));
    }
    xout[(size_t)p * H_ + lane] = m;
}

// ---------------------------------------------------------------- GEMM 64x64 f32 (UV + Wo)
__global__ __launch_bounds__(256) void gemm_kernel(const float* __restrict__ A1,
                                                   const float* __restrict__ Wm,
                                                   const float* __restrict__ bias,
                                                   float* __restrict__ Cm,
                                                   int M, int N, int Kd, int leaky) {
    __shared__ float sA[32][68];
    __shared__ float sB[32][68];

    int tid = threadIdx.x;
    int row0 = blockIdx.x * 64, col0 = blockIdx.y * 64;
    int tx = tid & 15, ty = tid >> 4;

    int lr  = tid >> 2;
    int lk4 = (tid & 3) * 4;
    int lkb = tid >> 4;
    int lnb = (tid & 15) * 4;

    float acc[4][4] = {};

    for (int k0 = 0; k0 < Kd; k0 += 32) {
        int arow = row0 + lr;
#pragma unroll
        for (int h = 0; h < 32; h += 16) {
            int kk = k0 + lk4 + h;
            const float* src = A1 + (size_t)arow * Kd + kk;
            float4 av = *(const float4*)src;
            sA[lk4 + h + 0][lr] = av.x; sA[lk4 + h + 1][lr] = av.y;
            sA[lk4 + h + 2][lr] = av.z; sA[lk4 + h + 3][lr] = av.w;
        }
        int bcol = col0 + lnb;
#pragma unroll
        for (int h = 0; h < 32; h += 16) {
            float4 bv = make_float4(0.f, 0.f, 0.f, 0.f);
            if (bcol < N) bv = *(const float4*)(Wm + (size_t)(k0 + lkb + h) * N + bcol);
            *(float4*)&sB[lkb + h][lnb] = bv;
        }
        __syncthreads();

#pragma unroll
        for (int kk2 = 0; kk2 < 32; ++kk2) {
            float4 a = *(const float4*)&sA[kk2][ty * 4];
            float4 bb = *(const float4*)&sB[kk2][tx * 4];
            acc[0][0] = fmaf(a.x, bb.x, acc[0][0]); acc[0][1] = fmaf(a.x, bb.y, acc[0][1]);
            acc[0][2] = fmaf(a.x, bb.z, acc[0][2]); acc[0][3] = fmaf(a.x, bb.w, acc[0][3]);
            acc[1][0] = fmaf(a.y, bb.x, acc[1][0]); acc[1][1] = fmaf(a.y, bb.y, acc[1][1]);
            acc[1][2] = fmaf(a.y, bb.z, acc[1][2]); acc[1][3] = fmaf(a.y, bb.w, acc[1][3]);
            acc[2][0] = fmaf(a.z, bb.x, acc[2][0]); acc[2][1] = fmaf(a.z, bb.y, acc[2][1]);
            acc[2][2] = fmaf(a.z, bb.z, acc[2][2]); acc[2][3] = fmaf(a.z, bb.w, acc[2][3]);
            acc[3][0] = fmaf(a.w, bb.x, acc[3][0]); acc[3][1] = fmaf(a.w, bb.y, acc[3][1]);
            acc[3][2] = fmaf(a.w, bb.z, acc[3][2]); acc[3][3] = fmaf(a.w, bb.w, acc[3][3]);
        }
        __syncthreads();
    }

    for (int i = 0; i < 4; ++i) {
        int row = row0 + ty * 4 + i;
        for (int j = 0; j < 4; ++j) {
            int col = col0 + tx * 4 + j;
            if (col < N) {
                float v = acc[i][j] + bias[col];
                if (leaky) v = v > 0.f ? v : NEG_SLOPE * v;
                Cm[(size_t)row * N + col] = v;
            }
        }
    }
}

// ---------------------------------------------------------------- head: f32 W[K,N] -> bf16 WT[N,K]
__global__ __launch_bounds__(256) void wcvtT_kernel(const float* __restrict__ W,
                                                    u16* __restrict__ WT, int K, int N) {
    int t = blockIdx.x * 256 + threadIdx.x;
    if (t >= K * N) return;
    int k = t / N, n = t % N;
    WT[(size_t)n * K + k] = f2bf(W[t]);
}

// ---------------------------------------------------------------- MFMA GEMM head (bf16 A)
template <int KD, int OUT_BF16>
__global__ __launch_bounds__(256) void gemm_mfma_kernel(const u16* __restrict__ A,
                                                        const u16* __restrict__ BT,
                                                        const float* __restrict__ bias,
                                                        void* __restrict__ Cout,
                                                        int N, int leaky) {
    __shared__ u16 sA[128 * 64];   // elem (r,k) at byte r*128 + ((k*2) ^ ((r&7)<<4))
    __shared__ u16 sB[128 * 64];

    int t = threadIdx.x;
    int wave = t >> 6, lane = t & 63;
    int wm = wave >> 1, wn = wave & 1;
    int row0 = blockIdx.x * 128;
    int col0 = blockIdx.y * 128;

    f32x4 acc[4][4] = {};

    for (int k0 = 0; k0 < KD; k0 += 64) {
        __syncthreads();
#pragma unroll
        for (int i = 0; i < 4; ++i) {
            int li = t + i * 256;
            int r = li >> 3;
            int kc = (li & 7) * 8;
            bf16x8 v = *(const bf16x8*)(A + (size_t)(row0 + r) * KD + k0 + kc);
            *(bf16x8*)((char*)sA + r * 128 + ((kc * 2) ^ ((r & 7) << 4))) = v;
        }
#pragma unroll
        for (int i = 0; i < 4; ++i) {
            int li = t + i * 256;
            int n = li >> 3;
            int kc = (li & 7) * 8;
            bf16x8 v = *(const bf16x8*)(BT + (size_t)(col0 + n) * KD + k0 + kc);
            *(bf16x8*)((char*)sB + n * 128 + ((kc * 2) ^ ((n & 7) << 4))) = v;
        }
        __syncthreads();

#pragma unroll
        for (int kk = 0; kk < 2; ++kk) {
            int kb = kk * 64 + (lane >> 4) * 16;
            bf16x8 af[4], bfr[4];
#pragma unroll
            for (int mi = 0; mi < 4; ++mi) {
                int r = wm * 64 + mi * 16 + (lane & 15);
                af[mi] = *(const bf16x8*)((char*)sA + r * 128 + (kb ^ ((r & 7) << 4)));
            }
#pragma unroll
            for (int ni = 0; ni < 4; ++ni) {
                int n = wn * 64 + ni * 16 + (lane & 15);
                bfr[ni] = *(const bf16x8*)((char*)sB + n * 128 + (kb ^ ((n & 7) << 4)));
            }
#pragma unroll
            for (int mi = 0; mi < 4; ++mi)
#pragma unroll
                for (int ni = 0; ni < 4; ++ni)
                    acc[mi][ni] = __builtin_amdgcn_mfma_f32_16x16x32_bf16(
                        af[mi], bfr[ni], acc[mi][ni], 0, 0, 0);
        }
    }

#pragma unroll
    for (int ni = 0; ni < 4; ++ni) {
        int col = col0 + wn * 64 + ni * 16 + (lane & 15);
        float bs = bias[col];
#pragma unroll
        for (int mi = 0; mi < 4; ++mi) {
#pragma unroll
            for (int r = 0; r < 4; ++r) {
                int row = row0 + wm * 64 + mi * 16 + (lane >> 4) * 4 + r;
                float v = acc[mi][ni][r] + bs;
                if (leaky) v = v > 0.f ? v : NEG_SLOPE * v;
                if (OUT_BF16)
                    ((u16*)Cout)[(size_t)row * N + col] = f2bf(v);
                else
                    ((float*)Cout)[(size_t)row * N + col] = v;
            }
        }
    }
}

// ---------------------------------------------------------------- MFMA GEMM, cat-f32 A (fused cvt)
// A = concat(x1,x2,x3)[row] converted to bf16 in-register. KD=192, BK=64 aligns sources.
__global__ __launch_bounds__(256) void gemm_mfma_cat_kernel(const float* __restrict__ x1,
                                                            const float* __restrict__ x2,
                                                            const float* __restrict__ x3,
                                                            const u16* __restrict__ BT,
                                                            const float* __restrict__ bias,
                                                            u16* __restrict__ Cout,
                                                            int N) {
    __shared__ u16 sA[128 * 64];
    __shared__ u16 sB[128 * 64];

    int t = threadIdx.x;
    int wave = t >> 6, lane = t & 63;
    int wm = wave >> 1, wn = wave & 1;
    int row0 = blockIdx.x * 128;
    int col0 = blockIdx.y * 128;

    f32x4 acc[4][4] = {};

#pragma unroll 1
    for (int k0 = 0; k0 < 192; k0 += 64) {
        const float* src = (k0 == 0) ? x1 : (k0 == 64) ? x2 : x3;
        __syncthreads();
#pragma unroll
        for (int i = 0; i < 4; ++i) {
            int li = t + i * 256;
            int r = li >> 3;
            int kc = (li & 7) * 8;
            const float* sp = src + (size_t)(row0 + r) * 64 + kc;
            float4 a0 = *(const float4*)sp;
            float4 a1 = *(const float4*)(sp + 4);
            bf16x8 v;
            v[0] = (short)f2bf(a0.x); v[1] = (short)f2bf(a0.y);
            v[2] = (short)f2bf(a0.z); v[3] = (short)f2bf(a0.w);
            v[4] = (short)f2bf(a1.x); v[5] = (short)f2bf(a1.y);
            v[6] = (short)f2bf(a1.z); v[7] = (short)f2bf(a1.w);
            *(bf16x8*)((char*)sA + r * 128 + ((kc * 2) ^ ((r & 7) << 4))) = v;
        }
#pragma unroll
        for (int i = 0; i < 4; ++i) {
            int li = t + i * 256;
            int n = li >> 3;
            int kc = (li & 7) * 8;
            bf16x8 v = *(const bf16x8*)(BT + (size_t)(col0 + n) * 192 + k0 + kc);
            *(bf16x8*)((char*)sB + n * 128 + ((kc * 2) ^ ((n & 7) << 4))) = v;
        }
        __syncthreads();

#pragma unroll
        for (int kk = 0; kk < 2; ++kk) {
            int kb = kk * 64 + (lane >> 4) * 16;
            bf16x8 af[4], bfr[4];
#pragma unroll
            for (int mi = 0; mi < 4; ++mi) {
                int r = wm * 64 + mi * 16 + (lane & 15);
                af[mi] = *(const bf16x8*)((char*)sA + r * 128 + (kb ^ ((r & 7) << 4)));
            }
#pragma unroll
            for (int ni = 0; ni < 4; ++ni) {
                int n = wn * 64 + ni * 16 + (lane & 15);
                bfr[ni] = *(const bf16x8*)((char*)sB + n * 128 + (kb ^ ((n & 7) << 4)));
            }
#pragma unroll
            for (int mi = 0; mi < 4; ++mi)
#pragma unroll
                for (int ni = 0; ni < 4; ++ni)
                    acc[mi][ni] = __builtin_amdgcn_mfma_f32_16x16x32_bf16(
                        af[mi], bfr[ni], acc[mi][ni], 0, 0, 0);
        }
    }

#pragma unroll
    for (int ni = 0; ni < 4; ++ni) {
        int col = col0 + wn * 64 + ni * 16 + (lane & 15);
        float bs = bias[col];
#pragma unroll
        for (int mi = 0; mi < 4; ++mi) {
#pragma unroll
            for (int r = 0; r < 4; ++r) {
                int row = row0 + wm * 64 + mi * 16 + (lane >> 4) * 4 + r;
                float v = acc[mi][ni][r] + bs;
                v = v > 0.f ? v : NEG_SLOPE * v;
                Cout[(size_t)row * N + col] = f2bf(v);
            }
        }
    }
}

// ---------------------------------------------------------------- log_softmax rows of 40
__global__ __launch_bounds__(256) void lsm_kernel(float* __restrict__ out) {
    int row = blockIdx.x * 4 + (threadIdx.x >> 6);
    int lane = threadIdx.x & 63;
    float v = -3.4e38f;
    if (lane < C_) v = out[(size_t)row * C_ + lane];
    float m = v;
#pragma unroll
    for (int s = 1; s < 64; s <<= 1) m = fmaxf(m, __shfl_xor(m, s));
    float e = (lane < C_) ? expf(v - m) : 0.f;
    float sum = e;
#pragma unroll
    for (int s = 1; s < 64; s <<= 1) sum += __shfl_xor(sum, s);
    if (lane < C_) out[(size_t)row * C_ + lane] = v - m - logf(sum);
}

// ----------------------------------------------------------------
extern "C" void kernel_launch(void* const* d_in, const int* in_sizes, int n_in,
                              void* d_out, int out_size, void* d_ws, size_t ws_size,
                              hipStream_t stream) {
    const float* x   = (const float*)d_in[0];
    const float* W1  = (const float*)d_in[2];
    const float* b1  = (const float*)d_in[3];
    const float* W2  = (const float*)d_in[4];
    const float* b2  = (const float*)d_in[5];
    const float* W3  = (const float*)d_in[6];
    const float* b3  = (const float*)d_in[7];
    const float* Wl  = (const float*)d_in[8];
    const float* bl  = (const float*)d_in[9];
    const float* Wm1 = (const float*)d_in[10];
    const float* bm1 = (const float*)d_in[11];
    const float* Wm2 = (const float*)d_in[12];
    const float* bm2 = (const float*)d_in[13];
    const float* Wo  = (const float*)d_in[14];
    const float* bo  = (const float*)d_in[15];
    float* out = (float*)d_out;

    // ---- workspace (max 50,987,008 B — proven footprint) ----
    char* ws = (char*)d_ws;
    float* x1   = (float*)(ws);                       // 8 MB
    float* x2   = (float*)(ws + 8388608);             // 8 MB
    float* x3   = (float*)(ws + 16777216);            // 8 MB
    int*   idx  = (int*)  (ws + 25165824);            // 2.62 MB (knn/edge phase)
    float* d2   = (float*)(ws + 27787264);            // 128 KB
    // region 27,918,336 .. 50,987,008 (23,068,672 B), phase-aliased:
    char* hb = ws + 27918336;
    // knn phase:
    u16*   xhs  = (u16*)(hb);                         // 4 MB
    u16*   xms  = (u16*)(hb + 4194304);               // 4 MB
    u16*   xls  = (u16*)(hb + 8388608);               // 4 MB
    // edge phase:
    float* UV   = (float*)(hb);                       // 16 MB
    float* Wpk  = (float*)(ws + 44695552);
    float* bpk  = (float*)(ws + 44728320);
    // head phase (idx dead -> weights live there; act3 aliases act1):
    u16*   WlT   = (u16*)(ws + 25165824);             // [1024][192] 393,216
    u16*   Wm1T  = (u16*)(ws + 25559040);             // [256][1024] 524,288
    u16*   Wm2T  = (u16*)(ws + 26083328);             // [128][256]   65,536
    u16*   act1  = (u16*)(hb);                        // [8192][1024] 16 MB
    u16*   act2  = (u16*)(hb + 16777216);             // [8192][256]   4 MB
    float* act3  = (float*)(hb);                      // [8192][128] f32 4 MB (alias act1)

    // ---- layer 1 (D=3)
    d2_kernel<3><<<NPT / 256, 256, 0, stream>>>(x, d2);
    knnf_kernel<3><<<dim3(P_ / 64, B_), 256, 0, stream>>>(x, d2, idx);
    uv3_kernel<<<NPT * 128 / 256, 256, 0, stream>>>(x, W1, b1, UV);
    edgemax_kernel<<<NPT / 4, 256, 0, stream>>>(UV, idx, x1);
    // ---- layer 2 (D=64)
    d2_kernel<64><<<NPT / 256, 256, 0, stream>>>(x1, d2);
    cvt3_kernel<<<NPT * 64 / 256, 256, 0, stream>>>(x1, xhs, xms, xls);
    knnm64_kernel<<<dim3(P_ / 64, B_), 256, 0, stream>>>(xhs, xms, xls, d2, idx);
    pack_kernel<<<64, 128, 0, stream>>>(W2, b2, Wpk, bpk);
    gemm_kernel<<<dim3(NPT / 64, 2), 256, 0, stream>>>(x1, Wpk, bpk, UV, NPT, 128, 64, 0);
    edgemax_kernel<<<NPT / 4, 256, 0, stream>>>(UV, idx, x2);
    // ---- layer 3 (D=64)
    d2_kernel<64><<<NPT / 256, 256, 0, stream>>>(x2, d2);
    cvt3_kernel<<<NPT * 64 / 256, 256, 0, stream>>>(x2, xhs, xms, xls);
    knnm64_kernel<<<dim3(P_ / 64, B_), 256, 0, stream>>>(xhs, xms, xls, d2, idx);
    pack_kernel<<<64, 128, 0, stream>>>(W3, b3, Wpk, bpk);
    gemm_kernel<<<dim3(NPT / 64, 2), 256, 0, stream>>>(x2, Wpk, bpk, UV, NPT, 128, 64, 0);
    edgemax_kernel<<<NPT / 4, 256, 0, stream>>>(UV, idx, x3);

    // ---- MLP head: 4 chunks of 8192 rows, fused cvt in first GEMM
    wcvtT_kernel<<<(192 * 1024 + 255) / 256, 256, 0, stream>>>(Wl, WlT, 192, 1024);
    wcvtT_kernel<<<(1024 * 256 + 255) / 256, 256, 0, stream>>>(Wm1, Wm1T, 1024, 256);
    wcvtT_kernel<<<(256 * 128 + 255) / 256, 256, 0, stream>>>(Wm2, Wm2T, 256, 128);

    for (int c = 0; c < 4; ++c) {
        size_t r0 = (size_t)c * 8192;
        gemm_mfma_cat_kernel<<<dim3(64, 8), 256, 0, stream>>>(x1 + r0 * 64, x2 + r0 * 64,
                                                              x3 + r0 * 64, WlT, bl, act1, 1024);
        gemm_mfma_kernel<1024, 1><<<dim3(64, 2), 256, 0, stream>>>(act1, Wm1T, bm1, act2, 256, 1);
        gemm_mfma_kernel<256, 0><<<dim3(64, 1), 256, 0, stream>>>(act2, Wm2T, bm2, act3, 128, 1);
        gemm_kernel<<<dim3(128, 1), 256, 0, stream>>>(act3, Wo, bo, out + r0 * C_, 8192, 40, 128, 0);
    }
    lsm_kernel<<<NPT / 4, 256, 0, stream>>>(out);
}

// Round 15
// 1047.673 us; speedup vs baseline: 1.4727x; 1.0589x over previous
//
#include <hip/hip_runtime.h>
#include <cstddef>
#include <cstdint>

constexpr int B_ = 8, P_ = 4096, K_ = 20, H_ = 64, C_ = 40;
constexpr int NPT = B_ * P_;
#define NEG_SLOPE 0.2f

typedef unsigned long long u64;
typedef unsigned int u32;
typedef unsigned short u16;
typedef __attribute__((ext_vector_type(8))) short bf16x8;
typedef __attribute__((ext_vector_type(4))) float f32x4;

__device__ inline u16 f2bf(float v) {   // round-to-nearest-even bf16
    u32 bits = __float_as_uint(v);
    return (u16)((bits + 0x7FFFu + ((bits >> 16) & 1)) >> 16);
}
__device__ inline float bf2f(u16 h) { return __uint_as_float((u32)h << 16); }

__device__ __forceinline__ void bubble20(double (&a)[K_], double key) {
    double carry = key;
#pragma unroll
    for (int s = 0; s < K_; ++s) {
        double as = a[s];
        a[s]  = fmin(carry, as);
        carry = fmax(carry, as);
    }
}

// ---------------------------------------------------------------- d2 = sum(x*x) (layer 1, D=3)
template <int D>
__global__ __launch_bounds__(256) void d2_kernel(const float* __restrict__ x,
                                                 float* __restrict__ d2) {
    int i = blockIdx.x * 256 + threadIdx.x;
    if (i >= NPT) return;
    const float* r = x + (size_t)i * D;
    float s = 0.f;
#pragma unroll
    for (int d = 0; d < D; ++d) { float v = r[d]; s += v * v; }
    d2[i] = s;
}

// ---------------------------------------------------------------- fused d2 + h/m/l split (D=64)
// d2 accumulation order identical to old d2_kernel<64> (bitwise-same keys).
__global__ __launch_bounds__(256) void d2cvt3_kernel(const float* __restrict__ x,
                                                     float* __restrict__ d2,
                                                     u16* __restrict__ xh,
                                                     u16* __restrict__ xm,
                                                     u16* __restrict__ xl) {
    int i = blockIdx.x * 256 + threadIdx.x;
    if (i >= NPT) return;
    const float* r = x + (size_t)i * 64;
    float s = 0.f;
#pragma unroll
    for (int d8 = 0; d8 < 64; d8 += 8) {
        float4 v0 = *(const float4*)(r + d8);
        float4 v1 = *(const float4*)(r + d8 + 4);
        s += v0.x * v0.x + v0.y * v0.y + v0.z * v0.z + v0.w * v0.w;
        s += v1.x * v1.x + v1.y * v1.y + v1.z * v1.z + v1.w * v1.w;
        float av[8] = {v0.x, v0.y, v0.z, v0.w, v1.x, v1.y, v1.z, v1.w};
        bf16x8 vh, vm, vl;
#pragma unroll
        for (int j = 0; j < 8; ++j) {
            u16 h = f2bf(av[j]);
            float r1 = av[j] - bf2f(h);
            u16 m = f2bf(r1);
            float r2 = r1 - bf2f(m);
            vh[j] = (short)h; vm[j] = (short)m; vl[j] = (short)f2bf(r2);
        }
        *(bf16x8*)(xh + (size_t)i * 64 + d8) = vh;
        *(bf16x8*)(xm + (size_t)i * 64 + d8) = vm;
        *(bf16x8*)(xl + (size_t)i * 64 + d8) = vl;
    }
    d2[i] = s;
}

// ---------------------------------------------------------------- layer-1 fused knn (D=3), depth-4 pending
template <int D>
__global__ __launch_bounds__(256) void knnf_kernel(const float* __restrict__ x,
                                                   const float* __restrict__ d2,
                                                   int* __restrict__ idx) {
    __shared__ float sQT[D][68];
    __shared__ float sCT[D][68];
    __shared__ float sD[64][68];

    int b = blockIdx.y;
    int q0 = blockIdx.x * 64;
    const float* xc  = x + (size_t)b * P_ * D;
    const float* d2b = d2 + (size_t)b * P_;

    int t = threadIdx.x;
    int ty = t >> 4, tx = t & 15;
    int w = t >> 6, ln = t & 63;
    int qs = w * 16 + (ln >> 2);
    int cs = ln & 3;

    if (t < 64) {
#pragma unroll
        for (int d = 0; d < D; ++d) sQT[d][t] = xc[(size_t)(q0 + t) * D + d];
    }
    float qd2i[4];
#pragma unroll
    for (int i = 0; i < 4; ++i) qd2i[i] = d2b[q0 + ty * 4 + i];

    double a[K_];
#pragma unroll
    for (int s = 0; s < K_; ++s)
        a[s] = __longlong_as_double((0x7F7FFFFFLL << 32) | (long long)(0xFFFF0000u + s));
    const double PINV = __longlong_as_double(0x7FE0000000000000LL);
    const double BIG  = __longlong_as_double((0x7F7FFFFFLL << 32) | 0xFFFFFFF0LL);

    double p0 = PINV, p1 = PINV, p2 = PINV, p3 = PINV;
    int pcnt = 0;
    float kthr = __uint_as_float(0x7F7FFFFFu);   // FLT_MAX

#pragma unroll 1
    for (int c0 = 0; c0 < P_; c0 += 64) {
        __syncthreads();
        if (t < 64) {
#pragma unroll
            for (int d = 0; d < D; ++d) sCT[d][t] = xc[(size_t)(c0 + t) * D + d];
        }
        __syncthreads();

        float acc[4][4] = {};
#pragma unroll
        for (int kk = 0; kk < D; ++kk) {
            float4 aq = *(const float4*)&sQT[kk][ty * 4];
            float4 bc = *(const float4*)&sCT[kk][tx * 4];
            acc[0][0] = fmaf(aq.x, bc.x, acc[0][0]); acc[0][1] = fmaf(aq.x, bc.y, acc[0][1]);
            acc[0][2] = fmaf(aq.x, bc.z, acc[0][2]); acc[0][3] = fmaf(aq.x, bc.w, acc[0][3]);
            acc[1][0] = fmaf(aq.y, bc.x, acc[1][0]); acc[1][1] = fmaf(aq.y, bc.y, acc[1][1]);
            acc[1][2] = fmaf(aq.y, bc.z, acc[1][2]); acc[1][3] = fmaf(aq.y, bc.w, acc[1][3]);
            acc[2][0] = fmaf(aq.z, bc.x, acc[2][0]); acc[2][1] = fmaf(aq.z, bc.y, acc[2][1]);
            acc[2][2] = fmaf(aq.z, bc.z, acc[2][2]); acc[2][3] = fmaf(aq.z, bc.w, acc[2][3]);
            acc[3][0] = fmaf(aq.w, bc.x, acc[3][0]); acc[3][1] = fmaf(aq.w, bc.y, acc[3][1]);
            acc[3][2] = fmaf(aq.w, bc.z, acc[3][2]); acc[3][3] = fmaf(aq.w, bc.w, acc[3][3]);
        }
        float cd2j[4];
#pragma unroll
        for (int j = 0; j < 4; ++j) cd2j[j] = d2b[c0 + tx * 4 + j];
        bool diag = (q0 == c0);
#pragma unroll
        for (int i = 0; i < 4; ++i) {
            float dd[4];
#pragma unroll
            for (int j = 0; j < 4; ++j) {
                float v = (qd2i[i] + cd2j[j]) - 2.f * acc[i][j];
                if (diag && (ty * 4 + i == tx * 4 + j)) v += 1e10f;
                dd[j] = fmaxf(v, 0.f);
            }
            *(float4*)&sD[ty * 4 + i][tx * 4] = make_float4(dd[0], dd[1], dd[2], dd[3]);
        }
        __syncthreads();

        float dvv[16];
        float mn = 3.4e38f;
#pragma unroll
        for (int u = 0; u < 16; ++u) {
            dvv[u] = sD[qs][cs + u * 4];
            mn = fminf(mn, dvv[u]);
        }
        if (__any(mn <= kthr)) {
#pragma unroll
            for (int u = 0; u < 16; ++u) {
                float dv = dvv[u];
                if (__any(dv <= kthr)) {
                    u64 kb = ((u64)__float_as_uint(dv) << 32) | (u32)(c0 + cs + u * 4);
                    double key = __longlong_as_double((long long)kb);
                    bool pass = key < a[K_ - 1];
                    p3 = pass ? p2 : p3;
                    p2 = pass ? p1 : p2;
                    p1 = pass ? p0 : p1;
                    p0 = pass ? key : p0;
                    pcnt = pass ? pcnt + 1 : pcnt;
                    if (__any(pcnt >= 4)) {
                        bubble20(a, p3); bubble20(a, p2); bubble20(a, p1); bubble20(a, p0);
                        p0 = p1 = p2 = p3 = PINV; pcnt = 0;
                        kthr = __uint_as_float((u32)(__double_as_longlong(a[K_ - 1]) >> 32));
                    }
                }
            }
        }
    }
    // final flush
    bubble20(a, p3); bubble20(a, p2); bubble20(a, p1); bubble20(a, p0);

    int* op = idx + ((size_t)(b * P_ + q0 + qs)) * K_;
#pragma unroll 1
    for (int k = 0; k < K_; ++k) {
        double v = a[0];
        double v1 = __shfl_xor(v, 1);
        v = fmin(v, v1);
        double v2 = __shfl_xor(v, 2);
        v = fmin(v, v2);
        bool win = (__double_as_longlong(a[0]) == __double_as_longlong(v));
#pragma unroll
        for (int s = 0; s < K_ - 1; ++s) a[s] = win ? a[s + 1] : a[s];
        a[K_ - 1] = win ? BIG : a[K_ - 1];
        if (cs == 0)
            op[k] = b * P_ + (int)(__double_as_longlong(v) & 0xFFFFFFFFLL);
    }
}

// ---------------------------------------------------------------- fused knn (D=64) via MFMA, depth-4 pending
__global__ __launch_bounds__(256) void knnm64_kernel(const u16* __restrict__ xh,
                                                     const u16* __restrict__ xm,
                                                     const u16* __restrict__ xl,
                                                     const float* __restrict__ d2,
                                                     int* __restrict__ idx) {
    __shared__ u16 sH[64 * 64];      // elem (r,k) at byte r*128 + ((k*2) ^ ((r&7)<<4))
    __shared__ u16 sM[64 * 64];
    __shared__ u16 sL[64 * 64];
    __shared__ float sd2[P_];        // 16 KB

    int b = blockIdx.y;
    int q0 = blockIdx.x * 64;
    const u16* xhb = xh + (size_t)b * P_ * 64;
    const u16* xmb = xm + (size_t)b * P_ * 64;
    const u16* xlb = xl + (size_t)b * P_ * 64;
    const float* d2b = d2 + (size_t)b * P_;

    int t = threadIdx.x, w = t >> 6, ln = t & 63;
    int q  = ln & 15;
    int ss = ln >> 4;

    for (int i = t; i < P_ / 4; i += 256)
        ((float4*)sd2)[i] = ((const float4*)d2b)[i];

    int qrow = q0 + w * 16 + q;
    bf16x8 qh[2], qm[2], ql[2];
#pragma unroll
    for (int kt = 0; kt < 2; ++kt) {
        size_t off = (size_t)qrow * 64 + kt * 32 + ss * 8;
        qh[kt] = *(const bf16x8*)(xhb + off);
        qm[kt] = *(const bf16x8*)(xmb + off);
        ql[kt] = *(const bf16x8*)(xlb + off);
    }

    __syncthreads();
    float qd2 = sd2[qrow];

    double a[K_];
#pragma unroll
    for (int s = 0; s < K_; ++s)
        a[s] = __longlong_as_double((0x7F7FFFFFLL << 32) | (long long)(0xFFFF0000u + s));
    const double BIG  = __longlong_as_double((0x7F7FFFFFLL << 32) | 0xFFFFFFF0LL);
    const double PINV = __longlong_as_double(0x7FE0000000000000LL);

    double p0 = PINV, p1 = PINV, p2 = PINV, p3 = PINV;
    int pcnt = 0;
    float kthr = __uint_as_float(0x7F7FFFFFu);

    int sr = t >> 2;
    int sk2 = (t & 3) * 32;
    int sbase = sr * 128, sswz = (sr & 7) << 4;
    size_t sgof = (size_t)sr * 64 + (t & 3) * 16;

#pragma unroll 1
    for (int c0 = 0; c0 < P_; c0 += 64) {
        __syncthreads();
        {
            size_t g = (size_t)c0 * 64 + sgof;
            bf16x8 h0 = *(const bf16x8*)(xhb + g);
            bf16x8 h1 = *(const bf16x8*)(xhb + g + 8);
            bf16x8 m0 = *(const bf16x8*)(xmb + g);
            bf16x8 m1 = *(const bf16x8*)(xmb + g + 8);
            bf16x8 l0 = *(const bf16x8*)(xlb + g);
            bf16x8 l1 = *(const bf16x8*)(xlb + g + 8);
            *(bf16x8*)((char*)sH + sbase + (sk2 ^ sswz)) = h0;
            *(bf16x8*)((char*)sH + sbase + ((sk2 + 16) ^ sswz)) = h1;
            *(bf16x8*)((char*)sM + sbase + (sk2 ^ sswz)) = m0;
            *(bf16x8*)((char*)sM + sbase + ((sk2 + 16) ^ sswz)) = m1;
            *(bf16x8*)((char*)sL + sbase + (sk2 ^ sswz)) = l0;
            *(bf16x8*)((char*)sL + sbase + ((sk2 + 16) ^ sswz)) = l1;
        }
        __syncthreads();

        f32x4 acc[4];
#pragma unroll
        for (int nt = 0; nt < 4; ++nt) {
            acc[nt] = (f32x4){0.f, 0.f, 0.f, 0.f};
            int r = nt * 16 + q;
            int base = r * 128, swz = (r & 7) << 4;
#pragma unroll
            for (int kt = 0; kt < 2; ++kt) {
                int k2 = kt * 64 + ss * 16;
                bf16x8 ch = *(const bf16x8*)((char*)sH + base + (k2 ^ swz));
                bf16x8 cm = *(const bf16x8*)((char*)sM + base + (k2 ^ swz));
                bf16x8 cl = *(const bf16x8*)((char*)sL + base + (k2 ^ swz));
                acc[nt] = __builtin_amdgcn_mfma_f32_16x16x32_bf16(cm, qm[kt], acc[nt], 0, 0, 0);
                acc[nt] = __builtin_amdgcn_mfma_f32_16x16x32_bf16(cl, qh[kt], acc[nt], 0, 0, 0);
                acc[nt] = __builtin_amdgcn_mfma_f32_16x16x32_bf16(ch, ql[kt], acc[nt], 0, 0, 0);
                acc[nt] = __builtin_amdgcn_mfma_f32_16x16x32_bf16(cm, qh[kt], acc[nt], 0, 0, 0);
                acc[nt] = __builtin_amdgcn_mfma_f32_16x16x32_bf16(ch, qm[kt], acc[nt], 0, 0, 0);
                acc[nt] = __builtin_amdgcn_mfma_f32_16x16x32_bf16(ch, qh[kt], acc[nt], 0, 0, 0);
            }
        }

        float dvv[4][4];
        float mn = 3.4e38f;
#pragma unroll
        for (int nt = 0; nt < 4; ++nt) {
#pragma unroll
            for (int r = 0; r < 4; ++r) {
                int cID = c0 + nt * 16 + ss * 4 + r;
                float dv = (qd2 + sd2[cID]) - 2.f * acc[nt][r];
                if (cID == qrow) dv += 1e10f;
                dv = fmaxf(dv, 0.f);
                dvv[nt][r] = dv;
                mn = fminf(mn, dv);
            }
        }
        if (__any(mn <= kthr)) {
#pragma unroll
            for (int nt = 0; nt < 4; ++nt) {
#pragma unroll
                for (int r = 0; r < 4; ++r) {
                    float dv = dvv[nt][r];
                    if (__any(dv <= kthr)) {
                        int cID = c0 + nt * 16 + ss * 4 + r;
                        u64 kb = ((u64)__float_as_uint(dv) << 32) | (u32)cID;
                        double key = __longlong_as_double((long long)kb);
                        bool pass = key < a[K_ - 1];
                        p3 = pass ? p2 : p3;
                        p2 = pass ? p1 : p2;
                        p1 = pass ? p0 : p1;
                        p0 = pass ? key : p0;
                        pcnt = pass ? pcnt + 1 : pcnt;
                        if (__any(pcnt >= 4)) {
                            bubble20(a, p3); bubble20(a, p2); bubble20(a, p1); bubble20(a, p0);
                            p0 = p1 = p2 = p3 = PINV; pcnt = 0;
                            kthr = __uint_as_float((u32)(__double_as_longlong(a[K_ - 1]) >> 32));
                        }
                    }
                }
            }
        }
    }
    // final flush
    bubble20(a, p3); bubble20(a, p2); bubble20(a, p1); bubble20(a, p0);

    int* op = idx + ((size_t)(b * P_ + qrow)) * K_;
#pragma unroll 1
    for (int k = 0; k < K_; ++k) {
        double v = a[0];
        double v1 = __shfl_xor(v, 16);
        v = fmin(v, v1);
        double v2 = __shfl_xor(v, 32);
        v = fmin(v, v2);
        bool win = (__double_as_longlong(a[0]) == __double_as_longlong(v));
#pragma unroll
        for (int s = 0; s < K_ - 1; ++s) a[s] = win ? a[s + 1] : a[s];
        a[K_ - 1] = win ? BIG : a[K_ - 1];
        if (ss == 0)
            op[k] = b * P_ + (int)(__double_as_longlong(v) & 0xFFFFFFFFLL);
    }
}

// ---------------------------------------------------------------- one-shot weight prep
// [0,8192) pack W2; [8192,16384) pack W3; then bf16-transpose Wl, Wm1, Wm2.
__global__ __launch_bounds__(256) void prep_kernel(const float* __restrict__ W2,
                                                   const float* __restrict__ b2,
                                                   const float* __restrict__ W3,
                                                   const float* __restrict__ b3,
                                                   const float* __restrict__ Wl,
                                                   const float* __restrict__ Wm1,
                                                   const float* __restrict__ Wm2,
                                                   float* __restrict__ Wpk2, float* __restrict__ bpk2,
                                                   float* __restrict__ Wpk3, float* __restrict__ bpk3,
                                                   u16* __restrict__ WlT,
                                                   u16* __restrict__ Wm1T,
                                                   u16* __restrict__ Wm2T) {
    int t = blockIdx.x * 256 + threadIdx.x;
    if (t < 8192) {
        int d = t >> 7, h2 = t & 127;
        Wpk2[t] = (h2 < 64) ? W2[d * 64 + h2] : W2[(64 + d) * 64 + (h2 - 64)];
        if (t < 128) bpk2[t] = (t < 64) ? b2[t] : 0.f;
    } else if (t < 16384) {
        int t2 = t - 8192;
        int d = t2 >> 7, h2 = t2 & 127;
        Wpk3[t2] = (h2 < 64) ? W3[d * 64 + h2] : W3[(64 + d) * 64 + (h2 - 64)];
        if (t2 < 128) bpk3[t2] = (t2 < 64) ? b3[t2] : 0.f;
    } else if (t < 212992) {
        int t2 = t - 16384;            // K=192, N=1024
        int k = t2 >> 10, n = t2 & 1023;
        WlT[(size_t)n * 192 + k] = f2bf(Wl[t2]);
    } else if (t < 475136) {
        int t2 = t - 212992;           // K=1024, N=256
        int k = t2 >> 8, n = t2 & 255;
        Wm1T[(size_t)n * 1024 + k] = f2bf(Wm1[t2]);
    } else if (t < 507904) {
        int t2 = t - 475136;           // K=256, N=128
        int k = t2 >> 7, n = t2 & 127;
        Wm2T[(size_t)n * 256 + k] = f2bf(Wm2[t2]);
    }
}

// ---------------------------------------------------------------- layer-1 UV (D=3, direct)
__global__ __launch_bounds__(256) void uv3_kernel(const float* __restrict__ x,
                                                  const float* __restrict__ W,
                                                  const float* __restrict__ b,
                                                  float* __restrict__ UV) {
    int t = blockIdx.x * 256 + threadIdx.x;
    int p = t >> 7, h2 = t & 127;
    float x0 = x[p * 3], x1 = x[p * 3 + 1], x2 = x[p * 3 + 2];
    float r;
    if (h2 < 64) {
        r = b[h2] + x0 * W[h2] + x1 * W[64 + h2] + x2 * W[128 + h2];
    } else {
        int h = h2 - 64;
        r = x0 * W[192 + h] + x1 * W[256 + h] + x2 * W[320 + h];
    }
    UV[t] = r;
}

// ---------------------------------------------------------------- edge max
__global__ __launch_bounds__(256) void edgemax_kernel(const float* __restrict__ UV,
                                                      const int* __restrict__ idx,
                                                      float* __restrict__ xout) {
    int wv = threadIdx.x >> 6, lane = threadIdx.x & 63;
    int p = blockIdx.x * 4 + wv;
    const float* uvp = UV + (size_t)p * 128;
    float duv = uvp[lane] - uvp[64 + lane];
    const int* ip = idx + (size_t)p * K_;
    int jj[K_];
#pragma unroll
    for (int k = 0; k < K_; ++k) jj[k] = ip[k];
    float m = -3.4e38f;
#pragma unroll
    for (int k = 0; k < K_; ++k) {
        float vj = UV[(size_t)jj[k] * 128 + 64 + lane];
        float t = duv + vj;
        m = fmaxf(m, fmaxf(t, NEG_SLOPE * t));
    }
    xout[(size_t)p * H_ + lane] = m;
}

// ---------------------------------------------------------------- GEMM 64x64 f32 (UV)
__global__ __launch_bounds__(256) void gemm_kernel(const float* __restrict__ A1,
                                                   const float* __restrict__ Wm,
                                                   const float* __restrict__ bias,
                                                   float* __restrict__ Cm,
                                                   int M, int N, int Kd, int leaky) {
    __shared__ float sA[32][68];
    __shared__ float sB[32][68];

    int tid = threadIdx.x;
    int row0 = blockIdx.x * 64, col0 = blockIdx.y * 64;
    int tx = tid & 15, ty = tid >> 4;

    int lr  = tid >> 2;
    int lk4 = (tid & 3) * 4;
    int lkb = tid >> 4;
    int lnb = (tid & 15) * 4;

    float acc[4][4] = {};

    for (int k0 = 0; k0 < Kd; k0 += 32) {
        int arow = row0 + lr;
#pragma unroll
        for (int h = 0; h < 32; h += 16) {
            int kk = k0 + lk4 + h;
            const float* src = A1 + (size_t)arow * Kd + kk;
            float4 av = *(const float4*)src;
            sA[lk4 + h + 0][lr] = av.x; sA[lk4 + h + 1][lr] = av.y;
            sA[lk4 + h + 2][lr] = av.z; sA[lk4 + h + 3][lr] = av.w;
        }
        int bcol = col0 + lnb;
#pragma unroll
        for (int h = 0; h < 32; h += 16) {
            float4 bv = make_float4(0.f, 0.f, 0.f, 0.f);
            if (bcol < N) bv = *(const float4*)(Wm + (size_t)(k0 + lkb + h) * N + bcol);
            *(float4*)&sB[lkb + h][lnb] = bv;
        }
        __syncthreads();

#pragma unroll
        for (int kk2 = 0; kk2 < 32; ++kk2) {
            float4 a = *(const float4*)&sA[kk2][ty * 4];
            float4 bb = *(const float4*)&sB[kk2][tx * 4];
            acc[0][0] = fmaf(a.x, bb.x, acc[0][0]); acc[0][1] = fmaf(a.x, bb.y, acc[0][1]);
            acc[0][2] = fmaf(a.x, bb.z, acc[0][2]); acc[0][3] = fmaf(a.x, bb.w, acc[0][3]);
            acc[1][0] = fmaf(a.y, bb.x, acc[1][0]); acc[1][1] = fmaf(a.y, bb.y, acc[1][1]);
            acc[1][2] = fmaf(a.y, bb.z, acc[1][2]); acc[1][3] = fmaf(a.y, bb.w, acc[1][3]);
            acc[2][0] = fmaf(a.z, bb.x, acc[2][0]); acc[2][1] = fmaf(a.z, bb.y, acc[2][1]);
            acc[2][2] = fmaf(a.z, bb.z, acc[2][2]); acc[2][3] = fmaf(a.z, bb.w, acc[2][3]);
            acc[3][0] = fmaf(a.w, bb.x, acc[3][0]); acc[3][1] = fmaf(a.w, bb.y, acc[3][1]);
            acc[3][2] = fmaf(a.w, bb.z, acc[3][2]); acc[3][3] = fmaf(a.w, bb.w, acc[3][3]);
        }
        __syncthreads();
    }

    for (int i = 0; i < 4; ++i) {
        int row = row0 + ty * 4 + i;
        for (int j = 0; j < 4; ++j) {
            int col = col0 + tx * 4 + j;
            if (col < N) {
                float v = acc[i][j] + bias[col];
                if (leaky) v = v > 0.f ? v : NEG_SLOPE * v;
                Cm[(size_t)row * N + col] = v;
            }
        }
    }
}

// ---------------------------------------------------------------- MFMA GEMM head (bf16 A)
template <int KD, int OUT_BF16>
__global__ __launch_bounds__(256) void gemm_mfma_kernel(const u16* __restrict__ A,
                                                        const u16* __restrict__ BT,
                                                        const float* __restrict__ bias,
                                                        void* __restrict__ Cout,
                                                        int N, int leaky) {
    __shared__ u16 sA[128 * 64];   // elem (r,k) at byte r*128 + ((k*2) ^ ((r&7)<<4))
    __shared__ u16 sB[128 * 64];

    int t = threadIdx.x;
    int wave = t >> 6, lane = t & 63;
    int wm = wave >> 1, wn = wave & 1;
    int row0 = blockIdx.x * 128;
    int col0 = blockIdx.y * 128;

    f32x4 acc[4][4] = {};

    for (int k0 = 0; k0 < KD; k0 += 64) {
        __syncthreads();
#pragma unroll
        for (int i = 0; i < 4; ++i) {
            int li = t + i * 256;
            int r = li >> 3;
            int kc = (li & 7) * 8;
            bf16x8 v = *(const bf16x8*)(A + (size_t)(row0 + r) * KD + k0 + kc);
            *(bf16x8*)((char*)sA + r * 128 + ((kc * 2) ^ ((r & 7) << 4))) = v;
        }
#pragma unroll
        for (int i = 0; i < 4; ++i) {
            int li = t + i * 256;
            int n = li >> 3;
            int kc = (li & 7) * 8;
            bf16x8 v = *(const bf16x8*)(BT + (size_t)(col0 + n) * KD + k0 + kc);
            *(bf16x8*)((char*)sB + n * 128 + ((kc * 2) ^ ((n & 7) << 4))) = v;
        }
        __syncthreads();

#pragma unroll
        for (int kk = 0; kk < 2; ++kk) {
            int kb = kk * 64 + (lane >> 4) * 16;
            bf16x8 af[4], bfr[4];
#pragma unroll
            for (int mi = 0; mi < 4; ++mi) {
                int r = wm * 64 + mi * 16 + (lane & 15);
                af[mi] = *(const bf16x8*)((char*)sA + r * 128 + (kb ^ ((r & 7) << 4)));
            }
#pragma unroll
            for (int ni = 0; ni < 4; ++ni) {
                int n = wn * 64 + ni * 16 + (lane & 15);
                bfr[ni] = *(const bf16x8*)((char*)sB + n * 128 + (kb ^ ((n & 7) << 4)));
            }
#pragma unroll
            for (int mi = 0; mi < 4; ++mi)
#pragma unroll
                for (int ni = 0; ni < 4; ++ni)
                    acc[mi][ni] = __builtin_amdgcn_mfma_f32_16x16x32_bf16(
                        af[mi], bfr[ni], acc[mi][ni], 0, 0, 0);
        }
    }

#pragma unroll
    for (int ni = 0; ni < 4; ++ni) {
        int col = col0 + wn * 64 + ni * 16 + (lane & 15);
        float bs = bias[col];
#pragma unroll
        for (int mi = 0; mi < 4; ++mi) {
#pragma unroll
            for (int r = 0; r < 4; ++r) {
                int row = row0 + wm * 64 + mi * 16 + (lane >> 4) * 4 + r;
                float v = acc[mi][ni][r] + bs;
                if (leaky) v = v > 0.f ? v : NEG_SLOPE * v;
                if (OUT_BF16)
                    ((u16*)Cout)[(size_t)row * N + col] = f2bf(v);
                else
                    ((float*)Cout)[(size_t)row * N + col] = v;
            }
        }
    }
}

// ---------------------------------------------------------------- MFMA GEMM, cat-f32 A (fused cvt)
__global__ __launch_bounds__(256) void gemm_mfma_cat_kernel(const float* __restrict__ x1,
                                                            const float* __restrict__ x2,
                                                            const float* __restrict__ x3,
                                                            const u16* __restrict__ BT,
                                                            const float* __restrict__ bias,
                                                            u16* __restrict__ Cout,
                                                            int N) {
    __shared__ u16 sA[128 * 64];
    __shared__ u16 sB[128 * 64];

    int t = threadIdx.x;
    int wave = t >> 6, lane = t & 63;
    int wm = wave >> 1, wn = wave & 1;
    int row0 = blockIdx.x * 128;
    int col0 = blockIdx.y * 128;

    f32x4 acc[4][4] = {};

#pragma unroll 1
    for (int k0 = 0; k0 < 192; k0 += 64) {
        const float* src = (k0 == 0) ? x1 : (k0 == 64) ? x2 : x3;
        __syncthreads();
#pragma unroll
        for (int i = 0; i < 4; ++i) {
            int li = t + i * 256;
            int r = li >> 3;
            int kc = (li & 7) * 8;
            const float* sp = src + (size_t)(row0 + r) * 64 + kc;
            float4 a0 = *(const float4*)sp;
            float4 a1 = *(const float4*)(sp + 4);
            bf16x8 v;
            v[0] = (short)f2bf(a0.x); v[1] = (short)f2bf(a0.y);
            v[2] = (short)f2bf(a0.z); v[3] = (short)f2bf(a0.w);
            v[4] = (short)f2bf(a1.x); v[5] = (short)f2bf(a1.y);
            v[6] = (short)f2bf(a1.z); v[7] = (short)f2bf(a1.w);
            *(bf16x8*)((char*)sA + r * 128 + ((kc * 2) ^ ((r & 7) << 4))) = v;
        }
#pragma unroll
        for (int i = 0; i < 4; ++i) {
            int li = t + i * 256;
            int n = li >> 3;
            int kc = (li & 7) * 8;
            bf16x8 v = *(const bf16x8*)(BT + (size_t)(col0 + n) * 192 + k0 + kc);
            *(bf16x8*)((char*)sB + n * 128 + ((kc * 2) ^ ((n & 7) << 4))) = v;
        }
        __syncthreads();

#pragma unroll
        for (int kk = 0; kk < 2; ++kk) {
            int kb = kk * 64 + (lane >> 4) * 16;
            bf16x8 af[4], bfr[4];
#pragma unroll
            for (int mi = 0; mi < 4; ++mi) {
                int r = wm * 64 + mi * 16 + (lane & 15);
                af[mi] = *(const bf16x8*)((char*)sA + r * 128 + (kb ^ ((r & 7) << 4)));
            }
#pragma unroll
            for (int ni = 0; ni < 4; ++ni) {
                int n = wn * 64 + ni * 16 + (lane & 15);
                bfr[ni] = *(const bf16x8*)((char*)sB + n * 128 + (kb ^ ((n & 7) << 4)));
            }
#pragma unroll
            for (int mi = 0; mi < 4; ++mi)
#pragma unroll
                for (int ni = 0; ni < 4; ++ni)
                    acc[mi][ni] = __builtin_amdgcn_mfma_f32_16x16x32_bf16(
                        af[mi], bfr[ni], acc[mi][ni], 0, 0, 0);
        }
    }

#pragma unroll
    for (int ni = 0; ni < 4; ++ni) {
        int col = col0 + wn * 64 + ni * 16 + (lane & 15);
        float bs = bias[col];
#pragma unroll
        for (int mi = 0; mi < 4; ++mi) {
#pragma unroll
            for (int r = 0; r < 4; ++r) {
                int row = row0 + wm * 64 + mi * 16 + (lane >> 4) * 4 + r;
                float v = acc[mi][ni][r] + bs;
                v = v > 0.f ? v : NEG_SLOPE * v;
                Cout[(size_t)row * N + col] = f2bf(v);
            }
        }
    }
}

// ---------------------------------------------------------------- fused Wo GEMM + log_softmax
// wave per row: lane c<40 computes out[c] = sum_k act[k]*Wo[k][c] + bo[c], then LSM.
__global__ __launch_bounds__(256) void lsm_wo_kernel(const float* __restrict__ act3,
                                                     const float* __restrict__ Wo,
                                                     const float* __restrict__ bo,
                                                     float* __restrict__ out) {
    __shared__ float sWo[128 * 44];   // [k][c], pad 44
    __shared__ float sAct[4][128];

    int t = threadIdx.x;
    for (int i = t; i < 128 * 40; i += 256) {
        int k = i / 40, c = i % 40;
        sWo[k * 44 + c] = Wo[i];
    }
    __syncthreads();

    int wv = t >> 6, lane = t & 63;
    int row = blockIdx.x * 4 + wv;
    sAct[wv][lane]      = act3[(size_t)row * 128 + lane];
    sAct[wv][64 + lane] = act3[(size_t)row * 128 + 64 + lane];
    // same-wave LDS write->read is in-order

    float acc = (lane < C_) ? bo[lane] : -3.4e38f;
    if (lane < C_) {
#pragma unroll 8
        for (int k = 0; k < 128; ++k)
            acc = fmaf(sAct[wv][k], sWo[k * 44 + lane], acc);
    }
    float m = acc;
#pragma unroll
    for (int s = 1; s < 64; s <<= 1) m = fmaxf(m, __shfl_xor(m, s));
    float e = (lane < C_) ? expf(acc - m) : 0.f;
    float sum = e;
#pragma unroll
    for (int s = 1; s < 64; s <<= 1) sum += __shfl_xor(sum, s);
    if (lane < C_) out[(size_t)row * C_ + lane] = acc - m - logf(sum);
}

// ----------------------------------------------------------------
extern "C" void kernel_launch(void* const* d_in, const int* in_sizes, int n_in,
                              void* d_out, int out_size, void* d_ws, size_t ws_size,
                              hipStream_t stream) {
    const float* x   = (const float*)d_in[0];
    const float* W1  = (const float*)d_in[2];
    const float* b1  = (const float*)d_in[3];
    const float* W2  = (const float*)d_in[4];
    const float* b2  = (const float*)d_in[5];
    const float* W3  = (const float*)d_in[6];
    const float* b3  = (const float*)d_in[7];
    const float* Wl  = (const float*)d_in[8];
    const float* bl  = (const float*)d_in[9];
    const float* Wm1 = (const float*)d_in[10];
    const float* bm1 = (const float*)d_in[11];
    const float* Wm2 = (const float*)d_in[12];
    const float* bm2 = (const float*)d_in[13];
    const float* Wo  = (const float*)d_in[14];
    const float* bo  = (const float*)d_in[15];
    float* out = (float*)d_out;

    // ---- workspace (max 50,987,008 B — proven footprint) ----
    char* ws = (char*)d_ws;
    float* x1   = (float*)(ws);                       // 8 MB
    float* x2   = (float*)(ws + 8388608);             // 8 MB
    float* x3   = (float*)(ws + 16777216);            // 8 MB
    int*   idx  = (int*)  (ws + 25165824);            // 2.62 MB
    float* d2   = (float*)(ws + 27787264);            // 128 KB
    char* hb = ws + 27918336;                         // 23,068,672 B phase window
    // knn phase: h/m/l splits (12 MB at hb)
    u16*   xhs  = (u16*)(hb);
    u16*   xms  = (u16*)(hb + 4194304);
    u16*   xls  = (u16*)(hb + 8388608);
    // edge phase: UV (16 MB at hb, ends exactly at 44,695,552)
    float* UV   = (float*)(hb);
    // persistent prep weights @44,695,552 .. 45,745,152 (never aliased):
    float* Wpk2 = (float*)(ws + 44695552);            // 32,768
    float* bpk2 = (float*)(ws + 44728320);            // 512
    float* Wpk3 = (float*)(ws + 44728832);            // 32,768
    float* bpk3 = (float*)(ws + 44761600);            // 512
    u16*   WlT  = (u16*)  (ws + 44762112);            // 393,216
    u16*   Wm1T = (u16*)  (ws + 45155328);            // 524,288
    u16*   Wm2T = (u16*)  (ws + 45679616);            // 65,536 -> ends 45,745,152
    // head phase: act1 @hb (16 MB), act2 @45,745,152 (4 MB -> 49,939,456), act3 aliases act1
    u16*   act1 = (u16*)(hb);
    u16*   act2 = (u16*)(ws + 45745152);
    float* act3 = (float*)(hb);

    // ---- weight prep (one launch)
    prep_kernel<<<1984, 256, 0, stream>>>(W2, b2, W3, b3, Wl, Wm1, Wm2,
                                          Wpk2, bpk2, Wpk3, bpk3, WlT, Wm1T, Wm2T);

    // ---- layer 1 (D=3)
    d2_kernel<3><<<NPT / 256, 256, 0, stream>>>(x, d2);
    knnf_kernel<3><<<dim3(P_ / 64, B_), 256, 0, stream>>>(x, d2, idx);
    uv3_kernel<<<NPT * 128 / 256, 256, 0, stream>>>(x, W1, b1, UV);
    edgemax_kernel<<<NPT / 4, 256, 0, stream>>>(UV, idx, x1);
    // ---- layer 2 (D=64)
    d2cvt3_kernel<<<NPT / 256, 256, 0, stream>>>(x1, d2, xhs, xms, xls);
    knnm64_kernel<<<dim3(P_ / 64, B_), 256, 0, stream>>>(xhs, xms, xls, d2, idx);
    gemm_kernel<<<dim3(NPT / 64, 2), 256, 0, stream>>>(x1, Wpk2, bpk2, UV, NPT, 128, 64, 0);
    edgemax_kernel<<<NPT / 4, 256, 0, stream>>>(UV, idx, x2);
    // ---- layer 3 (D=64)
    d2cvt3_kernel<<<NPT / 256, 256, 0, stream>>>(x2, d2, xhs, xms, xls);
    knnm64_kernel<<<dim3(P_ / 64, B_), 256, 0, stream>>>(xhs, xms, xls, d2, idx);
    gemm_kernel<<<dim3(NPT / 64, 2), 256, 0, stream>>>(x2, Wpk3, bpk3, UV, NPT, 128, 64, 0);
    edgemax_kernel<<<NPT / 4, 256, 0, stream>>>(UV, idx, x3);

    // ---- MLP head: 4 chunks of 8192 rows
    for (int c = 0; c < 4; ++c) {
        size_t r0 = (size_t)c * 8192;
        gemm_mfma_cat_kernel<<<dim3(64, 8), 256, 0, stream>>>(x1 + r0 * 64, x2 + r0 * 64,
                                                              x3 + r0 * 64, WlT, bl, act1, 1024);
        gemm_mfma_kernel<1024, 1><<<dim3(64, 2), 256, 0, stream>>>(act1, Wm1T, bm1, act2, 256, 1);
        gemm_mfma_kernel<256, 0><<<dim3(64, 1), 256, 0, stream>>>(act2, Wm2T, bm2, act3, 128, 1);
        lsm_wo_kernel<<<2048, 256, 0, stream>>>(act3, Wo, bo, out + r0 * C_);
    }
}

// Round 16
// 942.212 us; speedup vs baseline: 1.6376x; 1.1119x over previous
//
#include <hip/hip_runtime.h>
#include <cstddef>
#include <cstdint>

constexpr int B_ = 8, P_ = 4096, K_ = 20, H_ = 64, C_ = 40;
constexpr int NPT = B_ * P_;
#define NEG_SLOPE 0.2f

typedef unsigned long long u64;
typedef unsigned int u32;
typedef unsigned short u16;
typedef __attribute__((ext_vector_type(8))) short bf16x8;
typedef __attribute__((ext_vector_type(4))) float f32x4;

__device__ inline u16 f2bf(float v) {   // round-to-nearest-even bf16
    u32 bits = __float_as_uint(v);
    return (u16)((bits + 0x7FFFu + ((bits >> 16) & 1)) >> 16);
}
__device__ inline float bf2f(u16 h) { return __uint_as_float((u32)h << 16); }

// sorted-ascending 20-slot bubble insert, f32 keys (positive, bit-ordered)
__device__ __forceinline__ void bubble20f(float (&a)[K_], float key) {
    float carry = key;
#pragma unroll
    for (int s = 0; s < K_; ++s) {
        float as = a[s];
        a[s]  = fminf(carry, as);
        carry = fmaxf(carry, as);
    }
}
// key = (dist_bits & ~0xFFF) | cid   (cid < 4096; dist >= 0 finite)
__device__ __forceinline__ float mkkey(float dist, int cid) {
    return __uint_as_float((__float_as_uint(dist) & 0xFFFFF000u) | (u32)cid);
}

// ---------------------------------------------------------------- d2 = sum(x*x) (layer 1, D=3)
template <int D>
__global__ __launch_bounds__(256) void d2_kernel(const float* __restrict__ x,
                                                 float* __restrict__ d2) {
    int i = blockIdx.x * 256 + threadIdx.x;
    if (i >= NPT) return;
    const float* r = x + (size_t)i * D;
    float s = 0.f;
#pragma unroll
    for (int d = 0; d < D; ++d) { float v = r[d]; s += v * v; }
    d2[i] = s;
}

// ---------------------------------------------------------------- fused d2 + h/m/l split (D=64)
__global__ __launch_bounds__(256) void d2cvt3_kernel(const float* __restrict__ x,
                                                     float* __restrict__ d2,
                                                     u16* __restrict__ xh,
                                                     u16* __restrict__ xm,
                                                     u16* __restrict__ xl) {
    int i = blockIdx.x * 256 + threadIdx.x;
    if (i >= NPT) return;
    const float* r = x + (size_t)i * 64;
    float s = 0.f;
#pragma unroll
    for (int d8 = 0; d8 < 64; d8 += 8) {
        float4 v0 = *(const float4*)(r + d8);
        float4 v1 = *(const float4*)(r + d8 + 4);
        s += v0.x * v0.x + v0.y * v0.y + v0.z * v0.z + v0.w * v0.w;
        s += v1.x * v1.x + v1.y * v1.y + v1.z * v1.z + v1.w * v1.w;
        float av[8] = {v0.x, v0.y, v0.z, v0.w, v1.x, v1.y, v1.z, v1.w};
        bf16x8 vh, vm, vl;
#pragma unroll
        for (int j = 0; j < 8; ++j) {
            u16 h = f2bf(av[j]);
            float r1 = av[j] - bf2f(h);
            u16 m = f2bf(r1);
            float r2 = r1 - bf2f(m);
            vh[j] = (short)h; vm[j] = (short)m; vl[j] = (short)f2bf(r2);
        }
        *(bf16x8*)(xh + (size_t)i * 64 + d8) = vh;
        *(bf16x8*)(xm + (size_t)i * 64 + d8) = vm;
        *(bf16x8*)(xl + (size_t)i * 64 + d8) = vl;
    }
    d2[i] = s;
}

// ---------------------------------------------------------------- layer-1 fused knn (D=3), f32 keys
template <int D>
__global__ __launch_bounds__(256) void knnf_kernel(const float* __restrict__ x,
                                                   const float* __restrict__ d2,
                                                   int* __restrict__ idx) {
    __shared__ float sQT[D][68];
    __shared__ float sCT[D][68];
    __shared__ float sD[64][68];

    int b = blockIdx.y;
    int q0 = blockIdx.x * 64;
    const float* xc  = x + (size_t)b * P_ * D;
    const float* d2b = d2 + (size_t)b * P_;

    int t = threadIdx.x;
    int ty = t >> 4, tx = t & 15;
    int w = t >> 6, ln = t & 63;
    int qs = w * 16 + (ln >> 2);
    int cs = ln & 3;

    if (t < 64) {
#pragma unroll
        for (int d = 0; d < D; ++d) sQT[d][t] = xc[(size_t)(q0 + t) * D + d];
    }
    float qd2i[4];
#pragma unroll
    for (int i = 0; i < 4; ++i) qd2i[i] = d2b[q0 + ty * 4 + i];

    float a[K_];
#pragma unroll
    for (int s = 0; s < K_; ++s)
        a[s] = __uint_as_float(0x7F7FF000u | (u32)s);    // distinct huge finite sentinels
    const float PINV = __uint_as_float(0x7F800000u);     // +inf (fminf/fmaxf safe)
    const float BIGF = __uint_as_float(0x7F7FFFFFu);     // FLT_MAX

    float p0 = PINV, p1 = PINV, p2 = PINV, p3 = PINV;
    int pcnt = 0;
    float kthr = BIGF;

#pragma unroll 1
    for (int c0 = 0; c0 < P_; c0 += 64) {
        __syncthreads();
        if (t < 64) {
#pragma unroll
            for (int d = 0; d < D; ++d) sCT[d][t] = xc[(size_t)(c0 + t) * D + d];
        }
        __syncthreads();

        float acc[4][4] = {};
#pragma unroll
        for (int kk = 0; kk < D; ++kk) {
            float4 aq = *(const float4*)&sQT[kk][ty * 4];
            float4 bc = *(const float4*)&sCT[kk][tx * 4];
            acc[0][0] = fmaf(aq.x, bc.x, acc[0][0]); acc[0][1] = fmaf(aq.x, bc.y, acc[0][1]);
            acc[0][2] = fmaf(aq.x, bc.z, acc[0][2]); acc[0][3] = fmaf(aq.x, bc.w, acc[0][3]);
            acc[1][0] = fmaf(aq.y, bc.x, acc[1][0]); acc[1][1] = fmaf(aq.y, bc.y, acc[1][1]);
            acc[1][2] = fmaf(aq.y, bc.z, acc[1][2]); acc[1][3] = fmaf(aq.y, bc.w, acc[1][3]);
            acc[2][0] = fmaf(aq.z, bc.x, acc[2][0]); acc[2][1] = fmaf(aq.z, bc.y, acc[2][1]);
            acc[2][2] = fmaf(aq.z, bc.z, acc[2][2]); acc[2][3] = fmaf(aq.z, bc.w, acc[2][3]);
            acc[3][0] = fmaf(aq.w, bc.x, acc[3][0]); acc[3][1] = fmaf(aq.w, bc.y, acc[3][1]);
            acc[3][2] = fmaf(aq.w, bc.z, acc[3][2]); acc[3][3] = fmaf(aq.w, bc.w, acc[3][3]);
        }
        float cd2j[4];
#pragma unroll
        for (int j = 0; j < 4; ++j) cd2j[j] = d2b[c0 + tx * 4 + j];
        bool diag = (q0 == c0);
#pragma unroll
        for (int i = 0; i < 4; ++i) {
            float dd[4];
#pragma unroll
            for (int j = 0; j < 4; ++j) {
                float v = (qd2i[i] + cd2j[j]) - 2.f * acc[i][j];
                if (diag && (ty * 4 + i == tx * 4 + j)) v += 1e10f;
                dd[j] = fmaxf(v, 0.f);
            }
            *(float4*)&sD[ty * 4 + i][tx * 4] = make_float4(dd[0], dd[1], dd[2], dd[3]);
        }
        __syncthreads();

        float dvv[16];
        float mn = 3.4e38f;
#pragma unroll
        for (int u = 0; u < 16; ++u) {
            dvv[u] = sD[qs][cs + u * 4];
            mn = fminf(mn, dvv[u]);
        }
        if (__any(mn <= kthr)) {
#pragma unroll
            for (int u = 0; u < 16; ++u) {
                float dv = dvv[u];
                if (__any(dv <= kthr)) {
                    float key = mkkey(dv, c0 + cs + u * 4);
                    bool pass = key < a[K_ - 1];
                    p3 = pass ? p2 : p3;
                    p2 = pass ? p1 : p2;
                    p1 = pass ? p0 : p1;
                    p0 = pass ? key : p0;
                    pcnt = pass ? pcnt + 1 : pcnt;
                    if (__any(pcnt >= 4)) {
                        bubble20f(a, p3); bubble20f(a, p2); bubble20f(a, p1); bubble20f(a, p0);
                        p0 = p1 = p2 = p3 = PINV; pcnt = 0;
                        kthr = __uint_as_float(__float_as_uint(a[K_ - 1]) | 0xFFFu);
                    }
                }
            }
        }
    }
    bubble20f(a, p3); bubble20f(a, p2); bubble20f(a, p1); bubble20f(a, p0);

    int* op = idx + ((size_t)(b * P_ + q0 + qs)) * K_;
#pragma unroll 1
    for (int k = 0; k < K_; ++k) {
        float v = a[0];
        float v1 = __shfl_xor(v, 1);
        v = fminf(v, v1);
        float v2 = __shfl_xor(v, 2);
        v = fminf(v, v2);
        bool win = (__float_as_uint(a[0]) == __float_as_uint(v));
#pragma unroll
        for (int s = 0; s < K_ - 1; ++s) a[s] = win ? a[s + 1] : a[s];
        a[K_ - 1] = win ? BIGF : a[K_ - 1];
        if (cs == 0)
            op[k] = b * P_ + (int)(__float_as_uint(v) & 0xFFFu);
    }
}

// ---------------------------------------------------------------- fused knn (D=64) via MFMA, f32 keys
__global__ __launch_bounds__(256) void knnm64_kernel(const u16* __restrict__ xh,
                                                     const u16* __restrict__ xm,
                                                     const u16* __restrict__ xl,
                                                     const float* __restrict__ d2,
                                                     int* __restrict__ idx) {
    __shared__ u16 sH[64 * 64];      // elem (r,k) at byte r*128 + ((k*2) ^ ((r&7)<<4))
    __shared__ u16 sM[64 * 64];
    __shared__ u16 sL[64 * 64];
    __shared__ float sd2[P_];        // 16 KB

    int b = blockIdx.y;
    int q0 = blockIdx.x * 64;
    const u16* xhb = xh + (size_t)b * P_ * 64;
    const u16* xmb = xm + (size_t)b * P_ * 64;
    const u16* xlb = xl + (size_t)b * P_ * 64;
    const float* d2b = d2 + (size_t)b * P_;

    int t = threadIdx.x, w = t >> 6, ln = t & 63;
    int q  = ln & 15;
    int ss = ln >> 4;

    for (int i = t; i < P_ / 4; i += 256)
        ((float4*)sd2)[i] = ((const float4*)d2b)[i];

    int qrow = q0 + w * 16 + q;
    bf16x8 qh[2], qm[2], ql[2];
#pragma unroll
    for (int kt = 0; kt < 2; ++kt) {
        size_t off = (size_t)qrow * 64 + kt * 32 + ss * 8;
        qh[kt] = *(const bf16x8*)(xhb + off);
        qm[kt] = *(const bf16x8*)(xmb + off);
        ql[kt] = *(const bf16x8*)(xlb + off);
    }

    __syncthreads();
    float qd2 = sd2[qrow];

    float a[K_];
#pragma unroll
    for (int s = 0; s < K_; ++s)
        a[s] = __uint_as_float(0x7F7FF000u | (u32)s);
    const float PINV = __uint_as_float(0x7F800000u);     // +inf
    const float BIGF = __uint_as_float(0x7F7FFFFFu);     // FLT_MAX

    float p0 = PINV, p1 = PINV, p2 = PINV, p3 = PINV;
    int pcnt = 0;
    float kthr = BIGF;

    int sr = t >> 2;
    int sk2 = (t & 3) * 32;
    int sbase = sr * 128, sswz = (sr & 7) << 4;
    size_t sgof = (size_t)sr * 64 + (t & 3) * 16;

#pragma unroll 1
    for (int c0 = 0; c0 < P_; c0 += 64) {
        __syncthreads();
        {
            size_t g = (size_t)c0 * 64 + sgof;
            bf16x8 h0 = *(const bf16x8*)(xhb + g);
            bf16x8 h1 = *(const bf16x8*)(xhb + g + 8);
            bf16x8 m0 = *(const bf16x8*)(xmb + g);
            bf16x8 m1 = *(const bf16x8*)(xmb + g + 8);
            bf16x8 l0 = *(const bf16x8*)(xlb + g);
            bf16x8 l1 = *(const bf16x8*)(xlb + g + 8);
            *(bf16x8*)((char*)sH + sbase + (sk2 ^ sswz)) = h0;
            *(bf16x8*)((char*)sH + sbase + ((sk2 + 16) ^ sswz)) = h1;
            *(bf16x8*)((char*)sM + sbase + (sk2 ^ sswz)) = m0;
            *(bf16x8*)((char*)sM + sbase + ((sk2 + 16) ^ sswz)) = m1;
            *(bf16x8*)((char*)sL + sbase + (sk2 ^ sswz)) = l0;
            *(bf16x8*)((char*)sL + sbase + ((sk2 + 16) ^ sswz)) = l1;
        }
        __syncthreads();

        f32x4 acc[4];
#pragma unroll
        for (int nt = 0; nt < 4; ++nt) {
            acc[nt] = (f32x4){0.f, 0.f, 0.f, 0.f};
            int r = nt * 16 + q;
            int base = r * 128, swz = (r & 7) << 4;
#pragma unroll
            for (int kt = 0; kt < 2; ++kt) {
                int k2 = kt * 64 + ss * 16;
                bf16x8 ch = *(const bf16x8*)((char*)sH + base + (k2 ^ swz));
                bf16x8 cm = *(const bf16x8*)((char*)sM + base + (k2 ^ swz));
                bf16x8 cl = *(const bf16x8*)((char*)sL + base + (k2 ^ swz));
                acc[nt] = __builtin_amdgcn_mfma_f32_16x16x32_bf16(cm, qm[kt], acc[nt], 0, 0, 0);
                acc[nt] = __builtin_amdgcn_mfma_f32_16x16x32_bf16(cl, qh[kt], acc[nt], 0, 0, 0);
                acc[nt] = __builtin_amdgcn_mfma_f32_16x16x32_bf16(ch, ql[kt], acc[nt], 0, 0, 0);
                acc[nt] = __builtin_amdgcn_mfma_f32_16x16x32_bf16(cm, qh[kt], acc[nt], 0, 0, 0);
                acc[nt] = __builtin_amdgcn_mfma_f32_16x16x32_bf16(ch, qm[kt], acc[nt], 0, 0, 0);
                acc[nt] = __builtin_amdgcn_mfma_f32_16x16x32_bf16(ch, qh[kt], acc[nt], 0, 0, 0);
            }
        }

        float dvv[4][4];
        float mn = 3.4e38f;
#pragma unroll
        for (int nt = 0; nt < 4; ++nt) {
#pragma unroll
            for (int r = 0; r < 4; ++r) {
                int cID = c0 + nt * 16 + ss * 4 + r;
                float dv = (qd2 + sd2[cID]) - 2.f * acc[nt][r];
                if (cID == qrow) dv += 1e10f;
                dv = fmaxf(dv, 0.f);
                dvv[nt][r] = dv;
                mn = fminf(mn, dv);
            }
        }
        if (__any(mn <= kthr)) {
#pragma unroll
            for (int nt = 0; nt < 4; ++nt) {
#pragma unroll
                for (int r = 0; r < 4; ++r) {
                    float dv = dvv[nt][r];
                    if (__any(dv <= kthr)) {
                        float key = mkkey(dv, c0 + nt * 16 + ss * 4 + r);
                        bool pass = key < a[K_ - 1];
                        p3 = pass ? p2 : p3;
                        p2 = pass ? p1 : p2;
                        p1 = pass ? p0 : p1;
                        p0 = pass ? key : p0;
                        pcnt = pass ? pcnt + 1 : pcnt;
                        if (__any(pcnt >= 4)) {
                            bubble20f(a, p3); bubble20f(a, p2); bubble20f(a, p1); bubble20f(a, p0);
                            p0 = p1 = p2 = p3 = PINV; pcnt = 0;
                            kthr = __uint_as_float(__float_as_uint(a[K_ - 1]) | 0xFFFu);
                        }
                    }
                }
            }
        }
    }
    bubble20f(a, p3); bubble20f(a, p2); bubble20f(a, p1); bubble20f(a, p0);

    int* op = idx + ((size_t)(b * P_ + qrow)) * K_;
#pragma unroll 1
    for (int k = 0; k < K_; ++k) {
        float v = a[0];
        float v1 = __shfl_xor(v, 16);
        v = fminf(v, v1);
        float v2 = __shfl_xor(v, 32);
        v = fminf(v, v2);
        bool win = (__float_as_uint(a[0]) == __float_as_uint(v));
#pragma unroll
        for (int s = 0; s < K_ - 1; ++s) a[s] = win ? a[s + 1] : a[s];
        a[K_ - 1] = win ? BIGF : a[K_ - 1];
        if (ss == 0)
            op[k] = b * P_ + (int)(__float_as_uint(v) & 0xFFFu);
    }
}

// ---------------------------------------------------------------- one-shot weight prep
__global__ __launch_bounds__(256) void prep_kernel(const float* __restrict__ W2,
                                                   const float* __restrict__ b2,
                                                   const float* __restrict__ W3,
                                                   const float* __restrict__ b3,
                                                   const float* __restrict__ Wl,
                                                   const float* __restrict__ Wm1,
                                                   const float* __restrict__ Wm2,
                                                   float* __restrict__ Wpk2, float* __restrict__ bpk2,
                                                   float* __restrict__ Wpk3, float* __restrict__ bpk3,
                                                   u16* __restrict__ WlT,
                                                   u16* __restrict__ Wm1T,
                                                   u16* __restrict__ Wm2T) {
    int t = blockIdx.x * 256 + threadIdx.x;
    if (t < 8192) {
        int d = t >> 7, h2 = t & 127;
        Wpk2[t] = (h2 < 64) ? W2[d * 64 + h2] : W2[(64 + d) * 64 + (h2 - 64)];
        if (t < 128) bpk2[t] = (t < 64) ? b2[t] : 0.f;
    } else if (t < 16384) {
        int t2 = t - 8192;
        int d = t2 >> 7, h2 = t2 & 127;
        Wpk3[t2] = (h2 < 64) ? W3[d * 64 + h2] : W3[(64 + d) * 64 + (h2 - 64)];
        if (t2 < 128) bpk3[t2] = (t2 < 64) ? b3[t2] : 0.f;
    } else if (t < 212992) {
        int t2 = t - 16384;
        int k = t2 >> 10, n = t2 & 1023;
        WlT[(size_t)n * 192 + k] = f2bf(Wl[t2]);
    } else if (t < 475136) {
        int t2 = t - 212992;
        int k = t2 >> 8, n = t2 & 255;
        Wm1T[(size_t)n * 1024 + k] = f2bf(Wm1[t2]);
    } else if (t < 507904) {
        int t2 = t - 475136;
        int k = t2 >> 7, n = t2 & 127;
        Wm2T[(size_t)n * 256 + k] = f2bf(Wm2[t2]);
    }
}

// ---------------------------------------------------------------- layer-1 UV (D=3, direct)
__global__ __launch_bounds__(256) void uv3_kernel(const float* __restrict__ x,
                                                  const float* __restrict__ W,
                                                  const float* __restrict__ b,
                                                  float* __restrict__ UV) {
    int t = blockIdx.x * 256 + threadIdx.x;
    int p = t >> 7, h2 = t & 127;
    float x0 = x[p * 3], x1 = x[p * 3 + 1], x2 = x[p * 3 + 2];
    float r;
    if (h2 < 64) {
        r = b[h2] + x0 * W[h2] + x1 * W[64 + h2] + x2 * W[128 + h2];
    } else {
        int h = h2 - 64;
        r = x0 * W[192 + h] + x1 * W[256 + h] + x2 * W[320 + h];
    }
    UV[t] = r;
}

// ---------------------------------------------------------------- edge max
__global__ __launch_bounds__(256) void edgemax_kernel(const float* __restrict__ UV,
                                                      const int* __restrict__ idx,
                                                      float* __restrict__ xout) {
    int wv = threadIdx.x >> 6, lane = threadIdx.x & 63;
    int p = blockIdx.x * 4 + wv;
    const float* uvp = UV + (size_t)p * 128;
    float duv = uvp[lane] - uvp[64 + lane];
    const int* ip = idx + (size_t)p * K_;
    int jj[K_];
#pragma unroll
    for (int k = 0; k < K_; ++k) jj[k] = ip[k];
    float m = -3.4e38f;
#pragma unroll
    for (int k = 0; k < K_; ++k) {
        float vj = UV[(size_t)jj[k] * 128 + 64 + lane];
        float t = duv + vj;
        m = fmaxf(m, fmaxf(t, NEG_SLOPE * t));
    }
    xout[(size_t)p * H_ + lane] = m;
}

// ---------------------------------------------------------------- GEMM 64x64 f32 (UV)
__global__ __launch_bounds__(256) void gemm_kernel(const float* __restrict__ A1,
                                                   const float* __restrict__ Wm,
                                                   const float* __restrict__ bias,
                                                   float* __restrict__ Cm,
                                                   int M, int N, int Kd, int leaky) {
    __shared__ float sA[32][68];
    __shared__ float sB[32][68];

    int tid = threadIdx.x;
    int row0 = blockIdx.x * 64, col0 = blockIdx.y * 64;
    int tx = tid & 15, ty = tid >> 4;

    int lr  = tid >> 2;
    int lk4 = (tid & 3) * 4;
    int lkb = tid >> 4;
    int lnb = (tid & 15) * 4;

    float acc[4][4] = {};

    for (int k0 = 0; k0 < Kd; k0 += 32) {
        int arow = row0 + lr;
#pragma unroll
        for (int h = 0; h < 32; h += 16) {
            int kk = k0 + lk4 + h;
            const float* src = A1 + (size_t)arow * Kd + kk;
            float4 av = *(const float4*)src;
            sA[lk4 + h + 0][lr] = av.x; sA[lk4 + h + 1][lr] = av.y;
            sA[lk4 + h + 2][lr] = av.z; sA[lk4 + h + 3][lr] = av.w;
        }
        int bcol = col0 + lnb;
#pragma unroll
        for (int h = 0; h < 32; h += 16) {
            float4 bv = make_float4(0.f, 0.f, 0.f, 0.f);
            if (bcol < N) bv = *(const float4*)(Wm + (size_t)(k0 + lkb + h) * N + bcol);
            *(float4*)&sB[lkb + h][lnb] = bv;
        }
        __syncthreads();

#pragma unroll
        for (int kk2 = 0; kk2 < 32; ++kk2) {
            float4 a = *(const float4*)&sA[kk2][ty * 4];
            float4 bb = *(const float4*)&sB[kk2][tx * 4];
            acc[0][0] = fmaf(a.x, bb.x, acc[0][0]); acc[0][1] = fmaf(a.x, bb.y, acc[0][1]);
            acc[0][2] = fmaf(a.x, bb.z, acc[0][2]); acc[0][3] = fmaf(a.x, bb.w, acc[0][3]);
            acc[1][0] = fmaf(a.y, bb.x, acc[1][0]); acc[1][1] = fmaf(a.y, bb.y, acc[1][1]);
            acc[1][2] = fmaf(a.y, bb.z, acc[1][2]); acc[1][3] = fmaf(a.y, bb.w, acc[1][3]);
            acc[2][0] = fmaf(a.z, bb.x, acc[2][0]); acc[2][1] = fmaf(a.z, bb.y, acc[2][1]);
            acc[2][2] = fmaf(a.z, bb.z, acc[2][2]); acc[2][3] = fmaf(a.z, bb.w, acc[2][3]);
            acc[3][0] = fmaf(a.w, bb.x, acc[3][0]); acc[3][1] = fmaf(a.w, bb.y, acc[3][1]);
            acc[3][2] = fmaf(a.w, bb.z, acc[3][2]); acc[3][3] = fmaf(a.w, bb.w, acc[3][3]);
        }
        __syncthreads();
    }

    for (int i = 0; i < 4; ++i) {
        int row = row0 + ty * 4 + i;
        for (int j = 0; j < 4; ++j) {
            int col = col0 + tx * 4 + j;
            if (col < N) {
                float v = acc[i][j] + bias[col];
                if (leaky) v = v > 0.f ? v : NEG_SLOPE * v;
                Cm[(size_t)row * N + col] = v;
            }
        }
    }
}

// ---------------------------------------------------------------- MFMA GEMM head (bf16 A)
template <int KD, int OUT_BF16>
__global__ __launch_bounds__(256) void gemm_mfma_kernel(const u16* __restrict__ A,
                                                        const u16* __restrict__ BT,
                                                        const float* __restrict__ bias,
                                                        void* __restrict__ Cout,
                                                        int N, int leaky) {
    __shared__ u16 sA[128 * 64];
    __shared__ u16 sB[128 * 64];

    int t = threadIdx.x;
    int wave = t >> 6, lane = t & 63;
    int wm = wave >> 1, wn = wave & 1;
    int row0 = blockIdx.x * 128;
    int col0 = blockIdx.y * 128;

    f32x4 acc[4][4] = {};

    for (int k0 = 0; k0 < KD; k0 += 64) {
        __syncthreads();
#pragma unroll
        for (int i = 0; i < 4; ++i) {
            int li = t + i * 256;
            int r = li >> 3;
            int kc = (li & 7) * 8;
            bf16x8 v = *(const bf16x8*)(A + (size_t)(row0 + r) * KD + k0 + kc);
            *(bf16x8*)((char*)sA + r * 128 + ((kc * 2) ^ ((r & 7) << 4))) = v;
        }
#pragma unroll
        for (int i = 0; i < 4; ++i) {
            int li = t + i * 256;
            int n = li >> 3;
            int kc = (li & 7) * 8;
            bf16x8 v = *(const bf16x8*)(BT + (size_t)(col0 + n) * KD + k0 + kc);
            *(bf16x8*)((char*)sB + n * 128 + ((kc * 2) ^ ((n & 7) << 4))) = v;
        }
        __syncthreads();

#pragma unroll
        for (int kk = 0; kk < 2; ++kk) {
            int kb = kk * 64 + (lane >> 4) * 16;
            bf16x8 af[4], bfr[4];
#pragma unroll
            for (int mi = 0; mi < 4; ++mi) {
                int r = wm * 64 + mi * 16 + (lane & 15);
                af[mi] = *(const bf16x8*)((char*)sA + r * 128 + (kb ^ ((r & 7) << 4)));
            }
#pragma unroll
            for (int ni = 0; ni < 4; ++ni) {
                int n = wn * 64 + ni * 16 + (lane & 15);
                bfr[ni] = *(const bf16x8*)((char*)sB + n * 128 + (kb ^ ((n & 7) << 4)));
            }
#pragma unroll
            for (int mi = 0; mi < 4; ++mi)
#pragma unroll
                for (int ni = 0; ni < 4; ++ni)
                    acc[mi][ni] = __builtin_amdgcn_mfma_f32_16x16x32_bf16(
                        af[mi], bfr[ni], acc[mi][ni], 0, 0, 0);
        }
    }

#pragma unroll
    for (int ni = 0; ni < 4; ++ni) {
        int col = col0 + wn * 64 + ni * 16 + (lane & 15);
        float bs = bias[col];
#pragma unroll
        for (int mi = 0; mi < 4; ++mi) {
#pragma unroll
            for (int r = 0; r < 4; ++r) {
                int row = row0 + wm * 64 + mi * 16 + (lane >> 4) * 4 + r;
                float v = acc[mi][ni][r] + bs;
                if (leaky) v = v > 0.f ? v : NEG_SLOPE * v;
                if (OUT_BF16)
                    ((u16*)Cout)[(size_t)row * N + col] = f2bf(v);
                else
                    ((float*)Cout)[(size_t)row * N + col] = v;
            }
        }
    }
}

// ---------------------------------------------------------------- MFMA GEMM, cat-f32 A (fused cvt)
__global__ __launch_bounds__(256) void gemm_mfma_cat_kernel(const float* __restrict__ x1,
                                                            const float* __restrict__ x2,
                                                            const float* __restrict__ x3,
                                                            const u16* __restrict__ BT,
                                                            const float* __restrict__ bias,
                                                            u16* __restrict__ Cout,
                                                            int N) {
    __shared__ u16 sA[128 * 64];
    __shared__ u16 sB[128 * 64];

    int t = threadIdx.x;
    int wave = t >> 6, lane = t & 63;
    int wm = wave >> 1, wn = wave & 1;
    int row0 = blockIdx.x * 128;
    int col0 = blockIdx.y * 128;

    f32x4 acc[4][4] = {};

#pragma unroll 1
    for (int k0 = 0; k0 < 192; k0 += 64) {
        const float* src = (k0 == 0) ? x1 : (k0 == 64) ? x2 : x3;
        __syncthreads();
#pragma unroll
        for (int i = 0; i < 4; ++i) {
            int li = t + i * 256;
            int r = li >> 3;
            int kc = (li & 7) * 8;
            const float* sp = src + (size_t)(row0 + r) * 64 + kc;
            float4 a0 = *(const float4*)sp;
            float4 a1 = *(const float4*)(sp + 4);
            bf16x8 v;
            v[0] = (short)f2bf(a0.x); v[1] = (short)f2bf(a0.y);
            v[2] = (short)f2bf(a0.z); v[3] = (short)f2bf(a0.w);
            v[4] = (short)f2bf(a1.x); v[5] = (short)f2bf(a1.y);
            v[6] = (short)f2bf(a1.z); v[7] = (short)f2bf(a1.w);
            *(bf16x8*)((char*)sA + r * 128 + ((kc * 2) ^ ((r & 7) << 4))) = v;
        }
#pragma unroll
        for (int i = 0; i < 4; ++i) {
            int li = t + i * 256;
            int n = li >> 3;
            int kc = (li & 7) * 8;
            bf16x8 v = *(const bf16x8*)(BT + (size_t)(col0 + n) * 192 + k0 + kc);
            *(bf16x8*)((char*)sB + n * 128 + ((kc * 2) ^ ((n & 7) << 4))) = v;
        }
        __syncthreads();

#pragma unroll
        for (int kk = 0; kk < 2; ++kk) {
            int kb = kk * 64 + (lane >> 4) * 16;
            bf16x8 af[4], bfr[4];
#pragma unroll
            for (int mi = 0; mi < 4; ++mi) {
                int r = wm * 64 + mi * 16 + (lane & 15);
                af[mi] = *(const bf16x8*)((char*)sA + r * 128 + (kb ^ ((r & 7) << 4)));
            }
#pragma unroll
            for (int ni = 0; ni < 4; ++ni) {
                int n = wn * 64 + ni * 16 + (lane & 15);
                bfr[ni] = *(const bf16x8*)((char*)sB + n * 128 + (kb ^ ((n & 7) << 4)));
            }
#pragma unroll
            for (int mi = 0; mi < 4; ++mi)
#pragma unroll
                for (int ni = 0; ni < 4; ++ni)
                    acc[mi][ni] = __builtin_amdgcn_mfma_f32_16x16x32_bf16(
                        af[mi], bfr[ni], acc[mi][ni], 0, 0, 0);
        }
    }

#pragma unroll
    for (int ni = 0; ni < 4; ++ni) {
        int col = col0 + wn * 64 + ni * 16 + (lane & 15);
        float bs = bias[col];
#pragma unroll
        for (int mi = 0; mi < 4; ++mi) {
#pragma unroll
            for (int r = 0; r < 4; ++r) {
                int row = row0 + wm * 64 + mi * 16 + (lane >> 4) * 4 + r;
                float v = acc[mi][ni][r] + bs;
                v = v > 0.f ? v : NEG_SLOPE * v;
                Cout[(size_t)row * N + col] = f2bf(v);
            }
        }
    }
}

// ---------------------------------------------------------------- fused Wo GEMM + log_softmax
__global__ __launch_bounds__(256) void lsm_wo_kernel(const float* __restrict__ act3,
                                                     const float* __restrict__ Wo,
                                                     const float* __restrict__ bo,
                                                     float* __restrict__ out) {
    __shared__ float sWo[128 * 44];
    __shared__ float sAct[4][128];

    int t = threadIdx.x;
    for (int i = t; i < 128 * 40; i += 256) {
        int k = i / 40, c = i % 40;
        sWo[k * 44 + c] = Wo[i];
    }
    __syncthreads();

    int wv = t >> 6, lane = t & 63;
    int row = blockIdx.x * 4 + wv;
    sAct[wv][lane]      = act3[(size_t)row * 128 + lane];
    sAct[wv][64 + lane] = act3[(size_t)row * 128 + 64 + lane];

    float acc = (lane < C_) ? bo[lane] : -3.4e38f;
    if (lane < C_) {
#pragma unroll 8
        for (int k = 0; k < 128; ++k)
            acc = fmaf(sAct[wv][k], sWo[k * 44 + lane], acc);
    }
    float m = acc;
#pragma unroll
    for (int s = 1; s < 64; s <<= 1) m = fmaxf(m, __shfl_xor(m, s));
    float e = (lane < C_) ? expf(acc - m) : 0.f;
    float sum = e;
#pragma unroll
    for (int s = 1; s < 64; s <<= 1) sum += __shfl_xor(sum, s);
    if (lane < C_) out[(size_t)row * C_ + lane] = acc - m - logf(sum);
}

// ----------------------------------------------------------------
extern "C" void kernel_launch(void* const* d_in, const int* in_sizes, int n_in,
                              void* d_out, int out_size, void* d_ws, size_t ws_size,
                              hipStream_t stream) {
    const float* x   = (const float*)d_in[0];
    const float* W1  = (const float*)d_in[2];
    const float* b1  = (const float*)d_in[3];
    const float* W2  = (const float*)d_in[4];
    const float* b2  = (const float*)d_in[5];
    const float* W3  = (const float*)d_in[6];
    const float* b3  = (const float*)d_in[7];
    const float* Wl  = (const float*)d_in[8];
    const float* bl  = (const float*)d_in[9];
    const float* Wm1 = (const float*)d_in[10];
    const float* bm1 = (const float*)d_in[11];
    const float* Wm2 = (const float*)d_in[12];
    const float* bm2 = (const float*)d_in[13];
    const float* Wo  = (const float*)d_in[14];
    const float* bo  = (const float*)d_in[15];
    float* out = (float*)d_out;

    // ---- workspace (max 50,987,008 B — proven footprint) ----
    char* ws = (char*)d_ws;
    float* x1   = (float*)(ws);
    float* x2   = (float*)(ws + 8388608);
    float* x3   = (float*)(ws + 16777216);
    int*   idx  = (int*)  (ws + 25165824);
    float* d2   = (float*)(ws + 27787264);
    char* hb = ws + 27918336;
    u16*   xhs  = (u16*)(hb);
    u16*   xms  = (u16*)(hb + 4194304);
    u16*   xls  = (u16*)(hb + 8388608);
    float* UV   = (float*)(hb);
    float* Wpk2 = (float*)(ws + 44695552);
    float* bpk2 = (float*)(ws + 44728320);
    float* Wpk3 = (float*)(ws + 44728832);
    float* bpk3 = (float*)(ws + 44761600);
    u16*   WlT  = (u16*)  (ws + 44762112);
    u16*   Wm1T = (u16*)  (ws + 45155328);
    u16*   Wm2T = (u16*)  (ws + 45679616);
    u16*   act1 = (u16*)(hb);
    u16*   act2 = (u16*)(ws + 45745152);
    float* act3 = (float*)(hb);

    prep_kernel<<<1984, 256, 0, stream>>>(W2, b2, W3, b3, Wl, Wm1, Wm2,
                                          Wpk2, bpk2, Wpk3, bpk3, WlT, Wm1T, Wm2T);

    // ---- layer 1 (D=3)
    d2_kernel<3><<<NPT / 256, 256, 0, stream>>>(x, d2);
    knnf_kernel<3><<<dim3(P_ / 64, B_), 256, 0, stream>>>(x, d2, idx);
    uv3_kernel<<<NPT * 128 / 256, 256, 0, stream>>>(x, W1, b1, UV);
    edgemax_kernel<<<NPT / 4, 256, 0, stream>>>(UV, idx, x1);
    // ---- layer 2 (D=64)
    d2cvt3_kernel<<<NPT / 256, 256, 0, stream>>>(x1, d2, xhs, xms, xls);
    knnm64_kernel<<<dim3(P_ / 64, B_), 256, 0, stream>>>(xhs, xms, xls, d2, idx);
    gemm_kernel<<<dim3(NPT / 64, 2), 256, 0, stream>>>(x1, Wpk2, bpk2, UV, NPT, 128, 64, 0);
    edgemax_kernel<<<NPT / 4, 256, 0, stream>>>(UV, idx, x2);
    // ---- layer 3 (D=64)
    d2cvt3_kernel<<<NPT / 256, 256, 0, stream>>>(x2, d2, xhs, xms, xls);
    knnm64_kernel<<<dim3(P_ / 64, B_), 256, 0, stream>>>(xhs, xms, xls, d2, idx);
    gemm_kernel<<<dim3(NPT / 64, 2), 256, 0, stream>>>(x2, Wpk3, bpk3, UV, NPT, 128, 64, 0);
    edgemax_kernel<<<NPT / 4, 256, 0, stream>>>(UV, idx, x3);

    // ---- MLP head: 4 chunks of 8192 rows
    for (int c = 0; c < 4; ++c) {
        size_t r0 = (size_t)c * 8192;
        gemm_mfma_cat_kernel<<<dim3(64, 8), 256, 0, stream>>>(x1 + r0 * 64, x2 + r0 * 64,
                                                              x3 + r0 * 64, WlT, bl, act1, 1024);
        gemm_mfma_kernel<1024, 1><<<dim3(64, 2), 256, 0, stream>>>(act1, Wm1T, bm1, act2, 256, 1);
        gemm_mfma_kernel<256, 0><<<dim3(64, 1), 256, 0, stream>>>(act2, Wm2T, bm2, act3, 128, 1);
        lsm_wo_kernel<<<2048, 256, 0, stream>>>(act3, Wo, bo, out + r0 * C_);
    }
}

// Round 17
// 897.517 us; speedup vs baseline: 1.7191x; 1.0498x over previous
//
#include <hip/hip_runtime.h>
#include <cstddef>
#include <cstdint>

constexpr int B_ = 8, P_ = 4096, K_ = 20, H_ = 64, C_ = 40;
constexpr int NPT = B_ * P_;
#define NEG_SLOPE 0.2f

typedef unsigned long long u64;
typedef unsigned int u32;
typedef unsigned short u16;
typedef __attribute__((ext_vector_type(8))) short bf16x8;
typedef __attribute__((ext_vector_type(4))) float f32x4;

__device__ inline u16 f2bf(float v) {   // round-to-nearest-even bf16
    u32 bits = __float_as_uint(v);
    return (u16)((bits + 0x7FFFu + ((bits >> 16) & 1)) >> 16);
}
__device__ inline float bf2f(u16 h) { return __uint_as_float((u32)h << 16); }

// sorted-ascending 20-slot bubble insert, f32 keys (positive, bit-ordered)
__device__ __forceinline__ void bubble20f(float (&a)[K_], float key) {
    float carry = key;
#pragma unroll
    for (int s = 0; s < K_; ++s) {
        float as = a[s];
        a[s]  = fminf(carry, as);
        carry = fmaxf(carry, as);
    }
}
// key = (dist_bits & ~0xFFF) | cid   (cid < 4096; dist >= 0 finite)
__device__ __forceinline__ float mkkey(float dist, int cid) {
    return __uint_as_float((__float_as_uint(dist) & 0xFFFFF000u) | (u32)cid);
}

// ---------------------------------------------------------------- d2 = sum(x*x) (layer 1, D=3)
template <int D>
__global__ __launch_bounds__(256) void d2_kernel(const float* __restrict__ x,
                                                 float* __restrict__ d2) {
    int i = blockIdx.x * 256 + threadIdx.x;
    if (i >= NPT) return;
    const float* r = x + (size_t)i * D;
    float s = 0.f;
#pragma unroll
    for (int d = 0; d < D; ++d) { float v = r[d]; s += v * v; }
    d2[i] = s;
}

// ---------------------------------------------------------------- fused d2 + h/m split (D=64)
__global__ __launch_bounds__(256) void d2cvt2_kernel(const float* __restrict__ x,
                                                     float* __restrict__ d2,
                                                     u16* __restrict__ xh,
                                                     u16* __restrict__ xm) {
    int i = blockIdx.x * 256 + threadIdx.x;
    if (i >= NPT) return;
    const float* r = x + (size_t)i * 64;
    float s = 0.f;
#pragma unroll
    for (int d8 = 0; d8 < 64; d8 += 8) {
        float4 v0 = *(const float4*)(r + d8);
        float4 v1 = *(const float4*)(r + d8 + 4);
        s += v0.x * v0.x + v0.y * v0.y + v0.z * v0.z + v0.w * v0.w;
        s += v1.x * v1.x + v1.y * v1.y + v1.z * v1.z + v1.w * v1.w;
        float av[8] = {v0.x, v0.y, v0.z, v0.w, v1.x, v1.y, v1.z, v1.w};
        bf16x8 vh, vm;
#pragma unroll
        for (int j = 0; j < 8; ++j) {
            u16 h = f2bf(av[j]);
            float r1 = av[j] - bf2f(h);
            vh[j] = (short)h; vm[j] = (short)f2bf(r1);
        }
        *(bf16x8*)(xh + (size_t)i * 64 + d8) = vh;
        *(bf16x8*)(xm + (size_t)i * 64 + d8) = vm;
    }
    d2[i] = s;
}

// ---------------------------------------------------------------- layer-1 knn (D=3), direct register eval
// Lane layout = knnm64: lane (q=ln&15, ss=ln>>4); 4 waves x 16 queries/block.
__global__ __launch_bounds__(256) void knnf3_kernel(const float* __restrict__ x,
                                                    const float* __restrict__ d2,
                                                    int* __restrict__ idx) {
    __shared__ float sC[64][4];   // cand x,y,z,d2

    int b = blockIdx.y;
    int q0 = blockIdx.x * 64;
    const float* xc  = x + (size_t)b * P_ * 3;
    const float* d2b = d2 + (size_t)b * P_;

    int t = threadIdx.x, w = t >> 6, ln = t & 63;
    int q  = ln & 15;
    int ss = ln >> 4;

    int qrow = q0 + w * 16 + q;
    float qx = xc[(size_t)qrow * 3];
    float qy = xc[(size_t)qrow * 3 + 1];
    float qz = xc[(size_t)qrow * 3 + 2];
    float qd2 = d2b[qrow];

    float a[K_];
#pragma unroll
    for (int s = 0; s < K_; ++s)
        a[s] = __uint_as_float(0x7F7FF000u | (u32)s);    // distinct huge finite sentinels
    const float PINV = __uint_as_float(0x7F800000u);     // +inf
    const float BIGF = __uint_as_float(0x7F7FFFFFu);     // FLT_MAX

    float p0 = PINV, p1 = PINV, p2 = PINV, p3 = PINV;
    int pcnt = 0;
    float kthr = BIGF;

    int scc = t >> 2, scm = t & 3;   // staging: one value per thread

#pragma unroll 1
    for (int c0 = 0; c0 < P_; c0 += 64) {
        __syncthreads();   // prev chunk reads done
        sC[scc][scm] = (scm < 3) ? xc[(size_t)(c0 + scc) * 3 + scm] : d2b[c0 + scc];
        __syncthreads();   // tile ready

#pragma unroll
        for (int nt = 0; nt < 4; ++nt) {
#pragma unroll
            for (int r = 0; r < 4; ++r) {
                int cl = nt * 16 + ss * 4 + r;
                int cID = c0 + cl;
                float4 cv = *(const float4*)&sC[cl][0];
                float dv = (qd2 + cv.w) - 2.f * (qx * cv.x + qy * cv.y + qz * cv.z);
                if (cID == qrow) dv += 1e10f;
                dv = fmaxf(dv, 0.f);
                if (__any(dv <= kthr)) {
                    float key = mkkey(dv, cID);
                    bool pass = key < a[K_ - 1];
                    p3 = pass ? p2 : p3;
                    p2 = pass ? p1 : p2;
                    p1 = pass ? p0 : p1;
                    p0 = pass ? key : p0;
                    pcnt = pass ? pcnt + 1 : pcnt;
                    if (__any(pcnt >= 4)) {
                        bubble20f(a, p3); bubble20f(a, p2); bubble20f(a, p1); bubble20f(a, p0);
                        p0 = p1 = p2 = p3 = PINV; pcnt = 0;
                        kthr = __uint_as_float(__float_as_uint(a[K_ - 1]) | 0xFFFu);
                    }
                }
            }
        }
    }
    bubble20f(a, p3); bubble20f(a, p2); bubble20f(a, p1); bubble20f(a, p0);

    int* op = idx + ((size_t)(b * P_ + qrow)) * K_;
#pragma unroll 1
    for (int k = 0; k < K_; ++k) {
        float v = a[0];
        float v1 = __shfl_xor(v, 16);
        v = fminf(v, v1);
        float v2 = __shfl_xor(v, 32);
        v = fminf(v, v2);
        bool win = (__float_as_uint(a[0]) == __float_as_uint(v));
#pragma unroll
        for (int s = 0; s < K_ - 1; ++s) a[s] = win ? a[s + 1] : a[s];
        a[K_ - 1] = win ? BIGF : a[K_ - 1];
        if (ss == 0)
            op[k] = b * P_ + (int)(__float_as_uint(v) & 0xFFFu);
    }
}

// ---------------------------------------------------------------- fused knn (D=64) via MFMA, 3-product h/m
__global__ __launch_bounds__(256) void knnm64_kernel(const u16* __restrict__ xh,
                                                     const u16* __restrict__ xm,
                                                     const float* __restrict__ d2,
                                                     int* __restrict__ idx) {
    __shared__ u16 sH[64 * 64];      // elem (r,k) at byte r*128 + ((k*2) ^ ((r&7)<<4))
    __shared__ u16 sM[64 * 64];
    __shared__ float sd2[P_];        // 16 KB

    int b = blockIdx.y;
    int q0 = blockIdx.x * 64;
    const u16* xhb = xh + (size_t)b * P_ * 64;
    const u16* xmb = xm + (size_t)b * P_ * 64;
    const float* d2b = d2 + (size_t)b * P_;

    int t = threadIdx.x, w = t >> 6, ln = t & 63;
    int q  = ln & 15;
    int ss = ln >> 4;

    for (int i = t; i < P_ / 4; i += 256)
        ((float4*)sd2)[i] = ((const float4*)d2b)[i];

    int qrow = q0 + w * 16 + q;
    bf16x8 qh[2], qm[2];
#pragma unroll
    for (int kt = 0; kt < 2; ++kt) {
        size_t off = (size_t)qrow * 64 + kt * 32 + ss * 8;
        qh[kt] = *(const bf16x8*)(xhb + off);
        qm[kt] = *(const bf16x8*)(xmb + off);
    }

    __syncthreads();
    float qd2 = sd2[qrow];

    float a[K_];
#pragma unroll
    for (int s = 0; s < K_; ++s)
        a[s] = __uint_as_float(0x7F7FF000u | (u32)s);
    const float PINV = __uint_as_float(0x7F800000u);     // +inf
    const float BIGF = __uint_as_float(0x7F7FFFFFu);     // FLT_MAX

    float p0 = PINV, p1 = PINV, p2 = PINV, p3 = PINV;
    int pcnt = 0;
    float kthr = BIGF;

    int sr = t >> 2;
    int sk2 = (t & 3) * 32;
    int sbase = sr * 128, sswz = (sr & 7) << 4;
    size_t sgof = (size_t)sr * 64 + (t & 3) * 16;

#pragma unroll 1
    for (int c0 = 0; c0 < P_; c0 += 64) {
        __syncthreads();
        {
            size_t g = (size_t)c0 * 64 + sgof;
            bf16x8 h0 = *(const bf16x8*)(xhb + g);
            bf16x8 h1 = *(const bf16x8*)(xhb + g + 8);
            bf16x8 m0 = *(const bf16x8*)(xmb + g);
            bf16x8 m1 = *(const bf16x8*)(xmb + g + 8);
            *(bf16x8*)((char*)sH + sbase + (sk2 ^ sswz)) = h0;
            *(bf16x8*)((char*)sH + sbase + ((sk2 + 16) ^ sswz)) = h1;
            *(bf16x8*)((char*)sM + sbase + (sk2 ^ sswz)) = m0;
            *(bf16x8*)((char*)sM + sbase + ((sk2 + 16) ^ sswz)) = m1;
        }
        __syncthreads();

        f32x4 acc[4];
#pragma unroll
        for (int nt = 0; nt < 4; ++nt) {
            acc[nt] = (f32x4){0.f, 0.f, 0.f, 0.f};
            int r = nt * 16 + q;
            int base = r * 128, swz = (r & 7) << 4;
#pragma unroll
            for (int kt = 0; kt < 2; ++kt) {
                int k2 = kt * 64 + ss * 16;
                bf16x8 ch = *(const bf16x8*)((char*)sH + base + (k2 ^ swz));
                bf16x8 cm = *(const bf16x8*)((char*)sM + base + (k2 ^ swz));
                // 3-product split: hh + hm + mh (mm/hl/lh dropped; error << key quantum)
                acc[nt] = __builtin_amdgcn_mfma_f32_16x16x32_bf16(cm, qh[kt], acc[nt], 0, 0, 0);
                acc[nt] = __builtin_amdgcn_mfma_f32_16x16x32_bf16(ch, qm[kt], acc[nt], 0, 0, 0);
                acc[nt] = __builtin_amdgcn_mfma_f32_16x16x32_bf16(ch, qh[kt], acc[nt], 0, 0, 0);
            }
        }

        float dvv[4][4];
        float mn = 3.4e38f;
#pragma unroll
        for (int nt = 0; nt < 4; ++nt) {
#pragma unroll
            for (int r = 0; r < 4; ++r) {
                int cID = c0 + nt * 16 + ss * 4 + r;
                float dv = (qd2 + sd2[cID]) - 2.f * acc[nt][r];
                if (cID == qrow) dv += 1e10f;
                dv = fmaxf(dv, 0.f);
                dvv[nt][r] = dv;
                mn = fminf(mn, dv);
            }
        }
        if (__any(mn <= kthr)) {
#pragma unroll
            for (int nt = 0; nt < 4; ++nt) {
#pragma unroll
                for (int r = 0; r < 4; ++r) {
                    float dv = dvv[nt][r];
                    if (__any(dv <= kthr)) {
                        float key = mkkey(dv, c0 + nt * 16 + ss * 4 + r);
                        bool pass = key < a[K_ - 1];
                        p3 = pass ? p2 : p3;
                        p2 = pass ? p1 : p2;
                        p1 = pass ? p0 : p1;
                        p0 = pass ? key : p0;
                        pcnt = pass ? pcnt + 1 : pcnt;
                        if (__any(pcnt >= 4)) {
                            bubble20f(a, p3); bubble20f(a, p2); bubble20f(a, p1); bubble20f(a, p0);
                            p0 = p1 = p2 = p3 = PINV; pcnt = 0;
                            kthr = __uint_as_float(__float_as_uint(a[K_ - 1]) | 0xFFFu);
                        }
                    }
                }
            }
        }
    }
    bubble20f(a, p3); bubble20f(a, p2); bubble20f(a, p1); bubble20f(a, p0);

    int* op = idx + ((size_t)(b * P_ + qrow)) * K_;
#pragma unroll 1
    for (int k = 0; k < K_; ++k) {
        float v = a[0];
        float v1 = __shfl_xor(v, 16);
        v = fminf(v, v1);
        float v2 = __shfl_xor(v, 32);
        v = fminf(v, v2);
        bool win = (__float_as_uint(a[0]) == __float_as_uint(v));
#pragma unroll
        for (int s = 0; s < K_ - 1; ++s) a[s] = win ? a[s + 1] : a[s];
        a[K_ - 1] = win ? BIGF : a[K_ - 1];
        if (ss == 0)
            op[k] = b * P_ + (int)(__float_as_uint(v) & 0xFFFu);
    }
}

// ---------------------------------------------------------------- one-shot weight prep
__global__ __launch_bounds__(256) void prep_kernel(const float* __restrict__ W2,
                                                   const float* __restrict__ b2,
                                                   const float* __restrict__ W3,
                                                   const float* __restrict__ b3,
                                                   const float* __restrict__ Wl,
                                                   const float* __restrict__ Wm1,
                                                   const float* __restrict__ Wm2,
                                                   float* __restrict__ Wpk2, float* __restrict__ bpk2,
                                                   float* __restrict__ Wpk3, float* __restrict__ bpk3,
                                                   u16* __restrict__ WlT,
                                                   u16* __restrict__ Wm1T,
                                                   u16* __restrict__ Wm2T) {
    int t = blockIdx.x * 256 + threadIdx.x;
    if (t < 8192) {
        int d = t >> 7, h2 = t & 127;
        Wpk2[t] = (h2 < 64) ? W2[d * 64 + h2] : W2[(64 + d) * 64 + (h2 - 64)];
        if (t < 128) bpk2[t] = (t < 64) ? b2[t] : 0.f;
    } else if (t < 16384) {
        int t2 = t - 8192;
        int d = t2 >> 7, h2 = t2 & 127;
        Wpk3[t2] = (h2 < 64) ? W3[d * 64 + h2] : W3[(64 + d) * 64 + (h2 - 64)];
        if (t2 < 128) bpk3[t2] = (t2 < 64) ? b3[t2] : 0.f;
    } else if (t < 212992) {
        int t2 = t - 16384;
        int k = t2 >> 10, n = t2 & 1023;
        WlT[(size_t)n * 192 + k] = f2bf(Wl[t2]);
    } else if (t < 475136) {
        int t2 = t - 212992;
        int k = t2 >> 8, n = t2 & 255;
        Wm1T[(size_t)n * 1024 + k] = f2bf(Wm1[t2]);
    } else if (t < 507904) {
        int t2 = t - 475136;
        int k = t2 >> 7, n = t2 & 127;
        Wm2T[(size_t)n * 256 + k] = f2bf(Wm2[t2]);
    }
}

// ---------------------------------------------------------------- layer-1 UV (D=3, direct)
__global__ __launch_bounds__(256) void uv3_kernel(const float* __restrict__ x,
                                                  const float* __restrict__ W,
                                                  const float* __restrict__ b,
                                                  float* __restrict__ UV) {
    int t = blockIdx.x * 256 + threadIdx.x;
    int p = t >> 7, h2 = t & 127;
    float x0 = x[p * 3], x1 = x[p * 3 + 1], x2 = x[p * 3 + 2];
    float r;
    if (h2 < 64) {
        r = b[h2] + x0 * W[h2] + x1 * W[64 + h2] + x2 * W[128 + h2];
    } else {
        int h = h2 - 64;
        r = x0 * W[192 + h] + x1 * W[256 + h] + x2 * W[320 + h];
    }
    UV[t] = r;
}

// ---------------------------------------------------------------- edge max
__global__ __launch_bounds__(256) void edgemax_kernel(const float* __restrict__ UV,
                                                      const int* __restrict__ idx,
                                                      float* __restrict__ xout) {
    int wv = threadIdx.x >> 6, lane = threadIdx.x & 63;
    int p = blockIdx.x * 4 + wv;
    const float* uvp = UV + (size_t)p * 128;
    float duv = uvp[lane] - uvp[64 + lane];
    const int* ip = idx + (size_t)p * K_;
    int jj[K_];
#pragma unroll
    for (int k = 0; k < K_; ++k) jj[k] = ip[k];
    float m = -3.4e38f;
#pragma unroll
    for (int k = 0; k < K_; ++k) {
        float vj = UV[(size_t)jj[k] * 128 + 64 + lane];
        float t = duv + vj;
        m = fmaxf(m, fmaxf(t, NEG_SLOPE * t));
    }
    xout[(size_t)p * H_ + lane] = m;
}

// ---------------------------------------------------------------- GEMM 64x64 f32 (UV)
__global__ __launch_bounds__(256) void gemm_kernel(const float* __restrict__ A1,
                                                   const float* __restrict__ Wm,
                                                   const float* __restrict__ bias,
                                                   float* __restrict__ Cm,
                                                   int M, int N, int Kd, int leaky) {
    __shared__ float sA[32][68];
    __shared__ float sB[32][68];

    int tid = threadIdx.x;
    int row0 = blockIdx.x * 64, col0 = blockIdx.y * 64;
    int tx = tid & 15, ty = tid >> 4;

    int lr  = tid >> 2;
    int lk4 = (tid & 3) * 4;
    int lkb = tid >> 4;
    int lnb = (tid & 15) * 4;

    float acc[4][4] = {};

    for (int k0 = 0; k0 < Kd; k0 += 32) {
        int arow = row0 + lr;
#pragma unroll
        for (int h = 0; h < 32; h += 16) {
            int kk = k0 + lk4 + h;
            const float* src = A1 + (size_t)arow * Kd + kk;
            float4 av = *(const float4*)src;
            sA[lk4 + h + 0][lr] = av.x; sA[lk4 + h + 1][lr] = av.y;
            sA[lk4 + h + 2][lr] = av.z; sA[lk4 + h + 3][lr] = av.w;
        }
        int bcol = col0 + lnb;
#pragma unroll
        for (int h = 0; h < 32; h += 16) {
            float4 bv = make_float4(0.f, 0.f, 0.f, 0.f);
            if (bcol < N) bv = *(const float4*)(Wm + (size_t)(k0 + lkb + h) * N + bcol);
            *(float4*)&sB[lkb + h][lnb] = bv;
        }
        __syncthreads();

#pragma unroll
        for (int kk2 = 0; kk2 < 32; ++kk2) {
            float4 a = *(const float4*)&sA[kk2][ty * 4];
            float4 bb = *(const float4*)&sB[kk2][tx * 4];
            acc[0][0] = fmaf(a.x, bb.x, acc[0][0]); acc[0][1] = fmaf(a.x, bb.y, acc[0][1]);
            acc[0][2] = fmaf(a.x, bb.z, acc[0][2]); acc[0][3] = fmaf(a.x, bb.w, acc[0][3]);
            acc[1][0] = fmaf(a.y, bb.x, acc[1][0]); acc[1][1] = fmaf(a.y, bb.y, acc[1][1]);
            acc[1][2] = fmaf(a.y, bb.z, acc[1][2]); acc[1][3] = fmaf(a.y, bb.w, acc[1][3]);
            acc[2][0] = fmaf(a.z, bb.x, acc[2][0]); acc[2][1] = fmaf(a.z, bb.y, acc[2][1]);
            acc[2][2] = fmaf(a.z, bb.z, acc[2][2]); acc[2][3] = fmaf(a.z, bb.w, acc[2][3]);
            acc[3][0] = fmaf(a.w, bb.x, acc[3][0]); acc[3][1] = fmaf(a.w, bb.y, acc[3][1]);
            acc[3][2] = fmaf(a.w, bb.z, acc[3][2]); acc[3][3] = fmaf(a.w, bb.w, acc[3][3]);
        }
        __syncthreads();
    }

    for (int i = 0; i < 4; ++i) {
        int row = row0 + ty * 4 + i;
        for (int j = 0; j < 4; ++j) {
            int col = col0 + tx * 4 + j;
            if (col < N) {
                float v = acc[i][j] + bias[col];
                if (leaky) v = v > 0.f ? v : NEG_SLOPE * v;
                Cm[(size_t)row * N + col] = v;
            }
        }
    }
}

// ---------------------------------------------------------------- MFMA GEMM head (bf16 A)
template <int KD, int OUT_BF16>
__global__ __launch_bounds__(256) void gemm_mfma_kernel(const u16* __restrict__ A,
                                                        const u16* __restrict__ BT,
                                                        const float* __restrict__ bias,
                                                        void* __restrict__ Cout,
                                                        int N, int leaky) {
    __shared__ u16 sA[128 * 64];
    __shared__ u16 sB[128 * 64];

    int t = threadIdx.x;
    int wave = t >> 6, lane = t & 63;
    int wm = wave >> 1, wn = wave & 1;
    int row0 = blockIdx.x * 128;
    int col0 = blockIdx.y * 128;

    f32x4 acc[4][4] = {};

    for (int k0 = 0; k0 < KD; k0 += 64) {
        __syncthreads();
#pragma unroll
        for (int i = 0; i < 4; ++i) {
            int li = t + i * 256;
            int r = li >> 3;
            int kc = (li & 7) * 8;
            bf16x8 v = *(const bf16x8*)(A + (size_t)(row0 + r) * KD + k0 + kc);
            *(bf16x8*)((char*)sA + r * 128 + ((kc * 2) ^ ((r & 7) << 4))) = v;
        }
#pragma unroll
        for (int i = 0; i < 4; ++i) {
            int li = t + i * 256;
            int n = li >> 3;
            int kc = (li & 7) * 8;
            bf16x8 v = *(const bf16x8*)(BT + (size_t)(col0 + n) * KD + k0 + kc);
            *(bf16x8*)((char*)sB + n * 128 + ((kc * 2) ^ ((n & 7) << 4))) = v;
        }
        __syncthreads();

#pragma unroll
        for (int kk = 0; kk < 2; ++kk) {
            int kb = kk * 64 + (lane >> 4) * 16;
            bf16x8 af[4], bfr[4];
#pragma unroll
            for (int mi = 0; mi < 4; ++mi) {
                int r = wm * 64 + mi * 16 + (lane & 15);
                af[mi] = *(const bf16x8*)((char*)sA + r * 128 + (kb ^ ((r & 7) << 4)));
            }
#pragma unroll
            for (int ni = 0; ni < 4; ++ni) {
                int n = wn * 64 + ni * 16 + (lane & 15);
                bfr[ni] = *(const bf16x8*)((char*)sB + n * 128 + (kb ^ ((n & 7) << 4)));
            }
#pragma unroll
            for (int mi = 0; mi < 4; ++mi)
#pragma unroll
                for (int ni = 0; ni < 4; ++ni)
                    acc[mi][ni] = __builtin_amdgcn_mfma_f32_16x16x32_bf16(
                        af[mi], bfr[ni], acc[mi][ni], 0, 0, 0);
        }
    }

#pragma unroll
    for (int ni = 0; ni < 4; ++ni) {
        int col = col0 + wn * 64 + ni * 16 + (lane & 15);
        float bs = bias[col];
#pragma unroll
        for (int mi = 0; mi < 4; ++mi) {
#pragma unroll
            for (int r = 0; r < 4; ++r) {
                int row = row0 + wm * 64 + mi * 16 + (lane >> 4) * 4 + r;
                float v = acc[mi][ni][r] + bs;
                if (leaky) v = v > 0.f ? v : NEG_SLOPE * v;
                if (OUT_BF16)
                    ((u16*)Cout)[(size_t)row * N + col] = f2bf(v);
                else
                    ((float*)Cout)[(size_t)row * N + col] = v;
            }
        }
    }
}

// ---------------------------------------------------------------- MFMA GEMM, cat-f32 A (fused cvt)
__global__ __launch_bounds__(256) void gemm_mfma_cat_kernel(const float* __restrict__ x1,
                                                            const float* __restrict__ x2,
                                                            const float* __restrict__ x3,
                                                            const u16* __restrict__ BT,
                                                            const float* __restrict__ bias,
                                                            u16* __restrict__ Cout,
                                                            int N) {
    __shared__ u16 sA[128 * 64];
    __shared__ u16 sB[128 * 64];

    int t = threadIdx.x;
    int wave = t >> 6, lane = t & 63;
    int wm = wave >> 1, wn = wave & 1;
    int row0 = blockIdx.x * 128;
    int col0 = blockIdx.y * 128;

    f32x4 acc[4][4] = {};

#pragma unroll 1
    for (int k0 = 0; k0 < 192; k0 += 64) {
        const float* src = (k0 == 0) ? x1 : (k0 == 64) ? x2 : x3;
        __syncthreads();
#pragma unroll
        for (int i = 0; i < 4; ++i) {
            int li = t + i * 256;
            int r = li >> 3;
            int kc = (li & 7) * 8;
            const float* sp = src + (size_t)(row0 + r) * 64 + kc;
            float4 a0 = *(const float4*)sp;
            float4 a1 = *(const float4*)(sp + 4);
            bf16x8 v;
            v[0] = (short)f2bf(a0.x); v[1] = (short)f2bf(a0.y);
            v[2] = (short)f2bf(a0.z); v[3] = (short)f2bf(a0.w);
            v[4] = (short)f2bf(a1.x); v[5] = (short)f2bf(a1.y);
            v[6] = (short)f2bf(a1.z); v[7] = (short)f2bf(a1.w);
            *(bf16x8*)((char*)sA + r * 128 + ((kc * 2) ^ ((r & 7) << 4))) = v;
        }
#pragma unroll
        for (int i = 0; i < 4; ++i) {
            int li = t + i * 256;
            int n = li >> 3;
            int kc = (li & 7) * 8;
            bf16x8 v = *(const bf16x8*)(BT + (size_t)(col0 + n) * 192 + k0 + kc);
            *(bf16x8*)((char*)sB + n * 128 + ((kc * 2) ^ ((n & 7) << 4))) = v;
        }
        __syncthreads();

#pragma unroll
        for (int kk = 0; kk < 2; ++kk) {
            int kb = kk * 64 + (lane >> 4) * 16;
            bf16x8 af[4], bfr[4];
#pragma unroll
            for (int mi = 0; mi < 4; ++mi) {
                int r = wm * 64 + mi * 16 + (lane & 15);
                af[mi] = *(const bf16x8*)((char*)sA + r * 128 + (kb ^ ((r & 7) << 4)));
            }
#pragma unroll
            for (int ni = 0; ni < 4; ++ni) {
                int n = wn * 64 + ni * 16 + (lane & 15);
                bfr[ni] = *(const bf16x8*)((char*)sB + n * 128 + (kb ^ ((n & 7) << 4)));
            }
#pragma unroll
            for (int mi = 0; mi < 4; ++mi)
#pragma unroll
                for (int ni = 0; ni < 4; ++ni)
                    acc[mi][ni] = __builtin_amdgcn_mfma_f32_16x16x32_bf16(
                        af[mi], bfr[ni], acc[mi][ni], 0, 0, 0);
        }
    }

#pragma unroll
    for (int ni = 0; ni < 4; ++ni) {
        int col = col0 + wn * 64 + ni * 16 + (lane & 15);
        float bs = bias[col];
#pragma unroll
        for (int mi = 0; mi < 4; ++mi) {
#pragma unroll
            for (int r = 0; r < 4; ++r) {
                int row = row0 + wm * 64 + mi * 16 + (lane >> 4) * 4 + r;
                float v = acc[mi][ni][r] + bs;
                v = v > 0.f ? v : NEG_SLOPE * v;
                Cout[(size_t)row * N + col] = f2bf(v);
            }
        }
    }
}

// ---------------------------------------------------------------- fused Wo GEMM + log_softmax
__global__ __launch_bounds__(256) void lsm_wo_kernel(const float* __restrict__ act3,
                                                     const float* __restrict__ Wo,
                                                     const float* __restrict__ bo,
                                                     float* __restrict__ out) {
    __shared__ float sWo[128 * 44];
    __shared__ float sAct[4][128];

    int t = threadIdx.x;
    for (int i = t; i < 128 * 40; i += 256) {
        int k = i / 40, c = i % 40;
        sWo[k * 44 + c] = Wo[i];
    }
    __syncthreads();

    int wv = t >> 6, lane = t & 63;
    int row = blockIdx.x * 4 + wv;
    sAct[wv][lane]      = act3[(size_t)row * 128 + lane];
    sAct[wv][64 + lane] = act3[(size_t)row * 128 + 64 + lane];

    float acc = (lane < C_) ? bo[lane] : -3.4e38f;
    if (lane < C_) {
#pragma unroll 8
        for (int k = 0; k < 128; ++k)
            acc = fmaf(sAct[wv][k], sWo[k * 44 + lane], acc);
    }
    float m = acc;
#pragma unroll
    for (int s = 1; s < 64; s <<= 1) m = fmaxf(m, __shfl_xor(m, s));
    float e = (lane < C_) ? expf(acc - m) : 0.f;
    float sum = e;
#pragma unroll
    for (int s = 1; s < 64; s <<= 1) sum += __shfl_xor(sum, s);
    if (lane < C_) out[(size_t)row * C_ + lane] = acc - m - logf(sum);
}

// ----------------------------------------------------------------
extern "C" void kernel_launch(void* const* d_in, const int* in_sizes, int n_in,
                              void* d_out, int out_size, void* d_ws, size_t ws_size,
                              hipStream_t stream) {
    const float* x   = (const float*)d_in[0];
    const float* W1  = (const float*)d_in[2];
    const float* b1  = (const float*)d_in[3];
    const float* W2  = (const float*)d_in[4];
    const float* b2  = (const float*)d_in[5];
    const float* W3  = (const float*)d_in[6];
    const float* b3  = (const float*)d_in[7];
    const float* Wl  = (const float*)d_in[8];
    const float* bl  = (const float*)d_in[9];
    const float* Wm1 = (const float*)d_in[10];
    const float* bm1 = (const float*)d_in[11];
    const float* Wm2 = (const float*)d_in[12];
    const float* bm2 = (const float*)d_in[13];
    const float* Wo  = (const float*)d_in[14];
    const float* bo  = (const float*)d_in[15];
    float* out = (float*)d_out;

    // ---- workspace (max 50,987,008 B — proven footprint) ----
    char* ws = (char*)d_ws;
    float* x1   = (float*)(ws);
    float* x2   = (float*)(ws + 8388608);
    float* x3   = (float*)(ws + 16777216);
    int*   idx  = (int*)  (ws + 25165824);
    float* d2   = (float*)(ws + 27787264);
    char* hb = ws + 27918336;
    u16*   xhs  = (u16*)(hb);                         // 4 MB
    u16*   xms  = (u16*)(hb + 4194304);               // 4 MB
    float* UV   = (float*)(hb);                       // 16 MB
    float* Wpk2 = (float*)(ws + 44695552);
    float* bpk2 = (float*)(ws + 44728320);
    float* Wpk3 = (float*)(ws + 44728832);
    float* bpk3 = (float*)(ws + 44761600);
    u16*   WlT  = (u16*)  (ws + 44762112);
    u16*   Wm1T = (u16*)  (ws + 45155328);
    u16*   Wm2T = (u16*)  (ws + 45679616);
    u16*   act1 = (u16*)(hb);
    u16*   act2 = (u16*)(ws + 45745152);
    float* act3 = (float*)(hb);

    prep_kernel<<<1984, 256, 0, stream>>>(W2, b2, W3, b3, Wl, Wm1, Wm2,
                                          Wpk2, bpk2, Wpk3, bpk3, WlT, Wm1T, Wm2T);

    // ---- layer 1 (D=3)
    d2_kernel<3><<<NPT / 256, 256, 0, stream>>>(x, d2);
    knnf3_kernel<<<dim3(P_ / 64, B_), 256, 0, stream>>>(x, d2, idx);
    uv3_kernel<<<NPT * 128 / 256, 256, 0, stream>>>(x, W1, b1, UV);
    edgemax_kernel<<<NPT / 4, 256, 0, stream>>>(UV, idx, x1);
    // ---- layer 2 (D=64)
    d2cvt2_kernel<<<NPT / 256, 256, 0, stream>>>(x1, d2, xhs, xms);
    knnm64_kernel<<<dim3(P_ / 64, B_), 256, 0, stream>>>(xhs, xms, d2, idx);
    gemm_kernel<<<dim3(NPT / 64, 2), 256, 0, stream>>>(x1, Wpk2, bpk2, UV, NPT, 128, 64, 0);
    edgemax_kernel<<<NPT / 4, 256, 0, stream>>>(UV, idx, x2);
    // ---- layer 3 (D=64)
    d2cvt2_kernel<<<NPT / 256, 256, 0, stream>>>(x2, d2, xhs, xms);
    knnm64_kernel<<<dim3(P_ / 64, B_), 256, 0, stream>>>(xhs, xms, d2, idx);
    gemm_kernel<<<dim3(NPT / 64, 2), 256, 0, stream>>>(x2, Wpk3, bpk3, UV, NPT, 128, 64, 0);
    edgemax_kernel<<<NPT / 4, 256, 0, stream>>>(UV, idx, x3);

    // ---- MLP head: 4 chunks of 8192 rows
    for (int c = 0; c < 4; ++c) {
        size_t r0 = (size_t)c * 8192;
        gemm_mfma_cat_kernel<<<dim3(64, 8), 256, 0, stream>>>(x1 + r0 * 64, x2 + r0 * 64,
                                                              x3 + r0 * 64, WlT, bl, act1, 1024);
        gemm_mfma_kernel<1024, 1><<<dim3(64, 2), 256, 0, stream>>>(act1, Wm1T, bm1, act2, 256, 1);
        gemm_mfma_kernel<256, 0><<<dim3(64, 1), 256, 0, stream>>>(act2, Wm2T, bm2, act3, 128, 1);
        lsm_wo_kernel<<<2048, 256, 0, stream>>>(act3, Wo, bo, out + r0 * C_);
    }
}